// Round 16
// baseline (683.255 us; speedup 1.0000x reference)
//
#include <hip/hip_runtime.h>
#include <hip/hip_bf16.h>

#define NNODES 100000
#define NPG    12500
#define NGRAPH 8
#define KD     128
#define CD     128
#define INDIM  7
#define GSDIM  11
#define NBLKS  4
#define NCLF   5
#define NEDGE  800000
#define BCAP   32             // packed u64 entries; Poisson(8) tail P(d>32) ~ 3e-6
#define NPGP   12800          // padded nodes per graph (40 * 320)
#define TBSPLIT 40            // to_basis split-n
#define TBCHUNK 320           // = NPGP / TBSPLIT, 10 k-steps of 32
#define NT32    391           // ceil(12500/32)
#define NT128   98            // ceil(12500/128)

typedef __attribute__((ext_vector_type(8))) short short8v;
typedef __attribute__((ext_vector_type(4))) float f32x4;
typedef unsigned short u16;
typedef unsigned long long u64;

#define MFMA(acc, a, b) acc = __builtin_amdgcn_mfma_f32_16x16x32_bf16(a, b, acc, 0, 0, 0)

__device__ __forceinline__ u16 f2b(float f) {
  union { __hip_bfloat16 h; u16 u; } cv;
  cv.h = __float2bfloat16(f);
  return cv.u;
}
__device__ __forceinline__ float b2f(u16 u) {
  return __uint_as_float((unsigned)u << 16);
}

// ---------- LDS staging helpers (tile layout: [rows][40] u16, 32 valid k) ----------

__device__ __forceinline__ void stage64_f32(u16* S, const float* src, int ld, int k0, int valid) {
  int t = threadIdx.x, row = t >> 2, kq = t & 3;
  alignas(16) u16 tmp[8] = {0, 0, 0, 0, 0, 0, 0, 0};
  if (row < valid) {
    const float* p = src + (size_t)row * ld + k0 + kq * 8;
    float4 f0 = *(const float4*)p, f1 = *(const float4*)(p + 4);
    tmp[0] = f2b(f0.x); tmp[1] = f2b(f0.y); tmp[2] = f2b(f0.z); tmp[3] = f2b(f0.w);
    tmp[4] = f2b(f1.x); tmp[5] = f2b(f1.y); tmp[6] = f2b(f1.z); tmp[7] = f2b(f1.w);
  }
  *(uint4*)&S[row * 40 + kq * 8] = *(uint4*)tmp;
}

__device__ __forceinline__ void stage64_b16(u16* S, const u16* src, long ld, int k0, int valid) {
  int t = threadIdx.x, row = t >> 2, kq = t & 3;
  uint4 v = make_uint4(0, 0, 0, 0);
  if (row < valid) v = *(const uint4*)(src + (size_t)row * ld + k0 + kq * 8);
  *(uint4*)&S[row * 40 + kq * 8] = v;
}

// 32-row variant: threads 0..127 stage a [32][40] tile
__device__ __forceinline__ void stage32_b16(u16* S, const u16* src, long ld, int k0, int valid) {
  int t = threadIdx.x;
  if (t < 128) {
    int row = t >> 2, kq = t & 3;
    uint4 v = make_uint4(0, 0, 0, 0);
    if (row < valid) v = *(const uint4*)(src + (size_t)row * ld + k0 + kq * 8);
    *(uint4*)&S[row * 40 + kq * 8] = v;
  }
}

__device__ __forceinline__ void stage128_b16(u16* S, const u16* src, long ld, int k0) {
  int t = threadIdx.x, row = t >> 1, half = t & 1;
  const u16* p = src + (size_t)row * ld + k0 + half * 16;
  uint4 v0 = *(const uint4*)p, v1 = *(const uint4*)(p + 8);
  *(uint4*)&S[row * 40 + half * 16] = v0;
  *(uint4*)&S[row * 40 + half * 16 + 8] = v1;
}

__device__ __forceinline__ void stage128_f32(u16* S, const float* src, int ld, int k0) {
  int t = threadIdx.x, row = t >> 1, half = t & 1;
  const float* p = src + (size_t)row * ld + k0 + half * 16;
  float4 f0 = *(const float4*)p, f1 = *(const float4*)(p + 4);
  float4 f2 = *(const float4*)(p + 8), f3 = *(const float4*)(p + 12);
  alignas(16) u16 tmp[16];
  tmp[0] = f2b(f0.x); tmp[1] = f2b(f0.y); tmp[2]  = f2b(f0.z); tmp[3]  = f2b(f0.w);
  tmp[4] = f2b(f1.x); tmp[5] = f2b(f1.y); tmp[6]  = f2b(f1.z); tmp[7]  = f2b(f1.w);
  tmp[8] = f2b(f2.x); tmp[9] = f2b(f2.y); tmp[10] = f2b(f2.z); tmp[11] = f2b(f2.w);
  tmp[12] = f2b(f3.x); tmp[13] = f2b(f3.y); tmp[14] = f2b(f3.z); tmp[15] = f2b(f3.w);
  *(uint4*)&S[row * 40 + half * 16] = *(uint4*)&tmp[0];
  *(uint4*)&S[row * 40 + half * 16 + 8] = *(uint4*)&tmp[8];
}

// full 128x128 A tile staged by 512 threads (pitch 136)
__device__ __forceinline__ void stageA_b16(u16* Af, const u16* src, long ld, int valid) {
  int t = threadIdx.x;
#pragma unroll
  for (int q = 0; q < 4; ++q) {
    int lin = t + q * 512;
    int row = lin >> 4, kq = lin & 15;
    uint4 v = make_uint4(0, 0, 0, 0);
    if (row < valid) v = *(const uint4*)(src + (size_t)row * ld + kq * 8);
    *(uint4*)&Af[row * 136 + kq * 8] = v;
  }
}
__device__ __forceinline__ void stageA_f32(u16* Af, const float* src, long ld, int valid) {
  int t = threadIdx.x;
#pragma unroll
  for (int q = 0; q < 4; ++q) {
    int lin = t + q * 512;
    int row = lin >> 4, kq = lin & 15;
    alignas(16) u16 tmp[8] = {0, 0, 0, 0, 0, 0, 0, 0};
    if (row < valid) {
      const float* p = src + (size_t)row * ld + kq * 8;
      float4 f0 = *(const float4*)p, f1 = *(const float4*)(p + 4);
      tmp[0] = f2b(f0.x); tmp[1] = f2b(f0.y); tmp[2] = f2b(f0.z); tmp[3] = f2b(f0.w);
      tmp[4] = f2b(f1.x); tmp[5] = f2b(f1.y); tmp[6] = f2b(f1.z); tmp[7] = f2b(f1.w);
    }
    *(uint4*)&Af[row * 136 + kq * 8] = *(uint4*)tmp;
  }
}

// B tile (128 rows x 32 k) load/store: 1 uint4 per thread at 512 threads
__device__ __forceinline__ uint4 ldB(const u16* bt, int k0) {
  int t = threadIdx.x, row = t >> 2, kq = t & 3;
  return *(const uint4*)(bt + (size_t)row * 128 + k0 + kq * 8);
}
__device__ __forceinline__ void stB(u16* Bs, uint4 v) {
  int t = threadIdx.x, row = t >> 2, kq = t & 3;
  *(uint4*)&Bs[row * 40 + kq * 8] = v;
}

__device__ __forceinline__ short8v frag(const u16* S, int row0, int l) {
  return *(const short8v*)&S[(row0 + (l & 15)) * 40 + (l >> 4) * 8];
}
__device__ __forceinline__ short8v frag_p(const u16* S, int row0, int l, int pitch, int k0) {
  return *(const short8v*)&S[(row0 + (l & 15)) * pitch + k0 + (l >> 4) * 8];
}

// ---------------------- utility kernels ----------------------

__global__ void k_fill0(float4* p, int n4) {
  int i = blockIdx.x * blockDim.x + threadIdx.x;
  int s = gridDim.x * blockDim.x;
  float4 z = make_float4(0.f, 0.f, 0.f, 0.f);
  for (; i < n4; i += s) p[i] = z;
}

// fused embed: h16 = bf16(relu(x@W+b)); hmT = mass-scaled transpose
__global__ __launch_bounds__(256) void k_embed2(const float* __restrict__ x,
                                                const float* __restrict__ W,
                                                const float* __restrict__ bv,
                                                const float* __restrict__ mass,
                                                u16* __restrict__ h16,
                                                u16* __restrict__ hmT) {
  int b = blockIdx.x / 200, tile = blockIdx.x % 200;
  int n0 = tile * 64;
  size_t gbase = (size_t)b * NPG;
  int t = threadIdx.x;
  __shared__ float xs[64][8];
  __shared__ float Ws[INDIM][128];
  __shared__ float bs[128];
  __shared__ float ms[64];
  __shared__ float ld[64][132];
  if (t < 128) bs[t] = bv[t];
  for (int i = t; i < INDIM * 128; i += 256) Ws[i >> 7][i & 127] = W[i];
  for (int i = t; i < 64 * INDIM; i += 256) {
    int r = i / INDIM, q = i % INDIM;
    int gn = n0 + r;
    xs[r][q] = (gn < NPG) ? x[(gbase + gn) * INDIM + q] : 0.f;
  }
  if (t < 64) {
    int gn = n0 + t;
    ms[t] = (gn < NPG) ? mass[gbase + gn] : 0.f;
  }
  __syncthreads();
  {
    int row = t & 63, c0 = (t >> 6) * 32;
#pragma unroll
    for (int cc = 0; cc < 32; ++cc) {
      int c = c0 + cc;
      float acc = bs[c];
#pragma unroll
      for (int i = 0; i < INDIM; ++i) acc = fmaf(xs[row][i], Ws[i][c], acc);
      ld[row][c] = fmaxf(acc, 0.f);
    }
  }
  __syncthreads();
  {
    int row = t >> 2, q = t & 3;
    if (n0 + row < NPG) {
      size_t base = (gbase + n0 + row) * (size_t)CD + q * 32;
      alignas(16) u16 tmp[8];
#pragma unroll
      for (int u = 0; u < 4; ++u) {
#pragma unroll
        for (int i = 0; i < 8; ++i) tmp[i] = f2b(ld[row][q * 32 + u * 8 + i]);
        *(uint4*)&h16[base + u * 8] = *(uint4*)tmp;
      }
    }
  }
  {
    int crow = t >> 1, half = t & 1;
    alignas(16) u16 tmp[8];
#pragma unroll
    for (int q = 0; q < 4; ++q) {
      int nb = half * 32 + q * 8;
#pragma unroll
      for (int i = 0; i < 8; ++i) tmp[i] = f2b(ld[nb + i][crow] * ms[nb + i]);
      *(uint4*)&hmT[((size_t)(b * 128 + crow)) * NPGP + n0 + nb] = *(uint4*)tmp;
    }
  }
}

// packed bucket: entry = col | bf16(vre)<<32 | bf16(vim)<<48
__global__ void k_bucket_place(const int* __restrict__ rows, const int* __restrict__ cols,
                               const float* __restrict__ vre, const float* __restrict__ vim,
                               int* cnt, u64* bucket) {
  int e = blockIdx.x * 256 + threadIdx.x;
  if (e >= NEDGE) return;
  int r = rows[e];
  int pos = atomicAdd(&cnt[r], 1);
  if (pos < BCAP) {
    u64 ent = (u64)(unsigned)cols[e]
            | ((u64)f2b(vre[e]) << 32)
            | ((u64)f2b(vim[e]) << 48);
    bucket[(size_t)r * BCAP + pos] = ent;
  }
}

// gather: 2 waves per row (half the dependent-load chain each), LDS combine.
// XCD-swizzled: 50000 blocks = 8 graphs x 6250; 2 rows per block.
__global__ __launch_bounds__(256) void k_gather_ev(
    const int* __restrict__ cnt, const u64* __restrict__ bucket,
    const float* __restrict__ evf, const u16* __restrict__ ev16, int useB16,
    u16* __restrict__ gre, u16* __restrict__ gim) {
  int orig = blockIdx.x;                        // 50000 = 8 * 6250
  int blk  = (orig & 7) * 6250 + (orig >> 3);
  int t = threadIdx.x;
  int pair = t >> 7;        // row within block (0..1)
  int wv   = (t >> 6) & 1;  // wave within pair
  int ln   = t & 63;
  int r = blk * 2 + pair;
  int d = min(cnt[r], BCAP);
  const u64* bk = bucket + (size_t)r * BCAP;
  int i0 = wv ? (d >> 1) : 0;
  int i1 = wv ? d : (d >> 1);
  float2 ra = make_float2(0.f, 0.f), ia = make_float2(0.f, 0.f);
  if (useB16) {
    for (int i = i0; i < i1; ++i) {
      u64 e0 = bk[i];
      int c0 = (int)(unsigned)e0;
      float a = b2f((u16)(e0 >> 32)), b = b2f((u16)(e0 >> 48));
      ushort2 u0 = *(const ushort2*)&ev16[(size_t)c0 * KD + ln * 2];
      ra.x = fmaf(a, b2f(u0.x), ra.x); ra.y = fmaf(a, b2f(u0.y), ra.y);
      ia.x = fmaf(b, b2f(u0.x), ia.x); ia.y = fmaf(b, b2f(u0.y), ia.y);
    }
  } else {
    for (int i = i0; i < i1; ++i) {
      u64 e0 = bk[i];
      int c0 = (int)(unsigned)e0;
      float a = b2f((u16)(e0 >> 32)), b = b2f((u16)(e0 >> 48));
      float2 v = *(const float2*)&evf[(size_t)c0 * KD + ln * 2];
      ra.x = fmaf(a, v.x, ra.x); ra.y = fmaf(a, v.y, ra.y);
      ia.x = fmaf(b, v.x, ia.x); ia.y = fmaf(b, v.y, ia.y);
    }
  }
  __shared__ float part[2][64][4];
  if (wv == 1) {
    part[pair][ln][0] = ra.x; part[pair][ln][1] = ra.y;
    part[pair][ln][2] = ia.x; part[pair][ln][3] = ia.y;
  }
  __syncthreads();
  if (wv == 0) {
    ra.x += part[pair][ln][0]; ra.y += part[pair][ln][1];
    ia.x += part[pair][ln][2]; ia.y += part[pair][ln][3];
    ushort2 ro, io;
    ro.x = f2b(ra.x); ro.y = f2b(ra.y);
    io.x = f2b(ia.x); io.y = f2b(ia.y);
    *(ushort2*)&gre[(size_t)r * KD + ln * 2] = ro;
    *(ushort2*)&gim[(size_t)r * KD + ln * 2] = io;
  }
}

// Transposed bf16 weights: W*T[c][j] = W[j][c]
__global__ void k_prep_w(const float* __restrict__ W1, const float* __restrict__ W2,
                         u16* W1aT, u16* W1bT, u16* W1cT, u16* W2T) {
  int idx = blockIdx.x * 256 + threadIdx.x;      // 4 * 4 * 16384
  int blk = idx >> 16, rem = idx & 65535;
  int mat = rem >> 14, e = rem & 16383;
  int j = e >> 7, c = e & 127;
  float v;
  u16* dst;
  if (mat < 3) {
    v = W1[(size_t)blk * 3 * 16384 + (size_t)mat * 16384 + e];
    dst = (mat == 0) ? W1aT : (mat == 1 ? W1bT : W1cT);
  } else {
    v = W2[(size_t)blk * 16384 + e];
    dst = W2T;
  }
  dst[(size_t)blk * 16384 + c * 128 + j] = f2b(v);
}

// head weights: B1T[c][k] (64 x 160, k<139 valid), B2T[c][k] (16 x 64, c<5 valid)
__global__ void k_prep_head(const float* __restrict__ Wh1, const float* __restrict__ Wh2,
                            u16* __restrict__ B1T, u16* __restrict__ B2T) {
  for (int idx = threadIdx.x; idx < 64 * 160; idx += 256) {
    int c = idx / 160, k = idx % 160;
    B1T[idx] = f2b(k < (CD + GSDIM) ? Wh1[k * 64 + c] : 0.f);
  }
  for (int idx = threadIdx.x; idx < 16 * 64; idx += 256) {
    int c = idx >> 6, k = idx & 63;
    B2T[idx] = f2b(c < NCLF ? Wh2[k * NCLF + c] : 0.f);
  }
}

// evT[b][k][n_pad] = evecs[n][k] bf16 ; also writes row-major ev16 mirror
__global__ void k_transpose_nk(const float* __restrict__ src, u16* __restrict__ dst,
                               u16* __restrict__ ev16, int writeMir) {
  int b = blockIdx.x / 200, tile = blockIdx.x % 200;
  int n0 = tile * 64;
  size_t gbase = (size_t)b * NPG;
  int t = threadIdx.x;
  __shared__ float ld[64][132];
  int row0 = t >> 5, c4 = t & 31;
#pragma unroll
  for (int it = 0; it < 8; ++it) {
    int r = it * 8 + row0;
    int gn = n0 + r;
    float4 v = make_float4(0.f, 0.f, 0.f, 0.f);
    if (gn < NPG) v = *(const float4*)&src[(gbase + gn) * KD + c4 * 4];
    *(float4*)&ld[r][c4 * 4] = v;
    if (writeMir && gn < NPG) {
      ushort4 o;
      o.x = f2b(v.x); o.y = f2b(v.y); o.z = f2b(v.z); o.w = f2b(v.w);
      *(ushort4*)&ev16[(gbase + gn) * KD + c4 * 4] = o;
    }
  }
  __syncthreads();
  int crow = t >> 1, half = t & 1;
  alignas(16) u16 tmp[8];
#pragma unroll
  for (int q = 0; q < 4; ++q) {
    int nb = half * 32 + q * 8;
#pragma unroll
    for (int i = 0; i < 8; ++i) tmp[i] = f2b(ld[nb + i][crow]);
    *(uint4*)&dst[((size_t)(b * 128 + crow)) * NPGP + n0 + nb] = *(uint4*)tmp;
  }
}

// ---------------------- MFMA kernels ----------------------

// partials[(b*TBSPLIT+s)][kt*64+k][c] = sum_{n in chunk} evT[b][kt*64+k][n]*hmT[b][c][n]
__global__ __launch_bounds__(256) void k_tobasis(const u16* __restrict__ evT,
                                                 const u16* __restrict__ hmT,
                                                 float* __restrict__ partials) {
  int g = blockIdx.x;
  int kt = g & 1;
  int s  = (g >> 1) % TBSPLIT;
  int b  = g / (2 * TBSPLIT);
  int t = threadIdx.x, w = t >> 6, l = t & 63;
  __shared__ u16 As[64 * 40];
  __shared__ u16 Bs[128 * 40];
  f32x4 acc[8];
  f32x4 z = {0.f, 0.f, 0.f, 0.f};
#pragma unroll
  for (int j = 0; j < 8; ++j) acc[j] = z;
  const u16* ae = evT + ((size_t)(b * 128 + kt * 64)) * NPGP + s * TBCHUNK;
  const u16* bh = hmT + (size_t)b * 128 * NPGP + s * TBCHUNK;
  for (int ks = 0; ks < TBCHUNK / 32; ++ks) {
    stage64_b16(As, ae, NPGP, ks * 32, 64);
    stage128_b16(Bs, bh, NPGP, ks * 32);
    __syncthreads();
    short8v a = frag(As, w * 16, l);
    __builtin_amdgcn_s_setprio(1);
#pragma unroll
    for (int j = 0; j < 8; ++j) MFMA(acc[j], a, frag(Bs, j * 16, l));
    __builtin_amdgcn_s_setprio(0);
    __syncthreads();
  }
  float* op = partials + (size_t)(b * TBSPLIT + s) * 16384 + kt * 64 * 128;
#pragma unroll
  for (int j = 0; j < 8; ++j)
#pragma unroll
    for (int i = 0; i < 4; ++i) {
      int krow = w * 16 + (l >> 4) * 4 + i;
      int c = j * 16 + (l & 15);
      op[krow * 128 + c] = acc[j][i];
    }
}

// spec[b][k][c] = scale(sum_s partials); specT16[b][c][k] = bf16(spec)
__global__ void k_reduce_scale_t(const float* __restrict__ partials,
                                 const float* __restrict__ evals,
                                 const float* __restrict__ td,
                                 float* __restrict__ spec, u16* __restrict__ specT) {
  int b = blockIdx.x >> 6;
  int idx = (blockIdx.x & 63) * 256 + threadIdx.x;
  int k = idx >> 7, c = idx & 127;
  float s = 0.f;
#pragma unroll 8
  for (int sp = 0; sp < TBSPLIT; ++sp)
    s += partials[(size_t)(b * TBSPLIT + sp) * 16384 + idx];
  float tm = fmaxf(fabsf(td[c]), 1e-8f);
  s *= expf(-evals[b * KD + k] * tm);
  spec[(size_t)b * 16384 + idx] = s;
  specT[(size_t)b * 16384 + c * 128 + k] = f2b(s);
}

// job0: SAT16[b][c][k] = sum_j Agrad[c][j]*spec[b][k][j]
// job1: M1T16[b][c][k] = sum_j W1bT[c][j]*spec[b][k][j]
__global__ __launch_bounds__(256) void k_smallT(const float* __restrict__ Agrad_blk,
                                                const u16* __restrict__ W1bT_blk,
                                                const float* __restrict__ spec,
                                                u16* __restrict__ SAT, u16* __restrict__ M1T) {
  int b = blockIdx.x & 7;
  int job = (blockIdx.x >> 3) & 1;
  int q = blockIdx.x >> 4;                 // 0..3: c-row quarter
  int t = threadIdx.x, w = t >> 6, l = t & 63;
  __shared__ u16 As[128 * 40];
  __shared__ u16 Bs[128 * 40];
  f32x4 acc[2][2];
  f32x4 z = {0.f, 0.f, 0.f, 0.f};
#pragma unroll
  for (int mi = 0; mi < 2; ++mi) { acc[mi][0] = z; acc[mi][1] = z; }
  for (int ks = 0; ks < 4; ++ks) {
    if (job == 0) stage128_f32(As, Agrad_blk, 128, ks * 32);
    else          stage128_b16(As, W1bT_blk, 128, ks * 32);
    stage128_f32(Bs, spec + (size_t)b * 16384, 128, ks * 32);
    __syncthreads();
    short8v a0 = frag(As, q * 32, l);
    short8v a1 = frag(As, q * 32 + 16, l);
#pragma unroll
    for (int jj = 0; jj < 2; ++jj) {
      short8v bj = frag(Bs, (w * 2 + jj) * 16, l);
      MFMA(acc[0][jj], a0, bj);
      MFMA(acc[1][jj], a1, bj);
    }
    __syncthreads();
  }
  u16* out = (job == 0 ? SAT : M1T) + (size_t)b * 16384;
#pragma unroll
  for (int mi = 0; mi < 2; ++mi)
#pragma unroll
    for (int jj = 0; jj < 2; ++jj)
#pragma unroll
      for (int i = 0; i < 4; ++i)
        out[(q * 32 + mi * 16 + (l >> 4) * 4 + i) * 128 + (w * 2 + jj) * 16 + (l & 15)] =
            f2b(acc[mi][jj][i]);
}

// gf16 = tanh((Gre@spec')*(Gre@SA) + (Gim@spec')*(Gim@SA))   [bf16 out]
__global__ __launch_bounds__(256) void k_gfeat(const u16* __restrict__ Gre,
                                               const u16* __restrict__ Gim,
                                               const u16* __restrict__ specT,
                                               const u16* __restrict__ SAT,
                                               u16* __restrict__ gf) {
  int b = blockIdx.x / NT32, tile = blockIdx.x % NT32;
  int n0 = tile * 32;
  size_t gbase = (size_t)b * NPG;
  int t = threadIdx.x, w = t >> 6, l = t & 63;
  int r0 = (w & 1) * 16, c0 = (w >> 1) * 64;
  __shared__ u16 Sr[32 * 40];
  __shared__ u16 Si[32 * 40];
  __shared__ u16 Bs[128 * 40];
  __shared__ u16 Ba[128 * 40];
  f32x4 aGR[4], aAR[4], aGI[4], aAI[4];
  f32x4 z = {0.f, 0.f, 0.f, 0.f};
#pragma unroll
  for (int j = 0; j < 4; ++j) { aGR[j] = z; aAR[j] = z; aGI[j] = z; aAI[j] = z; }
  int valid = min(32, NPG - n0);
  const u16* gre = Gre + (gbase + n0) * KD;
  const u16* gim = Gim + (gbase + n0) * KD;
  for (int ks = 0; ks < 4; ++ks) {
    stage32_b16(Sr, gre, KD, ks * 32, valid);
    stage32_b16(Si, gim, KD, ks * 32, valid);
    stage128_b16(Bs, specT + (size_t)b * 16384, 128, ks * 32);
    stage128_b16(Ba, SAT + (size_t)b * 16384, 128, ks * 32);
    __syncthreads();
    short8v fr = frag(Sr, r0, l);
    short8v fi = frag(Si, r0, l);
    __builtin_amdgcn_s_setprio(1);
#pragma unroll
    for (int j = 0; j < 4; ++j) {
      short8v bs = frag(Bs, c0 + j * 16, l);
      short8v ba = frag(Ba, c0 + j * 16, l);
      MFMA(aGR[j], fr, bs);
      MFMA(aAR[j], fr, ba);
      MFMA(aGI[j], fi, bs);
      MFMA(aAI[j], fi, ba);
    }
    __builtin_amdgcn_s_setprio(0);
    __syncthreads();
  }
#pragma unroll
  for (int j = 0; j < 4; ++j) {
    int c = c0 + j * 16 + (l & 15);
#pragma unroll
    for (int i = 0; i < 4; ++i) {
      int n = n0 + r0 + (l >> 4) * 4 + i;
      if (n - n0 < valid) {
        float v = tanhf(fmaf(aGR[j][i], aAR[j][i], aGI[j][i] * aAI[j][i]));
        gf[(gbase + n) * CD + c] = f2b(v);
      }
    }
  }
}

// ---- fused mlp1+mlp2, 512 threads / 128-row tiles; persistent-A + dbuf-B ----
__global__ __launch_bounds__(512) void k_mlp12(const float* __restrict__ evf,
                                               const u16* __restrict__ ev16,
                                               int useB16,
                                               const u16* __restrict__ gf,
                                               const u16* __restrict__ W1aT,
                                               const u16* __restrict__ M1T,
                                               const u16* __restrict__ W1cT,
                                               const float* __restrict__ b1,
                                               const u16* __restrict__ W2T,
                                               const float* __restrict__ b2,
                                               const float* __restrict__ mass,
                                               u16* __restrict__ h16,
                                               u16* __restrict__ hmT,
                                               int writeHmT) {
  int b = blockIdx.x / NT128, tile = blockIdx.x % NT128;
  int n0 = tile * 128;
  size_t gbase = (size_t)b * NPG;
  int t = threadIdx.x, w = t >> 6, l = t & 63;     // 8 waves
  // LDS u16: Af[0,17408) pitch 136 ; Bs0[17408,22528) ; Bs1[22528,27648)
  // overlays in Af region: t1S pitch 132 (16896), Tm pitch 130 (16640)
  __shared__ u16 SH[27648];
  u16* Af  = SH;
  u16* t1S = SH;
  u16* Tm  = SH;
  u16* Bs0 = SH + 17408;
  u16* Bs1 = SH + 22528;
  f32x4 acc[8];
  f32x4 z = {0.f, 0.f, 0.f, 0.f};
#pragma unroll
  for (int j = 0; j < 8; ++j) acc[j] = z;
  int valid = min(128, NPG - n0);
  int r0 = w * 16;                    // wave's row block

  // ===== phase 1: mlp1 (3 segments of K=128), persistent A per segment =====
  for (int seg = 0; seg < 3; ++seg) {
    const u16* bt = (seg == 0) ? W1aT : (seg == 1 ? M1T + (size_t)b * 16384 : W1cT);
    if (seg == 0)      stageA_b16(Af, h16 + (gbase + n0) * CD, CD, valid);
    else if (seg == 1) {
      if (useB16) stageA_b16(Af, ev16 + (gbase + n0) * KD, KD, valid);
      else        stageA_f32(Af, evf + (gbase + n0) * KD, KD, valid);
    }
    else               stageA_b16(Af, gf + (gbase + n0) * CD, CD, valid);
    stB(Bs0, ldB(bt, 0));
    __syncthreads();
#pragma unroll
    for (int ks = 0; ks < 4; ++ks) {
      uint4 bvn;
      if (ks < 3) bvn = ldB(bt, (ks + 1) * 32);        // issue-early
      short8v a = frag_p(Af, r0, l, 136, ks * 32);
      u16* Bcur = (ks & 1) ? Bs1 : Bs0;
      __builtin_amdgcn_s_setprio(1);
#pragma unroll
      for (int j = 0; j < 8; ++j) MFMA(acc[j], a, frag(Bcur, j * 16, l));
      __builtin_amdgcn_s_setprio(0);
      if (ks < 3) stB((ks & 1) ? Bs0 : Bs1, bvn);       // write-late
      __syncthreads();
    }
  }
  // t1 -> LDS (bf16, relu+bias), pitch 132, overlays Af (all A reads done)
#pragma unroll
  for (int j = 0; j < 8; ++j) {
    int c = j * 16 + (l & 15);
    float bias = b1[c];
#pragma unroll
    for (int i = 0; i < 4; ++i) {
      int row = r0 + (l >> 4) * 4 + i;
      t1S[row * 132 + c] = f2b(fmaxf(acc[j][i] + bias, 0.f));
    }
  }
  stB(Bs0, ldB(W2T, 0));
  __syncthreads();

  // ===== phase 2: mlp2 (K=128), A = t1S persistent =====
#pragma unroll
  for (int j = 0; j < 8; ++j) acc[j] = z;
#pragma unroll
  for (int ks = 0; ks < 4; ++ks) {
    uint4 bvn;
    if (ks < 3) bvn = ldB(W2T, (ks + 1) * 32);
    short8v a = frag_p(t1S, r0, l, 132, ks * 32);
    u16* Bcur = (ks & 1) ? Bs1 : Bs0;
    __builtin_amdgcn_s_setprio(1);
#pragma unroll
    for (int j = 0; j < 8; ++j) MFMA(acc[j], a, frag(Bcur, j * 16, l));
    __builtin_amdgcn_s_setprio(0);
    if (ks < 3) stB((ks & 1) ? Bs0 : Bs1, bvn);
    __syncthreads();
  }

  // ===== epilogue: h16 += mlp2 + b2 (bf16 state) ; hmT =====
  float massv[4];
#pragma unroll
  for (int i = 0; i < 4; ++i) {
    int nl = r0 + (l >> 4) * 4 + i;
    massv[i] = (nl < valid) ? mass[gbase + n0 + nl] : 0.f;
  }
#pragma unroll
  for (int j = 0; j < 8; ++j) {
    int c = j * 16 + (l & 15);
    float bias = b2[c];
#pragma unroll
    for (int i = 0; i < 4; ++i) {
      int nl = r0 + (l >> 4) * 4 + i;
      float hv = 0.f;
      if (nl < valid) {
        size_t idx = (gbase + n0 + nl) * (size_t)CD + c;
        hv = b2f(h16[idx]) + acc[j][i] + bias;
        h16[idx] = f2b(hv);
      }
      if (writeHmT) Tm[c * 130 + nl] = f2b(hv * massv[i]);
    }
  }
  if (writeHmT) {
    __syncthreads();
#pragma unroll
    for (int q = 0; q < 4; ++q) {
      int lin = t + q * 512;            // 2048 chunks of 8 u16 (128c x 128n)
      int cc = lin >> 4, chunk = lin & 15;
      *(uint4*)&hmT[((size_t)(b * 128 + cc)) * NPGP + n0 + chunk * 8] =
          *(const uint4*)&Tm[cc * 130 + chunk * 8];
    }
  }
}

// ---- fused 2-layer head (bf16 MFMA): out = relu([h|gs]@Wh1+bh1)@Wh2+bh2 ----
__global__ __launch_bounds__(256) void k_head2(
    const u16* __restrict__ h16, const float* __restrict__ gs,
    const int* __restrict__ batch, const u16* __restrict__ B1T,
    const float* __restrict__ bh1, const u16* __restrict__ B2T,
    const float* __restrict__ bh2, float* __restrict__ out) {
  int n0 = blockIdx.x * 64;
  int t = threadIdx.x, w = t >> 6, l = t & 63;
  __shared__ u16 As[64 * 40];
  __shared__ u16 Bs[64 * 40];
  __shared__ u16 zS[64 * 72];
  int valid = min(64, NNODES - n0);
  f32x4 acc1[4];
  f32x4 z = {0.f, 0.f, 0.f, 0.f};
#pragma unroll
  for (int j = 0; j < 4; ++j) acc1[j] = z;
  for (int ks = 0; ks < 5; ++ks) {
    if (ks < 4) {
      stage64_b16(As, h16 + (size_t)n0 * CD, CD, ks * 32, valid);
    } else {
      int row = t >> 2, kq = t & 3;
      alignas(16) u16 tmp[8];
      int bb = (row < valid) ? batch[n0 + row] : 0;
#pragma unroll
      for (int q = 0; q < 8; ++q) {
        int kk = kq * 8 + q;
        float v = (row < valid && kk < GSDIM) ? gs[bb * GSDIM + kk] : 0.f;
        tmp[q] = f2b(v);
      }
      *(uint4*)&As[row * 40 + kq * 8] = *(uint4*)tmp;
    }
    stage64_b16(Bs, B1T, 160, ks * 32, 64);
    __syncthreads();
    short8v a = frag(As, w * 16, l);
#pragma unroll
    for (int j = 0; j < 4; ++j) MFMA(acc1[j], a, frag(Bs, j * 16, l));
    __syncthreads();
  }
#pragma unroll
  for (int j = 0; j < 4; ++j) {
    int c = j * 16 + (l & 15);
    float bias = bh1[c];
#pragma unroll
    for (int i = 0; i < 4; ++i) {
      int row = w * 16 + (l >> 4) * 4 + i;
      zS[row * 72 + c] = f2b(fmaxf(acc1[j][i] + bias, 0.f));
    }
  }
  __syncthreads();
  f32x4 acc2 = z;
  for (int ks = 0; ks < 2; ++ks) {
    stage64_b16(Bs, B2T, 64, ks * 32, 16);
    __syncthreads();
    short8v a2 = frag_p(zS, w * 16, l, 72, ks * 32);
    MFMA(acc2, a2, frag(Bs, 0, l));
    __syncthreads();
  }
  int c = l & 15;
  if (c < NCLF) {
    float bias = bh2[c];
#pragma unroll
    for (int i = 0; i < 4; ++i) {
      int n = n0 + w * 16 + (l >> 4) * 4 + i;
      if (n < NNODES) out[(size_t)n * NCLF + c] = acc2[i] + bias;
    }
  }
}

extern "C" void kernel_launch(void* const* d_in, const int* in_sizes, int n_in,
                              void* d_out, int out_size, void* d_ws, size_t ws_size,
                              hipStream_t stream) {
  const float* x     = (const float*)d_in[0];
  const float* evals = (const float*)d_in[1];
  const float* evecs = (const float*)d_in[2];
  const float* mass  = (const float*)d_in[3];
  const float* gs    = (const float*)d_in[4];
  const int*   batch = (const int*)d_in[5];
  const int*   grows = (const int*)d_in[6];
  const int*   gcols = (const int*)d_in[7];
  const float* vre   = (const float*)d_in[8];
  const float* vim   = (const float*)d_in[9];
  const float* Wemb  = (const float*)d_in[11];
  const float* bemb  = (const float*)d_in[12];
  const float* tdiff = (const float*)d_in[13];
  const float* Agrad = (const float*)d_in[14];
  const float* W1    = (const float*)d_in[15];
  const float* b1    = (const float*)d_in[16];
  const float* W2    = (const float*)d_in[17];
  const float* b2    = (const float*)d_in[18];
  const float* Wh1   = (const float*)d_in[19];
  const float* bh1   = (const float*)d_in[20];
  const float* Wh2   = (const float*)d_in[21];
  const float* bh2   = (const float*)d_in[22];

  char* base = (char*)d_ws;
  size_t off = 0;
  auto alloc = [&](size_t bytes) -> void* {
    void* p = base + off;
    off += (bytes + 255) & ~(size_t)255;
    return p;
  };
  u16*   evT16  = (u16*)alloc((size_t)NGRAPH * 128 * NPGP * 2);       // 26.2 MB
  u16*   hmT    = (u16*)alloc((size_t)NGRAPH * 128 * NPGP * 2);       // 26.2 MB
  u16*   Gre16  = (u16*)alloc((size_t)NNODES * KD * 2);               // 25.6 MB
  u16*   Gim16  = (u16*)alloc((size_t)NNODES * KD * 2);               // 25.6 MB
  u16*   h16    = (u16*)alloc((size_t)NNODES * CD * 2);               // 25.6 MB (sole h state)
  float* spec   = (float*)alloc((size_t)NGRAPH * 16384 * 4);
  u16*   specT16 = (u16*)alloc((size_t)NGRAPH * 16384 * 2);
  u16*   SAT16  = (u16*)alloc((size_t)NGRAPH * 16384 * 2);
  u16*   M1T16  = (u16*)alloc((size_t)NGRAPH * 16384 * 2);
  u16*   W1aT16 = (u16*)alloc((size_t)NBLKS * 16384 * 2);
  u16*   W1bT16 = (u16*)alloc((size_t)NBLKS * 16384 * 2);
  u16*   W1cT16 = (u16*)alloc((size_t)NBLKS * 16384 * 2);
  u16*   W2T16  = (u16*)alloc((size_t)NBLKS * 16384 * 2);
  u16*   B1T16  = (u16*)alloc(64 * 160 * 2);
  u16*   B2T16  = (u16*)alloc(16 * 64 * 2);
  int*   cnt    = (int*)alloc(100352 * 4);
  // R region (25.6 MB): bucket u64[N*32] / partials 21MB / gf16 25.6MB (disjoint liveness)
  void*  R      = alloc((size_t)NNODES * BCAP * 8);
  u64*   bucket = (u64*)R;
  float* partials = (float*)R;
  u16*   gf16   = (u16*)R;
  // bf16 evecs mirror (only if workspace allows)
  int useEv16 = 0;
  u16* ev16 = nullptr;
  if (off + ((size_t)NNODES * KD * 2 + 256) <= ws_size) {
    ev16 = (u16*)alloc((size_t)NNODES * KD * 2);                      // 25.6 MB
    useEv16 = 1;
  }
  float* out    = (float*)d_out;

  // ---- once per launch ----
  k_embed2<<<NGRAPH * 200, 256, 0, stream>>>(x, Wemb, bemb, mass, h16, hmT);
  k_fill0<<<98, 256, 0, stream>>>((float4*)cnt, 100352 / 4);
  k_bucket_place<<<(NEDGE + 255) / 256, 256, 0, stream>>>(grows, gcols, vre, vim,
                                                          cnt, bucket);
  k_transpose_nk<<<NGRAPH * 200, 256, 0, stream>>>(evecs, evT16, ev16, useEv16);
  k_gather_ev<<<NNODES / 2, 256, 0, stream>>>(cnt, bucket, evecs, ev16, useEv16,
                                              Gre16, Gim16);
  k_prep_w<<<1024, 256, 0, stream>>>(W1, W2, W1aT16, W1bT16, W1cT16, W2T16);
  k_prep_head<<<1, 256, 0, stream>>>(Wh1, Wh2, B1T16, B2T16);

  for (int blk = 0; blk < NBLKS; ++blk) {
    k_tobasis<<<NGRAPH * TBSPLIT * 2, 256, 0, stream>>>(evT16, hmT, partials);
    k_reduce_scale_t<<<NGRAPH * 64, 256, 0, stream>>>(partials, evals, tdiff + blk * CD,
                                                      spec, specT16);
    k_smallT<<<64, 256, 0, stream>>>(Agrad + (size_t)blk * 16384,
                                     W1bT16 + (size_t)blk * 16384, spec, SAT16, M1T16);
    k_gfeat<<<NGRAPH * NT32, 256, 0, stream>>>(Gre16, Gim16, specT16, SAT16, gf16);
    k_mlp12<<<NGRAPH * NT128, 512, 0, stream>>>(evecs, ev16, useEv16, gf16,
                                                W1aT16 + (size_t)blk * 16384, M1T16,
                                                W1cT16 + (size_t)blk * 16384,
                                                b1 + blk * CD,
                                                W2T16 + (size_t)blk * 16384,
                                                b2 + blk * CD, mass, h16, hmT,
                                                (blk < NBLKS - 1) ? 1 : 0);
  }
  k_head2<<<(NNODES + 63) / 64, 256, 0, stream>>>(h16, gs, batch, B1T16, bh1,
                                                  B2T16, bh2, out);
}

// Round 17
// 646.951 us; speedup vs baseline: 1.0561x; 1.0561x over previous
//
#include <hip/hip_runtime.h>
#include <hip/hip_bf16.h>

#define NNODES 100000
#define NPG    12500
#define NGRAPH 8
#define KD     128
#define CD     128
#define INDIM  7
#define GSDIM  11
#define NBLKS  4
#define NCLF   5
#define NEDGE  800000
#define BCAP   32             // packed u64 entries; Poisson(8) tail P(d>32) ~ 3e-6
#define NPGP   12800          // padded nodes per graph (40 * 320)
#define TBSPLIT 40            // to_basis split-n
#define TBCHUNK 320           // = NPGP / TBSPLIT, 10 k-steps of 32
#define NT32    391           // ceil(12500/32)
#define NT128   98            // ceil(12500/128)

typedef __attribute__((ext_vector_type(8))) short short8v;
typedef __attribute__((ext_vector_type(4))) float f32x4;
typedef unsigned short u16;
typedef unsigned long long u64;

#define MFMA(acc, a, b) acc = __builtin_amdgcn_mfma_f32_16x16x32_bf16(a, b, acc, 0, 0, 0)

__device__ __forceinline__ u16 f2b(float f) {
  union { __hip_bfloat16 h; u16 u; } cv;
  cv.h = __float2bfloat16(f);
  return cv.u;
}
__device__ __forceinline__ float b2f(u16 u) {
  return __uint_as_float((unsigned)u << 16);
}

// ---------- LDS staging helpers (tile layout: [rows][40] u16, 32 valid k) ----------

__device__ __forceinline__ void stage64_f32(u16* S, const float* src, int ld, int k0, int valid) {
  int t = threadIdx.x, row = t >> 2, kq = t & 3;
  alignas(16) u16 tmp[8] = {0, 0, 0, 0, 0, 0, 0, 0};
  if (row < valid) {
    const float* p = src + (size_t)row * ld + k0 + kq * 8;
    float4 f0 = *(const float4*)p, f1 = *(const float4*)(p + 4);
    tmp[0] = f2b(f0.x); tmp[1] = f2b(f0.y); tmp[2] = f2b(f0.z); tmp[3] = f2b(f0.w);
    tmp[4] = f2b(f1.x); tmp[5] = f2b(f1.y); tmp[6] = f2b(f1.z); tmp[7] = f2b(f1.w);
  }
  *(uint4*)&S[row * 40 + kq * 8] = *(uint4*)tmp;
}

__device__ __forceinline__ void stage64_b16(u16* S, const u16* src, long ld, int k0, int valid) {
  int t = threadIdx.x, row = t >> 2, kq = t & 3;
  uint4 v = make_uint4(0, 0, 0, 0);
  if (row < valid) v = *(const uint4*)(src + (size_t)row * ld + k0 + kq * 8);
  *(uint4*)&S[row * 40 + kq * 8] = v;
}

// 32-row variant: threads 0..127 stage a [32][40] tile
__device__ __forceinline__ void stage32_b16(u16* S, const u16* src, long ld, int k0, int valid) {
  int t = threadIdx.x;
  if (t < 128) {
    int row = t >> 2, kq = t & 3;
    uint4 v = make_uint4(0, 0, 0, 0);
    if (row < valid) v = *(const uint4*)(src + (size_t)row * ld + k0 + kq * 8);
    *(uint4*)&S[row * 40 + kq * 8] = v;
  }
}

__device__ __forceinline__ void stage128_b16(u16* S, const u16* src, long ld, int k0) {
  int t = threadIdx.x, row = t >> 1, half = t & 1;
  const u16* p = src + (size_t)row * ld + k0 + half * 16;
  uint4 v0 = *(const uint4*)p, v1 = *(const uint4*)(p + 8);
  *(uint4*)&S[row * 40 + half * 16] = v0;
  *(uint4*)&S[row * 40 + half * 16 + 8] = v1;
}

__device__ __forceinline__ void stage128_f32(u16* S, const float* src, int ld, int k0) {
  int t = threadIdx.x, row = t >> 1, half = t & 1;
  const float* p = src + (size_t)row * ld + k0 + half * 16;
  float4 f0 = *(const float4*)p, f1 = *(const float4*)(p + 4);
  float4 f2 = *(const float4*)(p + 8), f3 = *(const float4*)(p + 12);
  alignas(16) u16 tmp[16];
  tmp[0] = f2b(f0.x); tmp[1] = f2b(f0.y); tmp[2]  = f2b(f0.z); tmp[3]  = f2b(f0.w);
  tmp[4] = f2b(f1.x); tmp[5] = f2b(f1.y); tmp[6]  = f2b(f1.z); tmp[7]  = f2b(f1.w);
  tmp[8] = f2b(f2.x); tmp[9] = f2b(f2.y); tmp[10] = f2b(f2.z); tmp[11] = f2b(f2.w);
  tmp[12] = f2b(f3.x); tmp[13] = f2b(f3.y); tmp[14] = f2b(f3.z); tmp[15] = f2b(f3.w);
  *(uint4*)&S[row * 40 + half * 16] = *(uint4*)&tmp[0];
  *(uint4*)&S[row * 40 + half * 16 + 8] = *(uint4*)&tmp[8];
}

// full 128x128 A tile staged by 512 threads (pitch 136)
__device__ __forceinline__ void stageA_b16(u16* Af, const u16* src, long ld, int valid) {
  int t = threadIdx.x;
#pragma unroll
  for (int q = 0; q < 4; ++q) {
    int lin = t + q * 512;
    int row = lin >> 4, kq = lin & 15;
    uint4 v = make_uint4(0, 0, 0, 0);
    if (row < valid) v = *(const uint4*)(src + (size_t)row * ld + kq * 8);
    *(uint4*)&Af[row * 136 + kq * 8] = v;
  }
}
__device__ __forceinline__ void stageA_f32(u16* Af, const float* src, long ld, int valid) {
  int t = threadIdx.x;
#pragma unroll
  for (int q = 0; q < 4; ++q) {
    int lin = t + q * 512;
    int row = lin >> 4, kq = lin & 15;
    alignas(16) u16 tmp[8] = {0, 0, 0, 0, 0, 0, 0, 0};
    if (row < valid) {
      const float* p = src + (size_t)row * ld + kq * 8;
      float4 f0 = *(const float4*)p, f1 = *(const float4*)(p + 4);
      tmp[0] = f2b(f0.x); tmp[1] = f2b(f0.y); tmp[2] = f2b(f0.z); tmp[3] = f2b(f0.w);
      tmp[4] = f2b(f1.x); tmp[5] = f2b(f1.y); tmp[6] = f2b(f1.z); tmp[7] = f2b(f1.w);
    }
    *(uint4*)&Af[row * 136 + kq * 8] = *(uint4*)tmp;
  }
}

// B tile (128 rows x 32 k) load/store: 1 uint4 per thread at 512 threads
__device__ __forceinline__ uint4 ldB(const u16* bt, int k0) {
  int t = threadIdx.x, row = t >> 2, kq = t & 3;
  return *(const uint4*)(bt + (size_t)row * 128 + k0 + kq * 8);
}
__device__ __forceinline__ void stB(u16* Bs, uint4 v) {
  int t = threadIdx.x, row = t >> 2, kq = t & 3;
  *(uint4*)&Bs[row * 40 + kq * 8] = v;
}

__device__ __forceinline__ short8v frag(const u16* S, int row0, int l) {
  return *(const short8v*)&S[(row0 + (l & 15)) * 40 + (l >> 4) * 8];
}
__device__ __forceinline__ short8v frag_p(const u16* S, int row0, int l, int pitch, int k0) {
  return *(const short8v*)&S[(row0 + (l & 15)) * pitch + k0 + (l >> 4) * 8];
}

// ---------------------- utility kernels ----------------------

__global__ void k_fill0(float4* p, int n4) {
  int i = blockIdx.x * blockDim.x + threadIdx.x;
  int s = gridDim.x * blockDim.x;
  float4 z = make_float4(0.f, 0.f, 0.f, 0.f);
  for (; i < n4; i += s) p[i] = z;
}

// fused embed: h16 = bf16(relu(x@W+b)); hmT = mass-scaled transpose
__global__ __launch_bounds__(256) void k_embed2(const float* __restrict__ x,
                                                const float* __restrict__ W,
                                                const float* __restrict__ bv,
                                                const float* __restrict__ mass,
                                                u16* __restrict__ h16,
                                                u16* __restrict__ hmT) {
  int b = blockIdx.x / 200, tile = blockIdx.x % 200;
  int n0 = tile * 64;
  size_t gbase = (size_t)b * NPG;
  int t = threadIdx.x;
  __shared__ float xs[64][8];
  __shared__ float Ws[INDIM][128];
  __shared__ float bs[128];
  __shared__ float ms[64];
  __shared__ float ld[64][132];
  if (t < 128) bs[t] = bv[t];
  for (int i = t; i < INDIM * 128; i += 256) Ws[i >> 7][i & 127] = W[i];
  for (int i = t; i < 64 * INDIM; i += 256) {
    int r = i / INDIM, q = i % INDIM;
    int gn = n0 + r;
    xs[r][q] = (gn < NPG) ? x[(gbase + gn) * INDIM + q] : 0.f;
  }
  if (t < 64) {
    int gn = n0 + t;
    ms[t] = (gn < NPG) ? mass[gbase + gn] : 0.f;
  }
  __syncthreads();
  {
    int row = t & 63, c0 = (t >> 6) * 32;
#pragma unroll
    for (int cc = 0; cc < 32; ++cc) {
      int c = c0 + cc;
      float acc = bs[c];
#pragma unroll
      for (int i = 0; i < INDIM; ++i) acc = fmaf(xs[row][i], Ws[i][c], acc);
      ld[row][c] = fmaxf(acc, 0.f);
    }
  }
  __syncthreads();
  {
    int row = t >> 2, q = t & 3;
    if (n0 + row < NPG) {
      size_t base = (gbase + n0 + row) * (size_t)CD + q * 32;
      alignas(16) u16 tmp[8];
#pragma unroll
      for (int u = 0; u < 4; ++u) {
#pragma unroll
        for (int i = 0; i < 8; ++i) tmp[i] = f2b(ld[row][q * 32 + u * 8 + i]);
        *(uint4*)&h16[base + u * 8] = *(uint4*)tmp;
      }
    }
  }
  {
    int crow = t >> 1, half = t & 1;
    alignas(16) u16 tmp[8];
#pragma unroll
    for (int q = 0; q < 4; ++q) {
      int nb = half * 32 + q * 8;
#pragma unroll
      for (int i = 0; i < 8; ++i) tmp[i] = f2b(ld[nb + i][crow] * ms[nb + i]);
      *(uint4*)&hmT[((size_t)(b * 128 + crow)) * NPGP + n0 + nb] = *(uint4*)tmp;
    }
  }
}

// packed bucket: entry = col | bf16(vre)<<32 | bf16(vim)<<48
__global__ void k_bucket_place(const int* __restrict__ rows, const int* __restrict__ cols,
                               const float* __restrict__ vre, const float* __restrict__ vim,
                               int* cnt, u64* bucket) {
  int e = blockIdx.x * 256 + threadIdx.x;
  if (e >= NEDGE) return;
  int r = rows[e];
  int pos = atomicAdd(&cnt[r], 1);
  if (pos < BCAP) {
    u64 ent = (u64)(unsigned)cols[e]
            | ((u64)f2b(vre[e]) << 32)
            | ((u64)f2b(vim[e]) << 48);
    bucket[(size_t)r * BCAP + pos] = ent;
  }
}

// gather: one wave per row; packed entries; 2-way unroll; XCD-swizzled
__global__ void k_gather_ev(const int* __restrict__ cnt, const u64* __restrict__ bucket,
                            const float* __restrict__ evf, const u16* __restrict__ ev16,
                            int useB16,
                            u16* __restrict__ gre, u16* __restrict__ gim) {
  int orig = blockIdx.x;                       // 25000 = 8 * 3125
  int blk  = (orig & 7) * 3125 + (orig >> 3);  // graph (orig&7) -> XCD (orig&7)
  int wv = threadIdx.x >> 6;
  int ln = threadIdx.x & 63;
  int r  = blk * 4 + wv;
  int d = min(cnt[r], BCAP);
  const u64* bk = bucket + (size_t)r * BCAP;
  float2 ra0 = make_float2(0.f, 0.f), ia0 = make_float2(0.f, 0.f);
  float2 ra1 = make_float2(0.f, 0.f), ia1 = make_float2(0.f, 0.f);
  if (useB16) {
    int i = 0;
    for (; i + 2 <= d; i += 2) {
      u64 e0 = bk[i], e1 = bk[i + 1];
      int c0 = (int)(unsigned)e0, c1 = (int)(unsigned)e1;
      float a0 = b2f((u16)(e0 >> 32)), b0 = b2f((u16)(e0 >> 48));
      float a1 = b2f((u16)(e1 >> 32)), b1 = b2f((u16)(e1 >> 48));
      ushort2 u0 = *(const ushort2*)&ev16[(size_t)c0 * KD + ln * 2];
      ushort2 u1 = *(const ushort2*)&ev16[(size_t)c1 * KD + ln * 2];
      float vx0 = b2f(u0.x), vy0 = b2f(u0.y);
      float vx1 = b2f(u1.x), vy1 = b2f(u1.y);
      ra0.x = fmaf(a0, vx0, ra0.x); ra0.y = fmaf(a0, vy0, ra0.y);
      ia0.x = fmaf(b0, vx0, ia0.x); ia0.y = fmaf(b0, vy0, ia0.y);
      ra1.x = fmaf(a1, vx1, ra1.x); ra1.y = fmaf(a1, vy1, ra1.y);
      ia1.x = fmaf(b1, vx1, ia1.x); ia1.y = fmaf(b1, vy1, ia1.y);
    }
    if (i < d) {
      u64 e0 = bk[i];
      int c0 = (int)(unsigned)e0;
      float a0 = b2f((u16)(e0 >> 32)), b0 = b2f((u16)(e0 >> 48));
      ushort2 u0 = *(const ushort2*)&ev16[(size_t)c0 * KD + ln * 2];
      float vx0 = b2f(u0.x), vy0 = b2f(u0.y);
      ra0.x = fmaf(a0, vx0, ra0.x); ra0.y = fmaf(a0, vy0, ra0.y);
      ia0.x = fmaf(b0, vx0, ia0.x); ia0.y = fmaf(b0, vy0, ia0.y);
    }
  } else {
    for (int i = 0; i < d; ++i) {
      u64 e0 = bk[i];
      int c0 = (int)(unsigned)e0;
      float a = b2f((u16)(e0 >> 32)), b = b2f((u16)(e0 >> 48));
      float2 v = *(const float2*)&evf[(size_t)c0 * KD + ln * 2];
      ra0.x = fmaf(a, v.x, ra0.x); ra0.y = fmaf(a, v.y, ra0.y);
      ia0.x = fmaf(b, v.x, ia0.x); ia0.y = fmaf(b, v.y, ia0.y);
    }
  }
  ushort2 ro, io;
  ro.x = f2b(ra0.x + ra1.x); ro.y = f2b(ra0.y + ra1.y);
  io.x = f2b(ia0.x + ia1.x); io.y = f2b(ia0.y + ia1.y);
  *(ushort2*)&gre[(size_t)r * KD + ln * 2] = ro;
  *(ushort2*)&gim[(size_t)r * KD + ln * 2] = io;
}

// Transposed bf16 weights: W*T[c][j] = W[j][c]
__global__ void k_prep_w(const float* __restrict__ W1, const float* __restrict__ W2,
                         u16* W1aT, u16* W1bT, u16* W1cT, u16* W2T) {
  int idx = blockIdx.x * 256 + threadIdx.x;      // 4 * 4 * 16384
  int blk = idx >> 16, rem = idx & 65535;
  int mat = rem >> 14, e = rem & 16383;
  int j = e >> 7, c = e & 127;
  float v;
  u16* dst;
  if (mat < 3) {
    v = W1[(size_t)blk * 3 * 16384 + (size_t)mat * 16384 + e];
    dst = (mat == 0) ? W1aT : (mat == 1 ? W1bT : W1cT);
  } else {
    v = W2[(size_t)blk * 16384 + e];
    dst = W2T;
  }
  dst[(size_t)blk * 16384 + c * 128 + j] = f2b(v);
}

// head weights: B1T[c][k] (64 x 160, k<139 valid), B2T[c][k] (16 x 64, c<5 valid)
__global__ void k_prep_head(const float* __restrict__ Wh1, const float* __restrict__ Wh2,
                            u16* __restrict__ B1T, u16* __restrict__ B2T) {
  for (int idx = threadIdx.x; idx < 64 * 160; idx += 256) {
    int c = idx / 160, k = idx % 160;
    B1T[idx] = f2b(k < (CD + GSDIM) ? Wh1[k * 64 + c] : 0.f);
  }
  for (int idx = threadIdx.x; idx < 16 * 64; idx += 256) {
    int c = idx >> 6, k = idx & 63;
    B2T[idx] = f2b(c < NCLF ? Wh2[k * NCLF + c] : 0.f);
  }
}

// evT[b][k][n_pad] = evecs[n][k] bf16 ; also writes row-major ev16 mirror
__global__ void k_transpose_nk(const float* __restrict__ src, u16* __restrict__ dst,
                               u16* __restrict__ ev16, int writeMir) {
  int b = blockIdx.x / 200, tile = blockIdx.x % 200;
  int n0 = tile * 64;
  size_t gbase = (size_t)b * NPG;
  int t = threadIdx.x;
  __shared__ float ld[64][132];
  int row0 = t >> 5, c4 = t & 31;
#pragma unroll
  for (int it = 0; it < 8; ++it) {
    int r = it * 8 + row0;
    int gn = n0 + r;
    float4 v = make_float4(0.f, 0.f, 0.f, 0.f);
    if (gn < NPG) v = *(const float4*)&src[(gbase + gn) * KD + c4 * 4];
    *(float4*)&ld[r][c4 * 4] = v;
    if (writeMir && gn < NPG) {
      ushort4 o;
      o.x = f2b(v.x); o.y = f2b(v.y); o.z = f2b(v.z); o.w = f2b(v.w);
      *(ushort4*)&ev16[(gbase + gn) * KD + c4 * 4] = o;
    }
  }
  __syncthreads();
  int crow = t >> 1, half = t & 1;
  alignas(16) u16 tmp[8];
#pragma unroll
  for (int q = 0; q < 4; ++q) {
    int nb = half * 32 + q * 8;
#pragma unroll
    for (int i = 0; i < 8; ++i) tmp[i] = f2b(ld[nb + i][crow]);
    *(uint4*)&dst[((size_t)(b * 128 + crow)) * NPGP + n0 + nb] = *(uint4*)tmp;
  }
}

// ---------------------- MFMA kernels ----------------------

// partials[(b*TBSPLIT+s)][kt*64+k][c] = sum_{n in chunk} evT[b][kt*64+k][n]*hmT[b][c][n]
__global__ __launch_bounds__(256) void k_tobasis(const u16* __restrict__ evT,
                                                 const u16* __restrict__ hmT,
                                                 float* __restrict__ partials) {
  int g = blockIdx.x;
  int kt = g & 1;
  int s  = (g >> 1) % TBSPLIT;
  int b  = g / (2 * TBSPLIT);
  int t = threadIdx.x, w = t >> 6, l = t & 63;
  __shared__ u16 As[64 * 40];
  __shared__ u16 Bs[128 * 40];
  f32x4 acc[8];
  f32x4 z = {0.f, 0.f, 0.f, 0.f};
#pragma unroll
  for (int j = 0; j < 8; ++j) acc[j] = z;
  const u16* ae = evT + ((size_t)(b * 128 + kt * 64)) * NPGP + s * TBCHUNK;
  const u16* bh = hmT + (size_t)b * 128 * NPGP + s * TBCHUNK;
  for (int ks = 0; ks < TBCHUNK / 32; ++ks) {
    stage64_b16(As, ae, NPGP, ks * 32, 64);
    stage128_b16(Bs, bh, NPGP, ks * 32);
    __syncthreads();
    short8v a = frag(As, w * 16, l);
    __builtin_amdgcn_s_setprio(1);
#pragma unroll
    for (int j = 0; j < 8; ++j) MFMA(acc[j], a, frag(Bs, j * 16, l));
    __builtin_amdgcn_s_setprio(0);
    __syncthreads();
  }
  float* op = partials + (size_t)(b * TBSPLIT + s) * 16384 + kt * 64 * 128;
#pragma unroll
  for (int j = 0; j < 8; ++j)
#pragma unroll
    for (int i = 0; i < 4; ++i) {
      int krow = w * 16 + (l >> 4) * 4 + i;
      int c = j * 16 + (l & 15);
      op[krow * 128 + c] = acc[j][i];
    }
}

// spec[b][k][c] = scale(sum_s partials); specT16[b][c][k] = bf16(spec)
__global__ void k_reduce_scale_t(const float* __restrict__ partials,
                                 const float* __restrict__ evals,
                                 const float* __restrict__ td,
                                 float* __restrict__ spec, u16* __restrict__ specT) {
  int b = blockIdx.x >> 6;
  int idx = (blockIdx.x & 63) * 256 + threadIdx.x;
  int k = idx >> 7, c = idx & 127;
  float s = 0.f;
#pragma unroll 8
  for (int sp = 0; sp < TBSPLIT; ++sp)
    s += partials[(size_t)(b * TBSPLIT + sp) * 16384 + idx];
  float tm = fmaxf(fabsf(td[c]), 1e-8f);
  s *= expf(-evals[b * KD + k] * tm);
  spec[(size_t)b * 16384 + idx] = s;
  specT[(size_t)b * 16384 + c * 128 + k] = f2b(s);
}

// job0: SAT16[b][c][k] = sum_j Agrad[c][j]*spec[b][k][j]
// job1: M1T16[b][c][k] = sum_j W1bT[c][j]*spec[b][k][j]
__global__ __launch_bounds__(256) void k_smallT(const float* __restrict__ Agrad_blk,
                                                const u16* __restrict__ W1bT_blk,
                                                const float* __restrict__ spec,
                                                u16* __restrict__ SAT, u16* __restrict__ M1T) {
  int b = blockIdx.x & 7;
  int job = (blockIdx.x >> 3) & 1;
  int q = blockIdx.x >> 4;                 // 0..3: c-row quarter
  int t = threadIdx.x, w = t >> 6, l = t & 63;
  __shared__ u16 As[128 * 40];
  __shared__ u16 Bs[128 * 40];
  f32x4 acc[2][2];
  f32x4 z = {0.f, 0.f, 0.f, 0.f};
#pragma unroll
  for (int mi = 0; mi < 2; ++mi) { acc[mi][0] = z; acc[mi][1] = z; }
  for (int ks = 0; ks < 4; ++ks) {
    if (job == 0) stage128_f32(As, Agrad_blk, 128, ks * 32);
    else          stage128_b16(As, W1bT_blk, 128, ks * 32);
    stage128_f32(Bs, spec + (size_t)b * 16384, 128, ks * 32);
    __syncthreads();
    short8v a0 = frag(As, q * 32, l);
    short8v a1 = frag(As, q * 32 + 16, l);
#pragma unroll
    for (int jj = 0; jj < 2; ++jj) {
      short8v bj = frag(Bs, (w * 2 + jj) * 16, l);
      MFMA(acc[0][jj], a0, bj);
      MFMA(acc[1][jj], a1, bj);
    }
    __syncthreads();
  }
  u16* out = (job == 0 ? SAT : M1T) + (size_t)b * 16384;
#pragma unroll
  for (int mi = 0; mi < 2; ++mi)
#pragma unroll
    for (int jj = 0; jj < 2; ++jj)
#pragma unroll
      for (int i = 0; i < 4; ++i)
        out[(q * 32 + mi * 16 + (l >> 4) * 4 + i) * 128 + (w * 2 + jj) * 16 + (l & 15)] =
            f2b(acc[mi][jj][i]);
}

// gf16 = tanh((Gre@spec')*(Gre@SA) + (Gim@spec')*(Gim@SA))   [bf16 out]
__global__ __launch_bounds__(256) void k_gfeat(const u16* __restrict__ Gre,
                                               const u16* __restrict__ Gim,
                                               const u16* __restrict__ specT,
                                               const u16* __restrict__ SAT,
                                               u16* __restrict__ gf) {
  int b = blockIdx.x / NT32, tile = blockIdx.x % NT32;
  int n0 = tile * 32;
  size_t gbase = (size_t)b * NPG;
  int t = threadIdx.x, w = t >> 6, l = t & 63;
  int r0 = (w & 1) * 16, c0 = (w >> 1) * 64;
  __shared__ u16 Sr[32 * 40];
  __shared__ u16 Si[32 * 40];
  __shared__ u16 Bs[128 * 40];
  __shared__ u16 Ba[128 * 40];
  f32x4 aGR[4], aAR[4], aGI[4], aAI[4];
  f32x4 z = {0.f, 0.f, 0.f, 0.f};
#pragma unroll
  for (int j = 0; j < 4; ++j) { aGR[j] = z; aAR[j] = z; aGI[j] = z; aAI[j] = z; }
  int valid = min(32, NPG - n0);
  const u16* gre = Gre + (gbase + n0) * KD;
  const u16* gim = Gim + (gbase + n0) * KD;
  for (int ks = 0; ks < 4; ++ks) {
    stage32_b16(Sr, gre, KD, ks * 32, valid);
    stage32_b16(Si, gim, KD, ks * 32, valid);
    stage128_b16(Bs, specT + (size_t)b * 16384, 128, ks * 32);
    stage128_b16(Ba, SAT + (size_t)b * 16384, 128, ks * 32);
    __syncthreads();
    short8v fr = frag(Sr, r0, l);
    short8v fi = frag(Si, r0, l);
    __builtin_amdgcn_s_setprio(1);
#pragma unroll
    for (int j = 0; j < 4; ++j) {
      short8v bs = frag(Bs, c0 + j * 16, l);
      short8v ba = frag(Ba, c0 + j * 16, l);
      MFMA(aGR[j], fr, bs);
      MFMA(aAR[j], fr, ba);
      MFMA(aGI[j], fi, bs);
      MFMA(aAI[j], fi, ba);
    }
    __builtin_amdgcn_s_setprio(0);
    __syncthreads();
  }
#pragma unroll
  for (int j = 0; j < 4; ++j) {
    int c = c0 + j * 16 + (l & 15);
#pragma unroll
    for (int i = 0; i < 4; ++i) {
      int n = n0 + r0 + (l >> 4) * 4 + i;
      if (n - n0 < valid) {
        float v = tanhf(fmaf(aGR[j][i], aAR[j][i], aGI[j][i] * aAI[j][i]));
        gf[(gbase + n) * CD + c] = f2b(v);
      }
    }
  }
}

// ---- fused mlp1+mlp2, 512 threads / 128-row tiles; persistent-A + dbuf-B ----
__global__ __launch_bounds__(512) void k_mlp12(const float* __restrict__ evf,
                                               const u16* __restrict__ ev16,
                                               int useB16,
                                               const u16* __restrict__ gf,
                                               const u16* __restrict__ W1aT,
                                               const u16* __restrict__ M1T,
                                               const u16* __restrict__ W1cT,
                                               const float* __restrict__ b1,
                                               const u16* __restrict__ W2T,
                                               const float* __restrict__ b2,
                                               const float* __restrict__ mass,
                                               u16* __restrict__ h16,
                                               u16* __restrict__ hmT,
                                               int writeHmT) {
  int b = blockIdx.x / NT128, tile = blockIdx.x % NT128;
  int n0 = tile * 128;
  size_t gbase = (size_t)b * NPG;
  int t = threadIdx.x, w = t >> 6, l = t & 63;     // 8 waves
  __shared__ u16 SH[27648];
  u16* Af  = SH;
  u16* t1S = SH;
  u16* Tm  = SH;
  u16* Bs0 = SH + 17408;
  u16* Bs1 = SH + 22528;
  f32x4 acc[8];
  f32x4 z = {0.f, 0.f, 0.f, 0.f};
#pragma unroll
  for (int j = 0; j < 8; ++j) acc[j] = z;
  int valid = min(128, NPG - n0);
  int r0 = w * 16;                    // wave's row block

  // ===== phase 1: mlp1 (3 segments of K=128), persistent A per segment =====
  for (int seg = 0; seg < 3; ++seg) {
    const u16* bt = (seg == 0) ? W1aT : (seg == 1 ? M1T + (size_t)b * 16384 : W1cT);
    if (seg == 0)      stageA_b16(Af, h16 + (gbase + n0) * CD, CD, valid);
    else if (seg == 1) {
      if (useB16) stageA_b16(Af, ev16 + (gbase + n0) * KD, KD, valid);
      else        stageA_f32(Af, evf + (gbase + n0) * KD, KD, valid);
    }
    else               stageA_b16(Af, gf + (gbase + n0) * CD, CD, valid);
    stB(Bs0, ldB(bt, 0));
    __syncthreads();
#pragma unroll
    for (int ks = 0; ks < 4; ++ks) {
      uint4 bvn;
      if (ks < 3) bvn = ldB(bt, (ks + 1) * 32);        // issue-early
      short8v a = frag_p(Af, r0, l, 136, ks * 32);
      u16* Bcur = (ks & 1) ? Bs1 : Bs0;
      __builtin_amdgcn_s_setprio(1);
#pragma unroll
      for (int j = 0; j < 8; ++j) MFMA(acc[j], a, frag(Bcur, j * 16, l));
      __builtin_amdgcn_s_setprio(0);
      if (ks < 3) stB((ks & 1) ? Bs0 : Bs1, bvn);       // write-late
      __syncthreads();
    }
  }
  // t1 -> LDS (bf16, relu+bias), pitch 132, overlays Af (all A reads done)
#pragma unroll
  for (int j = 0; j < 8; ++j) {
    int c = j * 16 + (l & 15);
    float bias = b1[c];
#pragma unroll
    for (int i = 0; i < 4; ++i) {
      int row = r0 + (l >> 4) * 4 + i;
      t1S[row * 132 + c] = f2b(fmaxf(acc[j][i] + bias, 0.f));
    }
  }
  stB(Bs0, ldB(W2T, 0));
  __syncthreads();

  // ===== phase 2: mlp2 (K=128), A = t1S persistent =====
#pragma unroll
  for (int j = 0; j < 8; ++j) acc[j] = z;
#pragma unroll
  for (int ks = 0; ks < 4; ++ks) {
    uint4 bvn;
    if (ks < 3) bvn = ldB(W2T, (ks + 1) * 32);
    short8v a = frag_p(t1S, r0, l, 132, ks * 32);
    u16* Bcur = (ks & 1) ? Bs1 : Bs0;
    __builtin_amdgcn_s_setprio(1);
#pragma unroll
    for (int j = 0; j < 8; ++j) MFMA(acc[j], a, frag(Bcur, j * 16, l));
    __builtin_amdgcn_s_setprio(0);
    if (ks < 3) stB((ks & 1) ? Bs0 : Bs1, bvn);
    __syncthreads();
  }

  // ===== epilogue: h16 += mlp2 + b2 (bf16 state) ; hmT =====
  float massv[4];
#pragma unroll
  for (int i = 0; i < 4; ++i) {
    int nl = r0 + (l >> 4) * 4 + i;
    massv[i] = (nl < valid) ? mass[gbase + n0 + nl] : 0.f;
  }
#pragma unroll
  for (int j = 0; j < 8; ++j) {
    int c = j * 16 + (l & 15);
    float bias = b2[c];
#pragma unroll
    for (int i = 0; i < 4; ++i) {
      int nl = r0 + (l >> 4) * 4 + i;
      float hv = 0.f;
      if (nl < valid) {
        size_t idx = (gbase + n0 + nl) * (size_t)CD + c;
        hv = b2f(h16[idx]) + acc[j][i] + bias;
        h16[idx] = f2b(hv);
      }
      if (writeHmT) Tm[c * 130 + nl] = f2b(hv * massv[i]);
    }
  }
  if (writeHmT) {
    __syncthreads();
#pragma unroll
    for (int q = 0; q < 4; ++q) {
      int lin = t + q * 512;            // 2048 chunks of 8 u16 (128c x 128n)
      int cc = lin >> 4, chunk = lin & 15;
      *(uint4*)&hmT[((size_t)(b * 128 + cc)) * NPGP + n0 + chunk * 8] =
          *(const uint4*)&Tm[cc * 130 + chunk * 8];
    }
  }
}

// ---- fused 2-layer head (bf16 MFMA): out = relu([h|gs]@Wh1+bh1)@Wh2+bh2 ----
__global__ __launch_bounds__(256) void k_head2(
    const u16* __restrict__ h16, const float* __restrict__ gs,
    const int* __restrict__ batch, const u16* __restrict__ B1T,
    const float* __restrict__ bh1, const u16* __restrict__ B2T,
    const float* __restrict__ bh2, float* __restrict__ out) {
  int n0 = blockIdx.x * 64;
  int t = threadIdx.x, w = t >> 6, l = t & 63;
  __shared__ u16 As[64 * 40];
  __shared__ u16 Bs[64 * 40];
  __shared__ u16 zS[64 * 72];
  int valid = min(64, NNODES - n0);
  f32x4 acc1[4];
  f32x4 z = {0.f, 0.f, 0.f, 0.f};
#pragma unroll
  for (int j = 0; j < 4; ++j) acc1[j] = z;
  for (int ks = 0; ks < 5; ++ks) {
    if (ks < 4) {
      stage64_b16(As, h16 + (size_t)n0 * CD, CD, ks * 32, valid);
    } else {
      int row = t >> 2, kq = t & 3;
      alignas(16) u16 tmp[8];
      int bb = (row < valid) ? batch[n0 + row] : 0;
#pragma unroll
      for (int q = 0; q < 8; ++q) {
        int kk = kq * 8 + q;
        float v = (row < valid && kk < GSDIM) ? gs[bb * GSDIM + kk] : 0.f;
        tmp[q] = f2b(v);
      }
      *(uint4*)&As[row * 40 + kq * 8] = *(uint4*)tmp;
    }
    stage64_b16(Bs, B1T, 160, ks * 32, 64);
    __syncthreads();
    short8v a = frag(As, w * 16, l);
#pragma unroll
    for (int j = 0; j < 4; ++j) MFMA(acc1[j], a, frag(Bs, j * 16, l));
    __syncthreads();
  }
#pragma unroll
  for (int j = 0; j < 4; ++j) {
    int c = j * 16 + (l & 15);
    float bias = bh1[c];
#pragma unroll
    for (int i = 0; i < 4; ++i) {
      int row = w * 16 + (l >> 4) * 4 + i;
      zS[row * 72 + c] = f2b(fmaxf(acc1[j][i] + bias, 0.f));
    }
  }
  __syncthreads();
  f32x4 acc2 = z;
  for (int ks = 0; ks < 2; ++ks) {
    stage64_b16(Bs, B2T, 64, ks * 32, 16);
    __syncthreads();
    short8v a2 = frag_p(zS, w * 16, l, 72, ks * 32);
    MFMA(acc2, a2, frag(Bs, 0, l));
    __syncthreads();
  }
  int c = l & 15;
  if (c < NCLF) {
    float bias = bh2[c];
#pragma unroll
    for (int i = 0; i < 4; ++i) {
      int n = n0 + w * 16 + (l >> 4) * 4 + i;
      if (n < NNODES) out[(size_t)n * NCLF + c] = acc2[i] + bias;
    }
  }
}

extern "C" void kernel_launch(void* const* d_in, const int* in_sizes, int n_in,
                              void* d_out, int out_size, void* d_ws, size_t ws_size,
                              hipStream_t stream) {
  const float* x     = (const float*)d_in[0];
  const float* evals = (const float*)d_in[1];
  const float* evecs = (const float*)d_in[2];
  const float* mass  = (const float*)d_in[3];
  const float* gs    = (const float*)d_in[4];
  const int*   batch = (const int*)d_in[5];
  const int*   grows = (const int*)d_in[6];
  const int*   gcols = (const int*)d_in[7];
  const float* vre   = (const float*)d_in[8];
  const float* vim   = (const float*)d_in[9];
  const float* Wemb  = (const float*)d_in[11];
  const float* bemb  = (const float*)d_in[12];
  const float* tdiff = (const float*)d_in[13];
  const float* Agrad = (const float*)d_in[14];
  const float* W1    = (const float*)d_in[15];
  const float* b1    = (const float*)d_in[16];
  const float* W2    = (const float*)d_in[17];
  const float* b2    = (const float*)d_in[18];
  const float* Wh1   = (const float*)d_in[19];
  const float* bh1   = (const float*)d_in[20];
  const float* Wh2   = (const float*)d_in[21];
  const float* bh2   = (const float*)d_in[22];

  char* base = (char*)d_ws;
  size_t off = 0;
  auto alloc = [&](size_t bytes) -> void* {
    void* p = base + off;
    off += (bytes + 255) & ~(size_t)255;
    return p;
  };
  u16*   evT16  = (u16*)alloc((size_t)NGRAPH * 128 * NPGP * 2);       // 26.2 MB
  u16*   hmT    = (u16*)alloc((size_t)NGRAPH * 128 * NPGP * 2);       // 26.2 MB
  u16*   Gre16  = (u16*)alloc((size_t)NNODES * KD * 2);               // 25.6 MB
  u16*   Gim16  = (u16*)alloc((size_t)NNODES * KD * 2);               // 25.6 MB
  u16*   h16    = (u16*)alloc((size_t)NNODES * CD * 2);               // 25.6 MB (sole h state)
  float* spec   = (float*)alloc((size_t)NGRAPH * 16384 * 4);
  u16*   specT16 = (u16*)alloc((size_t)NGRAPH * 16384 * 2);
  u16*   SAT16  = (u16*)alloc((size_t)NGRAPH * 16384 * 2);
  u16*   M1T16  = (u16*)alloc((size_t)NGRAPH * 16384 * 2);
  u16*   W1aT16 = (u16*)alloc((size_t)NBLKS * 16384 * 2);
  u16*   W1bT16 = (u16*)alloc((size_t)NBLKS * 16384 * 2);
  u16*   W1cT16 = (u16*)alloc((size_t)NBLKS * 16384 * 2);
  u16*   W2T16  = (u16*)alloc((size_t)NBLKS * 16384 * 2);
  u16*   B1T16  = (u16*)alloc(64 * 160 * 2);
  u16*   B2T16  = (u16*)alloc(16 * 64 * 2);
  int*   cnt    = (int*)alloc(100352 * 4);
  // R region (25.6 MB): bucket u64[N*32] / partials 21MB / gf16 25.6MB (disjoint liveness)
  void*  R      = alloc((size_t)NNODES * BCAP * 8);
  u64*   bucket = (u64*)R;
  float* partials = (float*)R;
  u16*   gf16   = (u16*)R;
  // bf16 evecs mirror (only if workspace allows)
  int useEv16 = 0;
  u16* ev16 = nullptr;
  if (off + ((size_t)NNODES * KD * 2 + 256) <= ws_size) {
    ev16 = (u16*)alloc((size_t)NNODES * KD * 2);                      // 25.6 MB
    useEv16 = 1;
  }
  float* out    = (float*)d_out;

  // ---- once per launch ----
  k_embed2<<<NGRAPH * 200, 256, 0, stream>>>(x, Wemb, bemb, mass, h16, hmT);
  k_fill0<<<98, 256, 0, stream>>>((float4*)cnt, 100352 / 4);
  k_bucket_place<<<(NEDGE + 255) / 256, 256, 0, stream>>>(grows, gcols, vre, vim,
                                                          cnt, bucket);
  k_transpose_nk<<<NGRAPH * 200, 256, 0, stream>>>(evecs, evT16, ev16, useEv16);
  k_gather_ev<<<NNODES / 4, 256, 0, stream>>>(cnt, bucket, evecs, ev16, useEv16,
                                              Gre16, Gim16);
  k_prep_w<<<1024, 256, 0, stream>>>(W1, W2, W1aT16, W1bT16, W1cT16, W2T16);
  k_prep_head<<<1, 256, 0, stream>>>(Wh1, Wh2, B1T16, B2T16);

  for (int blk = 0; blk < NBLKS; ++blk) {
    k_tobasis<<<NGRAPH * TBSPLIT * 2, 256, 0, stream>>>(evT16, hmT, partials);
    k_reduce_scale_t<<<NGRAPH * 64, 256, 0, stream>>>(partials, evals, tdiff + blk * CD,
                                                      spec, specT16);
    k_smallT<<<64, 256, 0, stream>>>(Agrad + (size_t)blk * 16384,
                                     W1bT16 + (size_t)blk * 16384, spec, SAT16, M1T16);
    k_gfeat<<<NGRAPH * NT32, 256, 0, stream>>>(Gre16, Gim16, specT16, SAT16, gf16);
    k_mlp12<<<NGRAPH * NT128, 512, 0, stream>>>(evecs, ev16, useEv16, gf16,
                                                W1aT16 + (size_t)blk * 16384, M1T16,
                                                W1cT16 + (size_t)blk * 16384,
                                                b1 + blk * CD,
                                                W2T16 + (size_t)blk * 16384,
                                                b2 + blk * CD, mass, h16, hmT,
                                                (blk < NBLKS - 1) ? 1 : 0);
  }
  k_head2<<<(NNODES + 63) / 64, 256, 0, stream>>>(h16, gs, batch, B1T16, bh1,
                                                  B2T16, bh2, out);
}

// Round 18
// 640.224 us; speedup vs baseline: 1.0672x; 1.0105x over previous
//
#include <hip/hip_runtime.h>
#include <hip/hip_bf16.h>

#define NNODES 100000
#define NPG    12500
#define NGRAPH 8
#define KD     128
#define CD     128
#define INDIM  7
#define GSDIM  11
#define NBLKS  4
#define NCLF   5
#define NEDGE  800000
#define BCAP   32             // packed u64 entries; Poisson(8) tail P(d>32) ~ 3e-6
#define NPGP   12800          // padded nodes per graph (40 * 320)
#define TBSPLIT 40            // to_basis split-n
#define TBCHUNK 320           // = NPGP / TBSPLIT, 10 k-steps of 32
#define NT32    391           // ceil(12500/32)
#define NT128   98            // ceil(12500/128)

typedef __attribute__((ext_vector_type(8))) short short8v;
typedef __attribute__((ext_vector_type(4))) float f32x4;
typedef unsigned short u16;
typedef unsigned long long u64;

#define MFMA(acc, a, b) acc = __builtin_amdgcn_mfma_f32_16x16x32_bf16(a, b, acc, 0, 0, 0)

__device__ __forceinline__ u16 f2b(float f) {
  union { __hip_bfloat16 h; u16 u; } cv;
  cv.h = __float2bfloat16(f);
  return cv.u;
}
__device__ __forceinline__ float b2f(u16 u) {
  return __uint_as_float((unsigned)u << 16);
}

// ---------- LDS staging helpers (tile layout: [rows][40] u16, 32 valid k) ----------

__device__ __forceinline__ void stage64_f32(u16* S, const float* src, int ld, int k0, int valid) {
  int t = threadIdx.x, row = t >> 2, kq = t & 3;
  alignas(16) u16 tmp[8] = {0, 0, 0, 0, 0, 0, 0, 0};
  if (row < valid) {
    const float* p = src + (size_t)row * ld + k0 + kq * 8;
    float4 f0 = *(const float4*)p, f1 = *(const float4*)(p + 4);
    tmp[0] = f2b(f0.x); tmp[1] = f2b(f0.y); tmp[2] = f2b(f0.z); tmp[3] = f2b(f0.w);
    tmp[4] = f2b(f1.x); tmp[5] = f2b(f1.y); tmp[6] = f2b(f1.z); tmp[7] = f2b(f1.w);
  }
  *(uint4*)&S[row * 40 + kq * 8] = *(uint4*)tmp;
}

__device__ __forceinline__ void stage64_b16(u16* S, const u16* src, long ld, int k0, int valid) {
  int t = threadIdx.x, row = t >> 2, kq = t & 3;
  uint4 v = make_uint4(0, 0, 0, 0);
  if (row < valid) v = *(const uint4*)(src + (size_t)row * ld + k0 + kq * 8);
  *(uint4*)&S[row * 40 + kq * 8] = v;
}

// 32-row variant: threads 0..127 stage a [32][40] tile
__device__ __forceinline__ void stage32_b16(u16* S, const u16* src, long ld, int k0, int valid) {
  int t = threadIdx.x;
  if (t < 128) {
    int row = t >> 2, kq = t & 3;
    uint4 v = make_uint4(0, 0, 0, 0);
    if (row < valid) v = *(const uint4*)(src + (size_t)row * ld + k0 + kq * 8);
    *(uint4*)&S[row * 40 + kq * 8] = v;
  }
}

__device__ __forceinline__ void stage128_b16(u16* S, const u16* src, long ld, int k0) {
  int t = threadIdx.x, row = t >> 1, half = t & 1;
  const u16* p = src + (size_t)row * ld + k0 + half * 16;
  uint4 v0 = *(const uint4*)p, v1 = *(const uint4*)(p + 8);
  *(uint4*)&S[row * 40 + half * 16] = v0;
  *(uint4*)&S[row * 40 + half * 16 + 8] = v1;
}

__device__ __forceinline__ void stage128_f32(u16* S, const float* src, int ld, int k0) {
  int t = threadIdx.x, row = t >> 1, half = t & 1;
  const float* p = src + (size_t)row * ld + k0 + half * 16;
  float4 f0 = *(const float4*)p, f1 = *(const float4*)(p + 4);
  float4 f2 = *(const float4*)(p + 8), f3 = *(const float4*)(p + 12);
  alignas(16) u16 tmp[16];
  tmp[0] = f2b(f0.x); tmp[1] = f2b(f0.y); tmp[2]  = f2b(f0.z); tmp[3]  = f2b(f0.w);
  tmp[4] = f2b(f1.x); tmp[5] = f2b(f1.y); tmp[6]  = f2b(f1.z); tmp[7]  = f2b(f1.w);
  tmp[8] = f2b(f2.x); tmp[9] = f2b(f2.y); tmp[10] = f2b(f2.z); tmp[11] = f2b(f2.w);
  tmp[12] = f2b(f3.x); tmp[13] = f2b(f3.y); tmp[14] = f2b(f3.z); tmp[15] = f2b(f3.w);
  *(uint4*)&S[row * 40 + half * 16] = *(uint4*)&tmp[0];
  *(uint4*)&S[row * 40 + half * 16 + 8] = *(uint4*)&tmp[8];
}

// full 128x128 A tile staged by 512 threads (pitch 136)
__device__ __forceinline__ void stageA_b16(u16* Af, const u16* src, long ld, int valid) {
  int t = threadIdx.x;
#pragma unroll
  for (int q = 0; q < 4; ++q) {
    int lin = t + q * 512;
    int row = lin >> 4, kq = lin & 15;
    uint4 v = make_uint4(0, 0, 0, 0);
    if (row < valid) v = *(const uint4*)(src + (size_t)row * ld + kq * 8);
    *(uint4*)&Af[row * 136 + kq * 8] = v;
  }
}
__device__ __forceinline__ void stageA_f32(u16* Af, const float* src, long ld, int valid) {
  int t = threadIdx.x;
#pragma unroll
  for (int q = 0; q < 4; ++q) {
    int lin = t + q * 512;
    int row = lin >> 4, kq = lin & 15;
    alignas(16) u16 tmp[8] = {0, 0, 0, 0, 0, 0, 0, 0};
    if (row < valid) {
      const float* p = src + (size_t)row * ld + kq * 8;
      float4 f0 = *(const float4*)p, f1 = *(const float4*)(p + 4);
      tmp[0] = f2b(f0.x); tmp[1] = f2b(f0.y); tmp[2] = f2b(f0.z); tmp[3] = f2b(f0.w);
      tmp[4] = f2b(f1.x); tmp[5] = f2b(f1.y); tmp[6] = f2b(f1.z); tmp[7] = f2b(f1.w);
    }
    *(uint4*)&Af[row * 136 + kq * 8] = *(uint4*)tmp;
  }
}

// B tile (128 rows x 32 k) load/store: 1 uint4 per thread at 512 threads
__device__ __forceinline__ uint4 ldB(const u16* bt, int k0) {
  int t = threadIdx.x, row = t >> 2, kq = t & 3;
  return *(const uint4*)(bt + (size_t)row * 128 + k0 + kq * 8);
}
__device__ __forceinline__ void stB(u16* Bs, uint4 v) {
  int t = threadIdx.x, row = t >> 2, kq = t & 3;
  *(uint4*)&Bs[row * 40 + kq * 8] = v;
}

__device__ __forceinline__ short8v frag(const u16* S, int row0, int l) {
  return *(const short8v*)&S[(row0 + (l & 15)) * 40 + (l >> 4) * 8];
}
__device__ __forceinline__ short8v frag_p(const u16* S, int row0, int l, int pitch, int k0) {
  return *(const short8v*)&S[(row0 + (l & 15)) * pitch + k0 + (l >> 4) * 8];
}

// ---------------------- utility kernels ----------------------

__global__ void k_fill0(float4* p, int n4) {
  int i = blockIdx.x * blockDim.x + threadIdx.x;
  int s = gridDim.x * blockDim.x;
  float4 z = make_float4(0.f, 0.f, 0.f, 0.f);
  for (; i < n4; i += s) p[i] = z;
}

// fused embed: h16 = bf16(relu(x@W+b)); hT = plain transpose (mass folded into evT)
__global__ __launch_bounds__(256) void k_embed2(const float* __restrict__ x,
                                                const float* __restrict__ W,
                                                const float* __restrict__ bv,
                                                u16* __restrict__ h16,
                                                u16* __restrict__ hT) {
  int b = blockIdx.x / 200, tile = blockIdx.x % 200;
  int n0 = tile * 64;
  size_t gbase = (size_t)b * NPG;
  int t = threadIdx.x;
  __shared__ float xs[64][8];
  __shared__ float Ws[INDIM][128];
  __shared__ float bs[128];
  __shared__ float ld[64][132];
  if (t < 128) bs[t] = bv[t];
  for (int i = t; i < INDIM * 128; i += 256) Ws[i >> 7][i & 127] = W[i];
  for (int i = t; i < 64 * INDIM; i += 256) {
    int r = i / INDIM, q = i % INDIM;
    int gn = n0 + r;
    xs[r][q] = (gn < NPG) ? x[(gbase + gn) * INDIM + q] : 0.f;
  }
  __syncthreads();
  {
    int row = t & 63, c0 = (t >> 6) * 32;
#pragma unroll
    for (int cc = 0; cc < 32; ++cc) {
      int c = c0 + cc;
      float acc = bs[c];
#pragma unroll
      for (int i = 0; i < INDIM; ++i) acc = fmaf(xs[row][i], Ws[i][c], acc);
      ld[row][c] = fmaxf(acc, 0.f);
    }
  }
  __syncthreads();
  {
    int row = t >> 2, q = t & 3;
    if (n0 + row < NPG) {
      size_t base = (gbase + n0 + row) * (size_t)CD + q * 32;
      alignas(16) u16 tmp[8];
#pragma unroll
      for (int u = 0; u < 4; ++u) {
#pragma unroll
        for (int i = 0; i < 8; ++i) tmp[i] = f2b(ld[row][q * 32 + u * 8 + i]);
        *(uint4*)&h16[base + u * 8] = *(uint4*)tmp;
      }
    }
  }
  {
    int crow = t >> 1, half = t & 1;
    alignas(16) u16 tmp[8];
#pragma unroll
    for (int q = 0; q < 4; ++q) {
      int nb = half * 32 + q * 8;
#pragma unroll
      for (int i = 0; i < 8; ++i) tmp[i] = f2b(ld[nb + i][crow]);
      *(uint4*)&hT[((size_t)(b * 128 + crow)) * NPGP + n0 + nb] = *(uint4*)tmp;
    }
  }
}

// packed bucket: entry = col | bf16(vre)<<32 | bf16(vim)<<48
__global__ void k_bucket_place(const int* __restrict__ rows, const int* __restrict__ cols,
                               const float* __restrict__ vre, const float* __restrict__ vim,
                               int* cnt, u64* bucket) {
  int e = blockIdx.x * 256 + threadIdx.x;
  if (e >= NEDGE) return;
  int r = rows[e];
  int pos = atomicAdd(&cnt[r], 1);
  if (pos < BCAP) {
    u64 ent = (u64)(unsigned)cols[e]
            | ((u64)f2b(vre[e]) << 32)
            | ((u64)f2b(vim[e]) << 48);
    bucket[(size_t)r * BCAP + pos] = ent;
  }
}

// gather: one wave per row; packed entries; 2-way unroll; XCD-swizzled
__global__ void k_gather_ev(const int* __restrict__ cnt, const u64* __restrict__ bucket,
                            const float* __restrict__ evf, const u16* __restrict__ ev16,
                            int useB16,
                            u16* __restrict__ gre, u16* __restrict__ gim) {
  int orig = blockIdx.x;                       // 25000 = 8 * 3125
  int blk  = (orig & 7) * 3125 + (orig >> 3);  // graph (orig&7) -> XCD (orig&7)
  int wv = threadIdx.x >> 6;
  int ln = threadIdx.x & 63;
  int r  = blk * 4 + wv;
  int d = min(cnt[r], BCAP);
  const u64* bk = bucket + (size_t)r * BCAP;
  float2 ra0 = make_float2(0.f, 0.f), ia0 = make_float2(0.f, 0.f);
  float2 ra1 = make_float2(0.f, 0.f), ia1 = make_float2(0.f, 0.f);
  if (useB16) {
    int i = 0;
    for (; i + 2 <= d; i += 2) {
      u64 e0 = bk[i], e1 = bk[i + 1];
      int c0 = (int)(unsigned)e0, c1 = (int)(unsigned)e1;
      float a0 = b2f((u16)(e0 >> 32)), b0 = b2f((u16)(e0 >> 48));
      float a1 = b2f((u16)(e1 >> 32)), b1 = b2f((u16)(e1 >> 48));
      ushort2 u0 = *(const ushort2*)&ev16[(size_t)c0 * KD + ln * 2];
      ushort2 u1 = *(const ushort2*)&ev16[(size_t)c1 * KD + ln * 2];
      float vx0 = b2f(u0.x), vy0 = b2f(u0.y);
      float vx1 = b2f(u1.x), vy1 = b2f(u1.y);
      ra0.x = fmaf(a0, vx0, ra0.x); ra0.y = fmaf(a0, vy0, ra0.y);
      ia0.x = fmaf(b0, vx0, ia0.x); ia0.y = fmaf(b0, vy0, ia0.y);
      ra1.x = fmaf(a1, vx1, ra1.x); ra1.y = fmaf(a1, vy1, ra1.y);
      ia1.x = fmaf(b1, vx1, ia1.x); ia1.y = fmaf(b1, vy1, ia1.y);
    }
    if (i < d) {
      u64 e0 = bk[i];
      int c0 = (int)(unsigned)e0;
      float a0 = b2f((u16)(e0 >> 32)), b0 = b2f((u16)(e0 >> 48));
      ushort2 u0 = *(const ushort2*)&ev16[(size_t)c0 * KD + ln * 2];
      float vx0 = b2f(u0.x), vy0 = b2f(u0.y);
      ra0.x = fmaf(a0, vx0, ra0.x); ra0.y = fmaf(a0, vy0, ra0.y);
      ia0.x = fmaf(b0, vx0, ia0.x); ia0.y = fmaf(b0, vy0, ia0.y);
    }
  } else {
    for (int i = 0; i < d; ++i) {
      u64 e0 = bk[i];
      int c0 = (int)(unsigned)e0;
      float a = b2f((u16)(e0 >> 32)), b = b2f((u16)(e0 >> 48));
      float2 v = *(const float2*)&evf[(size_t)c0 * KD + ln * 2];
      ra0.x = fmaf(a, v.x, ra0.x); ra0.y = fmaf(a, v.y, ra0.y);
      ia0.x = fmaf(b, v.x, ia0.x); ia0.y = fmaf(b, v.y, ia0.y);
    }
  }
  ushort2 ro, io;
  ro.x = f2b(ra0.x + ra1.x); ro.y = f2b(ra0.y + ra1.y);
  io.x = f2b(ia0.x + ia1.x); io.y = f2b(ia0.y + ia1.y);
  *(ushort2*)&gre[(size_t)r * KD + ln * 2] = ro;
  *(ushort2*)&gim[(size_t)r * KD + ln * 2] = io;
}

// Transposed bf16 weights: W*T[c][j] = W[j][c]
__global__ void k_prep_w(const float* __restrict__ W1, const float* __restrict__ W2,
                         u16* W1aT, u16* W1bT, u16* W1cT, u16* W2T) {
  int idx = blockIdx.x * 256 + threadIdx.x;      // 4 * 4 * 16384
  int blk = idx >> 16, rem = idx & 65535;
  int mat = rem >> 14, e = rem & 16383;
  int j = e >> 7, c = e & 127;
  float v;
  u16* dst;
  if (mat < 3) {
    v = W1[(size_t)blk * 3 * 16384 + (size_t)mat * 16384 + e];
    dst = (mat == 0) ? W1aT : (mat == 1 ? W1bT : W1cT);
  } else {
    v = W2[(size_t)blk * 16384 + e];
    dst = W2T;
  }
  dst[(size_t)blk * 16384 + c * 128 + j] = f2b(v);
}

// head weights: B1T[c][k] (64 x 160, k<139 valid), B2T[c][k] (16 x 64, c<5 valid)
__global__ void k_prep_head(const float* __restrict__ Wh1, const float* __restrict__ Wh2,
                            u16* __restrict__ B1T, u16* __restrict__ B2T) {
  for (int idx = threadIdx.x; idx < 64 * 160; idx += 256) {
    int c = idx / 160, k = idx % 160;
    B1T[idx] = f2b(k < (CD + GSDIM) ? Wh1[k * 64 + c] : 0.f);
  }
  for (int idx = threadIdx.x; idx < 16 * 64; idx += 256) {
    int c = idx >> 6, k = idx & 63;
    B2T[idx] = f2b(c < NCLF ? Wh2[k * NCLF + c] : 0.f);
  }
}

// evT_m[b][k][n_pad] = evecs[n][k]*mass[n] bf16 ; ev16 mirror stays UNscaled
__global__ void k_transpose_nk(const float* __restrict__ src, const float* __restrict__ mass,
                               u16* __restrict__ dst, u16* __restrict__ ev16, int writeMir) {
  int b = blockIdx.x / 200, tile = blockIdx.x % 200;
  int n0 = tile * 64;
  size_t gbase = (size_t)b * NPG;
  int t = threadIdx.x;
  __shared__ float ld[64][132];
  __shared__ float ms[64];
  if (t < 64) {
    int gn = n0 + t;
    ms[t] = (gn < NPG) ? mass[gbase + gn] : 0.f;
  }
  int row0 = t >> 5, c4 = t & 31;
#pragma unroll
  for (int it = 0; it < 8; ++it) {
    int r = it * 8 + row0;
    int gn = n0 + r;
    float4 v = make_float4(0.f, 0.f, 0.f, 0.f);
    if (gn < NPG) v = *(const float4*)&src[(gbase + gn) * KD + c4 * 4];
    *(float4*)&ld[r][c4 * 4] = v;
    if (writeMir && gn < NPG) {
      ushort4 o;
      o.x = f2b(v.x); o.y = f2b(v.y); o.z = f2b(v.z); o.w = f2b(v.w);
      *(ushort4*)&ev16[(gbase + gn) * KD + c4 * 4] = o;
    }
  }
  __syncthreads();
  int crow = t >> 1, half = t & 1;
  alignas(16) u16 tmp[8];
#pragma unroll
  for (int q = 0; q < 4; ++q) {
    int nb = half * 32 + q * 8;
#pragma unroll
    for (int i = 0; i < 8; ++i) tmp[i] = f2b(ld[nb + i][crow] * ms[nb + i]);
    *(uint4*)&dst[((size_t)(b * 128 + crow)) * NPGP + n0 + nb] = *(uint4*)tmp;
  }
}

// ---------------------- MFMA kernels ----------------------

// partials[(b*TBSPLIT+s)][k][c] = sum_{n in chunk} evTm[b][k][n]*hT[b][c][n]
// full 128-k per WG (acc[2][8]); hT read ONCE per block iteration
__global__ __launch_bounds__(256) void k_tobasis(const u16* __restrict__ evTm,
                                                 const u16* __restrict__ hT,
                                                 float* __restrict__ partials) {
  int s = blockIdx.x % TBSPLIT;
  int b = blockIdx.x / TBSPLIT;
  int t = threadIdx.x, w = t >> 6, l = t & 63;
  __shared__ u16 As[128 * 40];
  __shared__ u16 Bs[128 * 40];
  f32x4 acc[2][8];
  f32x4 z = {0.f, 0.f, 0.f, 0.f};
#pragma unroll
  for (int mi = 0; mi < 2; ++mi)
#pragma unroll
    for (int j = 0; j < 8; ++j) acc[mi][j] = z;
  const u16* ae = evTm + (size_t)b * 128 * NPGP + s * TBCHUNK;
  const u16* bh = hT   + (size_t)b * 128 * NPGP + s * TBCHUNK;
  for (int ks = 0; ks < TBCHUNK / 32; ++ks) {
    stage128_b16(As, ae, NPGP, ks * 32);
    stage128_b16(Bs, bh, NPGP, ks * 32);
    __syncthreads();
    short8v a0 = frag(As, w * 32, l);
    short8v a1 = frag(As, w * 32 + 16, l);
    __builtin_amdgcn_s_setprio(1);
#pragma unroll
    for (int j = 0; j < 8; ++j) {
      short8v bj = frag(Bs, j * 16, l);
      MFMA(acc[0][j], a0, bj);
      MFMA(acc[1][j], a1, bj);
    }
    __builtin_amdgcn_s_setprio(0);
    __syncthreads();
  }
  float* op = partials + (size_t)(b * TBSPLIT + s) * 16384;
#pragma unroll
  for (int mi = 0; mi < 2; ++mi)
#pragma unroll
    for (int j = 0; j < 8; ++j)
#pragma unroll
      for (int i = 0; i < 4; ++i) {
        int krow = w * 32 + mi * 16 + (l >> 4) * 4 + i;
        int c = j * 16 + (l & 15);
        op[krow * 128 + c] = acc[mi][j][i];
      }
}

// spec[b][k][c] = scale(sum_s partials); specT16[b][c][k] = bf16(spec)
__global__ void k_reduce_scale_t(const float* __restrict__ partials,
                                 const float* __restrict__ evals,
                                 const float* __restrict__ td,
                                 float* __restrict__ spec, u16* __restrict__ specT) {
  int b = blockIdx.x >> 6;
  int idx = (blockIdx.x & 63) * 256 + threadIdx.x;
  int k = idx >> 7, c = idx & 127;
  float s = 0.f;
#pragma unroll 8
  for (int sp = 0; sp < TBSPLIT; ++sp)
    s += partials[(size_t)(b * TBSPLIT + sp) * 16384 + idx];
  float tm = fmaxf(fabsf(td[c]), 1e-8f);
  s *= expf(-evals[b * KD + k] * tm);
  spec[(size_t)b * 16384 + idx] = s;
  specT[(size_t)b * 16384 + c * 128 + k] = f2b(s);
}

// job0: SAT16[b][c][k] = sum_j Agrad[c][j]*spec[b][k][j]
// job1: M1T16[b][c][k] = sum_j W1bT[c][j]*spec[b][k][j]
__global__ __launch_bounds__(256) void k_smallT(const float* __restrict__ Agrad_blk,
                                                const u16* __restrict__ W1bT_blk,
                                                const float* __restrict__ spec,
                                                u16* __restrict__ SAT, u16* __restrict__ M1T) {
  int b = blockIdx.x & 7;
  int job = (blockIdx.x >> 3) & 1;
  int q = blockIdx.x >> 4;                 // 0..3: c-row quarter
  int t = threadIdx.x, w = t >> 6, l = t & 63;
  __shared__ u16 As[128 * 40];
  __shared__ u16 Bs[128 * 40];
  f32x4 acc[2][2];
  f32x4 z = {0.f, 0.f, 0.f, 0.f};
#pragma unroll
  for (int mi = 0; mi < 2; ++mi) { acc[mi][0] = z; acc[mi][1] = z; }
  for (int ks = 0; ks < 4; ++ks) {
    if (job == 0) stage128_f32(As, Agrad_blk, 128, ks * 32);
    else          stage128_b16(As, W1bT_blk, 128, ks * 32);
    stage128_f32(Bs, spec + (size_t)b * 16384, 128, ks * 32);
    __syncthreads();
    short8v a0 = frag(As, q * 32, l);
    short8v a1 = frag(As, q * 32 + 16, l);
#pragma unroll
    for (int jj = 0; jj < 2; ++jj) {
      short8v bj = frag(Bs, (w * 2 + jj) * 16, l);
      MFMA(acc[0][jj], a0, bj);
      MFMA(acc[1][jj], a1, bj);
    }
    __syncthreads();
  }
  u16* out = (job == 0 ? SAT : M1T) + (size_t)b * 16384;
#pragma unroll
  for (int mi = 0; mi < 2; ++mi)
#pragma unroll
    for (int jj = 0; jj < 2; ++jj)
#pragma unroll
      for (int i = 0; i < 4; ++i)
        out[(q * 32 + mi * 16 + (l >> 4) * 4 + i) * 128 + (w * 2 + jj) * 16 + (l & 15)] =
            f2b(acc[mi][jj][i]);
}

// gf16 = tanh((Gre@spec')*(Gre@SA) + (Gim@spec')*(Gim@SA))   [bf16 out]
__global__ __launch_bounds__(256) void k_gfeat(const u16* __restrict__ Gre,
                                               const u16* __restrict__ Gim,
                                               const u16* __restrict__ specT,
                                               const u16* __restrict__ SAT,
                                               u16* __restrict__ gf) {
  int b = blockIdx.x / NT32, tile = blockIdx.x % NT32;
  int n0 = tile * 32;
  size_t gbase = (size_t)b * NPG;
  int t = threadIdx.x, w = t >> 6, l = t & 63;
  int r0 = (w & 1) * 16, c0 = (w >> 1) * 64;
  __shared__ u16 Sr[32 * 40];
  __shared__ u16 Si[32 * 40];
  __shared__ u16 Bs[128 * 40];
  __shared__ u16 Ba[128 * 40];
  f32x4 aGR[4], aAR[4], aGI[4], aAI[4];
  f32x4 z = {0.f, 0.f, 0.f, 0.f};
#pragma unroll
  for (int j = 0; j < 4; ++j) { aGR[j] = z; aAR[j] = z; aGI[j] = z; aAI[j] = z; }
  int valid = min(32, NPG - n0);
  const u16* gre = Gre + (gbase + n0) * KD;
  const u16* gim = Gim + (gbase + n0) * KD;
  for (int ks = 0; ks < 4; ++ks) {
    stage32_b16(Sr, gre, KD, ks * 32, valid);
    stage32_b16(Si, gim, KD, ks * 32, valid);
    stage128_b16(Bs, specT + (size_t)b * 16384, 128, ks * 32);
    stage128_b16(Ba, SAT + (size_t)b * 16384, 128, ks * 32);
    __syncthreads();
    short8v fr = frag(Sr, r0, l);
    short8v fi = frag(Si, r0, l);
    __builtin_amdgcn_s_setprio(1);
#pragma unroll
    for (int j = 0; j < 4; ++j) {
      short8v bs = frag(Bs, c0 + j * 16, l);
      short8v ba = frag(Ba, c0 + j * 16, l);
      MFMA(aGR[j], fr, bs);
      MFMA(aAR[j], fr, ba);
      MFMA(aGI[j], fi, bs);
      MFMA(aAI[j], fi, ba);
    }
    __builtin_amdgcn_s_setprio(0);
    __syncthreads();
  }
#pragma unroll
  for (int j = 0; j < 4; ++j) {
    int c = c0 + j * 16 + (l & 15);
#pragma unroll
    for (int i = 0; i < 4; ++i) {
      int n = n0 + r0 + (l >> 4) * 4 + i;
      if (n - n0 < valid) {
        float v = tanhf(fmaf(aGR[j][i], aAR[j][i], aGI[j][i] * aAI[j][i]));
        gf[(gbase + n) * CD + c] = f2b(v);
      }
    }
  }
}

// ---- fused mlp1+mlp2, 512 threads / 128-row tiles; persistent-A + dbuf-B ----
__global__ __launch_bounds__(512) void k_mlp12(const float* __restrict__ evf,
                                               const u16* __restrict__ ev16,
                                               int useB16,
                                               const u16* __restrict__ gf,
                                               const u16* __restrict__ W1aT,
                                               const u16* __restrict__ M1T,
                                               const u16* __restrict__ W1cT,
                                               const float* __restrict__ b1,
                                               const u16* __restrict__ W2T,
                                               const float* __restrict__ b2,
                                               u16* __restrict__ h16,
                                               u16* __restrict__ hT,
                                               int writeHT) {
  int b = blockIdx.x / NT128, tile = blockIdx.x % NT128;
  int n0 = tile * 128;
  size_t gbase = (size_t)b * NPG;
  int t = threadIdx.x, w = t >> 6, l = t & 63;     // 8 waves
  __shared__ u16 SH[27648];
  u16* Af  = SH;
  u16* t1S = SH;
  u16* Tm  = SH;
  u16* Bs0 = SH + 17408;
  u16* Bs1 = SH + 22528;
  f32x4 acc[8];
  f32x4 z = {0.f, 0.f, 0.f, 0.f};
#pragma unroll
  for (int j = 0; j < 8; ++j) acc[j] = z;
  int valid = min(128, NPG - n0);
  int r0 = w * 16;                    // wave's row block

  // ===== phase 1: mlp1 (3 segments of K=128), persistent A per segment =====
  for (int seg = 0; seg < 3; ++seg) {
    const u16* bt = (seg == 0) ? W1aT : (seg == 1 ? M1T + (size_t)b * 16384 : W1cT);
    if (seg == 0)      stageA_b16(Af, h16 + (gbase + n0) * CD, CD, valid);
    else if (seg == 1) {
      if (useB16) stageA_b16(Af, ev16 + (gbase + n0) * KD, KD, valid);
      else        stageA_f32(Af, evf + (gbase + n0) * KD, KD, valid);
    }
    else               stageA_b16(Af, gf + (gbase + n0) * CD, CD, valid);
    stB(Bs0, ldB(bt, 0));
    __syncthreads();
#pragma unroll
    for (int ks = 0; ks < 4; ++ks) {
      uint4 bvn;
      if (ks < 3) bvn = ldB(bt, (ks + 1) * 32);        // issue-early
      short8v a = frag_p(Af, r0, l, 136, ks * 32);
      u16* Bcur = (ks & 1) ? Bs1 : Bs0;
      __builtin_amdgcn_s_setprio(1);
#pragma unroll
      for (int j = 0; j < 8; ++j) MFMA(acc[j], a, frag(Bcur, j * 16, l));
      __builtin_amdgcn_s_setprio(0);
      if (ks < 3) stB((ks & 1) ? Bs0 : Bs1, bvn);       // write-late
      __syncthreads();
    }
  }
  // t1 -> LDS (bf16, relu+bias), pitch 132, overlays Af (all A reads done)
#pragma unroll
  for (int j = 0; j < 8; ++j) {
    int c = j * 16 + (l & 15);
    float bias = b1[c];
#pragma unroll
    for (int i = 0; i < 4; ++i) {
      int row = r0 + (l >> 4) * 4 + i;
      t1S[row * 132 + c] = f2b(fmaxf(acc[j][i] + bias, 0.f));
    }
  }
  stB(Bs0, ldB(W2T, 0));
  __syncthreads();

  // ===== phase 2: mlp2 (K=128), A = t1S persistent =====
#pragma unroll
  for (int j = 0; j < 8; ++j) acc[j] = z;
#pragma unroll
  for (int ks = 0; ks < 4; ++ks) {
    uint4 bvn;
    if (ks < 3) bvn = ldB(W2T, (ks + 1) * 32);
    short8v a = frag_p(t1S, r0, l, 132, ks * 32);
    u16* Bcur = (ks & 1) ? Bs1 : Bs0;
    __builtin_amdgcn_s_setprio(1);
#pragma unroll
    for (int j = 0; j < 8; ++j) MFMA(acc[j], a, frag(Bcur, j * 16, l));
    __builtin_amdgcn_s_setprio(0);
    if (ks < 3) stB((ks & 1) ? Bs0 : Bs1, bvn);
    __syncthreads();
  }

  // ===== epilogue: h16 += mlp2 + b2 (bf16 state) ; hT (plain transpose) =====
#pragma unroll
  for (int j = 0; j < 8; ++j) {
    int c = j * 16 + (l & 15);
    float bias = b2[c];
#pragma unroll
    for (int i = 0; i < 4; ++i) {
      int nl = r0 + (l >> 4) * 4 + i;
      float hv = 0.f;
      if (nl < valid) {
        size_t idx = (gbase + n0 + nl) * (size_t)CD + c;
        hv = b2f(h16[idx]) + acc[j][i] + bias;
        h16[idx] = f2b(hv);
      }
      if (writeHT) Tm[c * 130 + nl] = f2b(hv);
    }
  }
  if (writeHT) {
    __syncthreads();
#pragma unroll
    for (int q = 0; q < 4; ++q) {
      int lin = t + q * 512;            // 2048 chunks of 8 u16 (128c x 128n)
      int cc = lin >> 4, chunk = lin & 15;
      *(uint4*)&hT[((size_t)(b * 128 + cc)) * NPGP + n0 + chunk * 8] =
          *(const uint4*)&Tm[cc * 130 + chunk * 8];
    }
  }
}

// ---- fused 2-layer head (bf16 MFMA): out = relu([h|gs]@Wh1+bh1)@Wh2+bh2 ----
__global__ __launch_bounds__(256) void k_head2(
    const u16* __restrict__ h16, const float* __restrict__ gs,
    const int* __restrict__ batch, const u16* __restrict__ B1T,
    const float* __restrict__ bh1, const u16* __restrict__ B2T,
    const float* __restrict__ bh2, float* __restrict__ out) {
  int n0 = blockIdx.x * 64;
  int t = threadIdx.x, w = t >> 6, l = t & 63;
  __shared__ u16 As[64 * 40];
  __shared__ u16 Bs[64 * 40];
  __shared__ u16 zS[64 * 72];
  int valid = min(64, NNODES - n0);
  f32x4 acc1[4];
  f32x4 z = {0.f, 0.f, 0.f, 0.f};
#pragma unroll
  for (int j = 0; j < 4; ++j) acc1[j] = z;
  for (int ks = 0; ks < 5; ++ks) {
    if (ks < 4) {
      stage64_b16(As, h16 + (size_t)n0 * CD, CD, ks * 32, valid);
    } else {
      int row = t >> 2, kq = t & 3;
      alignas(16) u16 tmp[8];
      int bb = (row < valid) ? batch[n0 + row] : 0;
#pragma unroll
      for (int q = 0; q < 8; ++q) {
        int kk = kq * 8 + q;
        float v = (row < valid && kk < GSDIM) ? gs[bb * GSDIM + kk] : 0.f;
        tmp[q] = f2b(v);
      }
      *(uint4*)&As[row * 40 + kq * 8] = *(uint4*)tmp;
    }
    stage64_b16(Bs, B1T, 160, ks * 32, 64);
    __syncthreads();
    short8v a = frag(As, w * 16, l);
#pragma unroll
    for (int j = 0; j < 4; ++j) MFMA(acc1[j], a, frag(Bs, j * 16, l));
    __syncthreads();
  }
#pragma unroll
  for (int j = 0; j < 4; ++j) {
    int c = j * 16 + (l & 15);
    float bias = bh1[c];
#pragma unroll
    for (int i = 0; i < 4; ++i) {
      int row = w * 16 + (l >> 4) * 4 + i;
      zS[row * 72 + c] = f2b(fmaxf(acc1[j][i] + bias, 0.f));
    }
  }
  __syncthreads();
  f32x4 acc2 = z;
  for (int ks = 0; ks < 2; ++ks) {
    stage64_b16(Bs, B2T, 64, ks * 32, 16);
    __syncthreads();
    short8v a2 = frag_p(zS, w * 16, l, 72, ks * 32);
    MFMA(acc2, a2, frag(Bs, 0, l));
    __syncthreads();
  }
  int c = l & 15;
  if (c < NCLF) {
    float bias = bh2[c];
#pragma unroll
    for (int i = 0; i < 4; ++i) {
      int n = n0 + w * 16 + (l >> 4) * 4 + i;
      if (n < NNODES) out[(size_t)n * NCLF + c] = acc2[i] + bias;
    }
  }
}

extern "C" void kernel_launch(void* const* d_in, const int* in_sizes, int n_in,
                              void* d_out, int out_size, void* d_ws, size_t ws_size,
                              hipStream_t stream) {
  const float* x     = (const float*)d_in[0];
  const float* evals = (const float*)d_in[1];
  const float* evecs = (const float*)d_in[2];
  const float* mass  = (const float*)d_in[3];
  const float* gs    = (const float*)d_in[4];
  const int*   batch = (const int*)d_in[5];
  const int*   grows = (const int*)d_in[6];
  const int*   gcols = (const int*)d_in[7];
  const float* vre   = (const float*)d_in[8];
  const float* vim   = (const float*)d_in[9];
  const float* Wemb  = (const float*)d_in[11];
  const float* bemb  = (const float*)d_in[12];
  const float* tdiff = (const float*)d_in[13];
  const float* Agrad = (const float*)d_in[14];
  const float* W1    = (const float*)d_in[15];
  const float* b1    = (const float*)d_in[16];
  const float* W2    = (const float*)d_in[17];
  const float* b2    = (const float*)d_in[18];
  const float* Wh1   = (const float*)d_in[19];
  const float* bh1   = (const float*)d_in[20];
  const float* Wh2   = (const float*)d_in[21];
  const float* bh2   = (const float*)d_in[22];

  char* base = (char*)d_ws;
  size_t off = 0;
  auto alloc = [&](size_t bytes) -> void* {
    void* p = base + off;
    off += (bytes + 255) & ~(size_t)255;
    return p;
  };
  u16*   evT16  = (u16*)alloc((size_t)NGRAPH * 128 * NPGP * 2);       // 26.2 MB (mass-scaled)
  u16*   hT     = (u16*)alloc((size_t)NGRAPH * 128 * NPGP * 2);       // 26.2 MB (plain h^T)
  u16*   Gre16  = (u16*)alloc((size_t)NNODES * KD * 2);               // 25.6 MB
  u16*   Gim16  = (u16*)alloc((size_t)NNODES * KD * 2);               // 25.6 MB
  u16*   h16    = (u16*)alloc((size_t)NNODES * CD * 2);               // 25.6 MB (sole h state)
  float* spec   = (float*)alloc((size_t)NGRAPH * 16384 * 4);
  u16*   specT16 = (u16*)alloc((size_t)NGRAPH * 16384 * 2);
  u16*   SAT16  = (u16*)alloc((size_t)NGRAPH * 16384 * 2);
  u16*   M1T16  = (u16*)alloc((size_t)NGRAPH * 16384 * 2);
  u16*   W1aT16 = (u16*)alloc((size_t)NBLKS * 16384 * 2);
  u16*   W1bT16 = (u16*)alloc((size_t)NBLKS * 16384 * 2);
  u16*   W1cT16 = (u16*)alloc((size_t)NBLKS * 16384 * 2);
  u16*   W2T16  = (u16*)alloc((size_t)NBLKS * 16384 * 2);
  u16*   B1T16  = (u16*)alloc(64 * 160 * 2);
  u16*   B2T16  = (u16*)alloc(16 * 64 * 2);
  int*   cnt    = (int*)alloc(100352 * 4);
  // R region (25.6 MB): bucket u64[N*32] / partials 21MB / gf16 25.6MB (disjoint liveness)
  void*  R      = alloc((size_t)NNODES * BCAP * 8);
  u64*   bucket = (u64*)R;
  float* partials = (float*)R;
  u16*   gf16   = (u16*)R;
  // bf16 evecs mirror (only if workspace allows)
  int useEv16 = 0;
  u16* ev16 = nullptr;
  if (off + ((size_t)NNODES * KD * 2 + 256) <= ws_size) {
    ev16 = (u16*)alloc((size_t)NNODES * KD * 2);                      // 25.6 MB
    useEv16 = 1;
  }
  float* out    = (float*)d_out;

  // ---- once per launch ----
  k_embed2<<<NGRAPH * 200, 256, 0, stream>>>(x, Wemb, bemb, h16, hT);
  k_fill0<<<98, 256, 0, stream>>>((float4*)cnt, 100352 / 4);
  k_bucket_place<<<(NEDGE + 255) / 256, 256, 0, stream>>>(grows, gcols, vre, vim,
                                                          cnt, bucket);
  k_transpose_nk<<<NGRAPH * 200, 256, 0, stream>>>(evecs, mass, evT16, ev16, useEv16);
  k_gather_ev<<<NNODES / 4, 256, 0, stream>>>(cnt, bucket, evecs, ev16, useEv16,
                                              Gre16, Gim16);
  k_prep_w<<<1024, 256, 0, stream>>>(W1, W2, W1aT16, W1bT16, W1cT16, W2T16);
  k_prep_head<<<1, 256, 0, stream>>>(Wh1, Wh2, B1T16, B2T16);

  for (int blk = 0; blk < NBLKS; ++blk) {
    k_tobasis<<<NGRAPH * TBSPLIT, 256, 0, stream>>>(evT16, hT, partials);
    k_reduce_scale_t<<<NGRAPH * 64, 256, 0, stream>>>(partials, evals, tdiff + blk * CD,
                                                      spec, specT16);
    k_smallT<<<64, 256, 0, stream>>>(Agrad + (size_t)blk * 16384,
                                     W1bT16 + (size_t)blk * 16384, spec, SAT16, M1T16);
    k_gfeat<<<NGRAPH * NT32, 256, 0, stream>>>(Gre16, Gim16, specT16, SAT16, gf16);
    k_mlp12<<<NGRAPH * NT128, 512, 0, stream>>>(evecs, ev16, useEv16, gf16,
                                                W1aT16 + (size_t)blk * 16384, M1T16,
                                                W1cT16 + (size_t)blk * 16384,
                                                b1 + blk * CD,
                                                W2T16 + (size_t)blk * 16384,
                                                b2 + blk * CD, h16, hT,
                                                (blk < NBLKS - 1) ? 1 : 0);
  }
  k_head2<<<(NNODES + 63) / 64, 256, 0, stream>>>(h16, gs, batch, B1T16, bh1,
                                                  B2T16, bh2, out);
}

// Round 19
// 633.408 us; speedup vs baseline: 1.0787x; 1.0108x over previous
//
#include <hip/hip_runtime.h>
#include <hip/hip_bf16.h>

#define NNODES 100000
#define NPG    12500
#define NGRAPH 8
#define KD     128
#define CD     128
#define INDIM  7
#define GSDIM  11
#define NBLKS  4
#define NCLF   5
#define NEDGE  800000
#define BCAP   32             // packed u64 entries; Poisson(8) tail P(d>32) ~ 3e-6
#define NPGP   12800          // padded nodes per graph (40 * 320)
#define TBSPLIT 40            // to_basis split-n
#define TBCHUNK 320           // = NPGP / TBSPLIT, 10 k-steps of 32
#define NT32    391           // ceil(12500/32)
#define NT128   98            // ceil(12500/128)

typedef __attribute__((ext_vector_type(8))) short short8v;
typedef __attribute__((ext_vector_type(4))) float f32x4;
typedef unsigned short u16;
typedef unsigned long long u64;

#define MFMA(acc, a, b) acc = __builtin_amdgcn_mfma_f32_16x16x32_bf16(a, b, acc, 0, 0, 0)

__device__ __forceinline__ u16 f2b(float f) {
  union { __hip_bfloat16 h; u16 u; } cv;
  cv.h = __float2bfloat16(f);
  return cv.u;
}
__device__ __forceinline__ float b2f(u16 u) {
  return __uint_as_float((unsigned)u << 16);
}

// ---------- LDS staging helpers (tile layout: [rows][40] u16, 32 valid k) ----------

__device__ __forceinline__ void stage64_f32(u16* S, const float* src, int ld, int k0, int valid) {
  int t = threadIdx.x, row = t >> 2, kq = t & 3;
  alignas(16) u16 tmp[8] = {0, 0, 0, 0, 0, 0, 0, 0};
  if (row < valid) {
    const float* p = src + (size_t)row * ld + k0 + kq * 8;
    float4 f0 = *(const float4*)p, f1 = *(const float4*)(p + 4);
    tmp[0] = f2b(f0.x); tmp[1] = f2b(f0.y); tmp[2] = f2b(f0.z); tmp[3] = f2b(f0.w);
    tmp[4] = f2b(f1.x); tmp[5] = f2b(f1.y); tmp[6] = f2b(f1.z); tmp[7] = f2b(f1.w);
  }
  *(uint4*)&S[row * 40 + kq * 8] = *(uint4*)tmp;
}

__device__ __forceinline__ void stage64_b16(u16* S, const u16* src, long ld, int k0, int valid) {
  int t = threadIdx.x, row = t >> 2, kq = t & 3;
  uint4 v = make_uint4(0, 0, 0, 0);
  if (row < valid) v = *(const uint4*)(src + (size_t)row * ld + k0 + kq * 8);
  *(uint4*)&S[row * 40 + kq * 8] = v;
}

// 32-row variant: threads 0..127 stage a [32][40] tile
__device__ __forceinline__ void stage32_b16(u16* S, const u16* src, long ld, int k0, int valid) {
  int t = threadIdx.x;
  if (t < 128) {
    int row = t >> 2, kq = t & 3;
    uint4 v = make_uint4(0, 0, 0, 0);
    if (row < valid) v = *(const uint4*)(src + (size_t)row * ld + k0 + kq * 8);
    *(uint4*)&S[row * 40 + kq * 8] = v;
  }
}

__device__ __forceinline__ void stage128_b16(u16* S, const u16* src, long ld, int k0) {
  int t = threadIdx.x, row = t >> 1, half = t & 1;
  const u16* p = src + (size_t)row * ld + k0 + half * 16;
  uint4 v0 = *(const uint4*)p, v1 = *(const uint4*)(p + 8);
  *(uint4*)&S[row * 40 + half * 16] = v0;
  *(uint4*)&S[row * 40 + half * 16 + 8] = v1;
}

__device__ __forceinline__ void stage128_f32(u16* S, const float* src, int ld, int k0) {
  int t = threadIdx.x, row = t >> 1, half = t & 1;
  const float* p = src + (size_t)row * ld + k0 + half * 16;
  float4 f0 = *(const float4*)p, f1 = *(const float4*)(p + 4);
  float4 f2 = *(const float4*)(p + 8), f3 = *(const float4*)(p + 12);
  alignas(16) u16 tmp[16];
  tmp[0] = f2b(f0.x); tmp[1] = f2b(f0.y); tmp[2]  = f2b(f0.z); tmp[3]  = f2b(f0.w);
  tmp[4] = f2b(f1.x); tmp[5] = f2b(f1.y); tmp[6]  = f2b(f1.z); tmp[7]  = f2b(f1.w);
  tmp[8] = f2b(f2.x); tmp[9] = f2b(f2.y); tmp[10] = f2b(f2.z); tmp[11] = f2b(f2.w);
  tmp[12] = f2b(f3.x); tmp[13] = f2b(f3.y); tmp[14] = f2b(f3.z); tmp[15] = f2b(f3.w);
  *(uint4*)&S[row * 40 + half * 16] = *(uint4*)&tmp[0];
  *(uint4*)&S[row * 40 + half * 16 + 8] = *(uint4*)&tmp[8];
}

// full 128x128 A tile staged by 512 threads (pitch 136)
__device__ __forceinline__ void stageA_b16(u16* Af, const u16* src, long ld, int valid) {
  int t = threadIdx.x;
#pragma unroll
  for (int q = 0; q < 4; ++q) {
    int lin = t + q * 512;
    int row = lin >> 4, kq = lin & 15;
    uint4 v = make_uint4(0, 0, 0, 0);
    if (row < valid) v = *(const uint4*)(src + (size_t)row * ld + kq * 8);
    *(uint4*)&Af[row * 136 + kq * 8] = v;
  }
}
__device__ __forceinline__ void stageA_f32(u16* Af, const float* src, long ld, int valid) {
  int t = threadIdx.x;
#pragma unroll
  for (int q = 0; q < 4; ++q) {
    int lin = t + q * 512;
    int row = lin >> 4, kq = lin & 15;
    alignas(16) u16 tmp[8] = {0, 0, 0, 0, 0, 0, 0, 0};
    if (row < valid) {
      const float* p = src + (size_t)row * ld + kq * 8;
      float4 f0 = *(const float4*)p, f1 = *(const float4*)(p + 4);
      tmp[0] = f2b(f0.x); tmp[1] = f2b(f0.y); tmp[2] = f2b(f0.z); tmp[3] = f2b(f0.w);
      tmp[4] = f2b(f1.x); tmp[5] = f2b(f1.y); tmp[6] = f2b(f1.z); tmp[7] = f2b(f1.w);
    }
    *(uint4*)&Af[row * 136 + kq * 8] = *(uint4*)tmp;
  }
}

// B tile (128 rows x 32 k) load/store: 1 uint4 per thread at 512 threads
__device__ __forceinline__ uint4 ldB(const u16* bt, int k0) {
  int t = threadIdx.x, row = t >> 2, kq = t & 3;
  return *(const uint4*)(bt + (size_t)row * 128 + k0 + kq * 8);
}
__device__ __forceinline__ void stB(u16* Bs, uint4 v) {
  int t = threadIdx.x, row = t >> 2, kq = t & 3;
  *(uint4*)&Bs[row * 40 + kq * 8] = v;
}

__device__ __forceinline__ short8v frag(const u16* S, int row0, int l) {
  return *(const short8v*)&S[(row0 + (l & 15)) * 40 + (l >> 4) * 8];
}
__device__ __forceinline__ short8v frag_p(const u16* S, int row0, int l, int pitch, int k0) {
  return *(const short8v*)&S[(row0 + (l & 15)) * pitch + k0 + (l >> 4) * 8];
}

// ---------------------- utility kernels ----------------------

__global__ void k_fill0(float4* p, int n4) {
  int i = blockIdx.x * blockDim.x + threadIdx.x;
  int s = gridDim.x * blockDim.x;
  float4 z = make_float4(0.f, 0.f, 0.f, 0.f);
  for (; i < n4; i += s) p[i] = z;
}

// fused embed: h16 = bf16(relu(x@W+b)); hT = plain transpose (mass folded into evT)
__global__ __launch_bounds__(256) void k_embed2(const float* __restrict__ x,
                                                const float* __restrict__ W,
                                                const float* __restrict__ bv,
                                                u16* __restrict__ h16,
                                                u16* __restrict__ hT) {
  int b = blockIdx.x / 200, tile = blockIdx.x % 200;
  int n0 = tile * 64;
  size_t gbase = (size_t)b * NPG;
  int t = threadIdx.x;
  __shared__ float xs[64][8];
  __shared__ float Ws[INDIM][128];
  __shared__ float bs[128];
  __shared__ float ld[64][132];
  if (t < 128) bs[t] = bv[t];
  for (int i = t; i < INDIM * 128; i += 256) Ws[i >> 7][i & 127] = W[i];
  for (int i = t; i < 64 * INDIM; i += 256) {
    int r = i / INDIM, q = i % INDIM;
    int gn = n0 + r;
    xs[r][q] = (gn < NPG) ? x[(gbase + gn) * INDIM + q] : 0.f;
  }
  __syncthreads();
  {
    int row = t & 63, c0 = (t >> 6) * 32;
#pragma unroll
    for (int cc = 0; cc < 32; ++cc) {
      int c = c0 + cc;
      float acc = bs[c];
#pragma unroll
      for (int i = 0; i < INDIM; ++i) acc = fmaf(xs[row][i], Ws[i][c], acc);
      ld[row][c] = fmaxf(acc, 0.f);
    }
  }
  __syncthreads();
  {
    int row = t >> 2, q = t & 3;
    if (n0 + row < NPG) {
      size_t base = (gbase + n0 + row) * (size_t)CD + q * 32;
      alignas(16) u16 tmp[8];
#pragma unroll
      for (int u = 0; u < 4; ++u) {
#pragma unroll
        for (int i = 0; i < 8; ++i) tmp[i] = f2b(ld[row][q * 32 + u * 8 + i]);
        *(uint4*)&h16[base + u * 8] = *(uint4*)tmp;
      }
    }
  }
  {
    int crow = t >> 1, half = t & 1;
    alignas(16) u16 tmp[8];
#pragma unroll
    for (int q = 0; q < 4; ++q) {
      int nb = half * 32 + q * 8;
#pragma unroll
      for (int i = 0; i < 8; ++i) tmp[i] = f2b(ld[nb + i][crow]);
      *(uint4*)&hT[((size_t)(b * 128 + crow)) * NPGP + n0 + nb] = *(uint4*)tmp;
    }
  }
}

// packed bucket: entry = col | bf16(vre)<<32 | bf16(vim)<<48
__global__ void k_bucket_place(const int* __restrict__ rows, const int* __restrict__ cols,
                               const float* __restrict__ vre, const float* __restrict__ vim,
                               int* cnt, u64* bucket) {
  int e = blockIdx.x * 256 + threadIdx.x;
  if (e >= NEDGE) return;
  int r = rows[e];
  int pos = atomicAdd(&cnt[r], 1);
  if (pos < BCAP) {
    u64 ent = (u64)(unsigned)cols[e]
            | ((u64)f2b(vre[e]) << 32)
            | ((u64)f2b(vim[e]) << 48);
    bucket[(size_t)r * BCAP + pos] = ent;
  }
}

// gather: one wave per row; packed entries; 4-way unroll; XCD-swizzled
__global__ void k_gather_ev(const int* __restrict__ cnt, const u64* __restrict__ bucket,
                            const float* __restrict__ evf, const u16* __restrict__ ev16,
                            int useB16,
                            u16* __restrict__ gre, u16* __restrict__ gim) {
  int orig = blockIdx.x;                       // 25000 = 8 * 3125
  int blk  = (orig & 7) * 3125 + (orig >> 3);  // graph (orig&7) -> XCD (orig&7)
  int wv = threadIdx.x >> 6;
  int ln = threadIdx.x & 63;
  int r  = blk * 4 + wv;
  int d = min(cnt[r], BCAP);
  const u64* bk = bucket + (size_t)r * BCAP;
  float2 ra0 = make_float2(0.f, 0.f), ia0 = make_float2(0.f, 0.f);
  float2 ra1 = make_float2(0.f, 0.f), ia1 = make_float2(0.f, 0.f);
  float2 ra2 = make_float2(0.f, 0.f), ia2 = make_float2(0.f, 0.f);
  float2 ra3 = make_float2(0.f, 0.f), ia3 = make_float2(0.f, 0.f);
  if (useB16) {
    int i = 0;
    for (; i + 4 <= d; i += 4) {
      u64 e0 = bk[i], e1 = bk[i + 1], e2 = bk[i + 2], e3 = bk[i + 3];
      int c0 = (int)(unsigned)e0, c1 = (int)(unsigned)e1;
      int c2 = (int)(unsigned)e2, c3 = (int)(unsigned)e3;
      float a0 = b2f((u16)(e0 >> 32)), b0 = b2f((u16)(e0 >> 48));
      float a1 = b2f((u16)(e1 >> 32)), b1 = b2f((u16)(e1 >> 48));
      float a2 = b2f((u16)(e2 >> 32)), b2 = b2f((u16)(e2 >> 48));
      float a3 = b2f((u16)(e3 >> 32)), b3 = b2f((u16)(e3 >> 48));
      ushort2 u0 = *(const ushort2*)&ev16[(size_t)c0 * KD + ln * 2];
      ushort2 u1 = *(const ushort2*)&ev16[(size_t)c1 * KD + ln * 2];
      ushort2 u2 = *(const ushort2*)&ev16[(size_t)c2 * KD + ln * 2];
      ushort2 u3 = *(const ushort2*)&ev16[(size_t)c3 * KD + ln * 2];
      float vx0 = b2f(u0.x), vy0 = b2f(u0.y);
      float vx1 = b2f(u1.x), vy1 = b2f(u1.y);
      float vx2 = b2f(u2.x), vy2 = b2f(u2.y);
      float vx3 = b2f(u3.x), vy3 = b2f(u3.y);
      ra0.x = fmaf(a0, vx0, ra0.x); ra0.y = fmaf(a0, vy0, ra0.y);
      ia0.x = fmaf(b0, vx0, ia0.x); ia0.y = fmaf(b0, vy0, ia0.y);
      ra1.x = fmaf(a1, vx1, ra1.x); ra1.y = fmaf(a1, vy1, ra1.y);
      ia1.x = fmaf(b1, vx1, ia1.x); ia1.y = fmaf(b1, vy1, ia1.y);
      ra2.x = fmaf(a2, vx2, ra2.x); ra2.y = fmaf(a2, vy2, ra2.y);
      ia2.x = fmaf(b2, vx2, ia2.x); ia2.y = fmaf(b2, vy2, ia2.y);
      ra3.x = fmaf(a3, vx3, ra3.x); ra3.y = fmaf(a3, vy3, ra3.y);
      ia3.x = fmaf(b3, vx3, ia3.x); ia3.y = fmaf(b3, vy3, ia3.y);
    }
    for (; i < d; ++i) {
      u64 e0 = bk[i];
      int c0 = (int)(unsigned)e0;
      float a0 = b2f((u16)(e0 >> 32)), b0 = b2f((u16)(e0 >> 48));
      ushort2 u0 = *(const ushort2*)&ev16[(size_t)c0 * KD + ln * 2];
      float vx0 = b2f(u0.x), vy0 = b2f(u0.y);
      ra0.x = fmaf(a0, vx0, ra0.x); ra0.y = fmaf(a0, vy0, ra0.y);
      ia0.x = fmaf(b0, vx0, ia0.x); ia0.y = fmaf(b0, vy0, ia0.y);
    }
  } else {
    for (int i = 0; i < d; ++i) {
      u64 e0 = bk[i];
      int c0 = (int)(unsigned)e0;
      float a = b2f((u16)(e0 >> 32)), b = b2f((u16)(e0 >> 48));
      float2 v = *(const float2*)&evf[(size_t)c0 * KD + ln * 2];
      ra0.x = fmaf(a, v.x, ra0.x); ra0.y = fmaf(a, v.y, ra0.y);
      ia0.x = fmaf(b, v.x, ia0.x); ia0.y = fmaf(b, v.y, ia0.y);
    }
  }
  ushort2 ro, io;
  ro.x = f2b((ra0.x + ra1.x) + (ra2.x + ra3.x));
  ro.y = f2b((ra0.y + ra1.y) + (ra2.y + ra3.y));
  io.x = f2b((ia0.x + ia1.x) + (ia2.x + ia3.x));
  io.y = f2b((ia0.y + ia1.y) + (ia2.y + ia3.y));
  *(ushort2*)&gre[(size_t)r * KD + ln * 2] = ro;
  *(ushort2*)&gim[(size_t)r * KD + ln * 2] = io;
}

// Transposed bf16 weights: W*T[c][j] = W[j][c]
__global__ void k_prep_w(const float* __restrict__ W1, const float* __restrict__ W2,
                         u16* W1aT, u16* W1bT, u16* W1cT, u16* W2T) {
  int idx = blockIdx.x * 256 + threadIdx.x;      // 4 * 4 * 16384
  int blk = idx >> 16, rem = idx & 65535;
  int mat = rem >> 14, e = rem & 16383;
  int j = e >> 7, c = e & 127;
  float v;
  u16* dst;
  if (mat < 3) {
    v = W1[(size_t)blk * 3 * 16384 + (size_t)mat * 16384 + e];
    dst = (mat == 0) ? W1aT : (mat == 1 ? W1bT : W1cT);
  } else {
    v = W2[(size_t)blk * 16384 + e];
    dst = W2T;
  }
  dst[(size_t)blk * 16384 + c * 128 + j] = f2b(v);
}

// head weights: B1T[c][k] (64 x 160, k<139 valid), B2T[c][k] (16 x 64, c<5 valid)
__global__ void k_prep_head(const float* __restrict__ Wh1, const float* __restrict__ Wh2,
                            u16* __restrict__ B1T, u16* __restrict__ B2T) {
  for (int idx = threadIdx.x; idx < 64 * 160; idx += 256) {
    int c = idx / 160, k = idx % 160;
    B1T[idx] = f2b(k < (CD + GSDIM) ? Wh1[k * 64 + c] : 0.f);
  }
  for (int idx = threadIdx.x; idx < 16 * 64; idx += 256) {
    int c = idx >> 6, k = idx & 63;
    B2T[idx] = f2b(c < NCLF ? Wh2[k * NCLF + c] : 0.f);
  }
}

// evT_m[b][k][n_pad] = evecs[n][k]*mass[n] bf16 ; ev16 mirror stays UNscaled
__global__ void k_transpose_nk(const float* __restrict__ src, const float* __restrict__ mass,
                               u16* __restrict__ dst, u16* __restrict__ ev16, int writeMir) {
  int b = blockIdx.x / 200, tile = blockIdx.x % 200;
  int n0 = tile * 64;
  size_t gbase = (size_t)b * NPG;
  int t = threadIdx.x;
  __shared__ float ld[64][132];
  __shared__ float ms[64];
  if (t < 64) {
    int gn = n0 + t;
    ms[t] = (gn < NPG) ? mass[gbase + gn] : 0.f;
  }
  int row0 = t >> 5, c4 = t & 31;
#pragma unroll
  for (int it = 0; it < 8; ++it) {
    int r = it * 8 + row0;
    int gn = n0 + r;
    float4 v = make_float4(0.f, 0.f, 0.f, 0.f);
    if (gn < NPG) v = *(const float4*)&src[(gbase + gn) * KD + c4 * 4];
    *(float4*)&ld[r][c4 * 4] = v;
    if (writeMir && gn < NPG) {
      ushort4 o;
      o.x = f2b(v.x); o.y = f2b(v.y); o.z = f2b(v.z); o.w = f2b(v.w);
      *(ushort4*)&ev16[(gbase + gn) * KD + c4 * 4] = o;
    }
  }
  __syncthreads();
  int crow = t >> 1, half = t & 1;
  alignas(16) u16 tmp[8];
#pragma unroll
  for (int q = 0; q < 4; ++q) {
    int nb = half * 32 + q * 8;
#pragma unroll
    for (int i = 0; i < 8; ++i) tmp[i] = f2b(ld[nb + i][crow] * ms[nb + i]);
    *(uint4*)&dst[((size_t)(b * 128 + crow)) * NPGP + n0 + nb] = *(uint4*)tmp;
  }
}

// ---------------------- MFMA kernels ----------------------

// partials[(b*TBSPLIT+s)][k][c] = sum_{n in chunk} evTm[b][k][n]*hT[b][c][n]
__global__ __launch_bounds__(256) void k_tobasis(const u16* __restrict__ evTm,
                                                 const u16* __restrict__ hT,
                                                 float* __restrict__ partials) {
  int s = blockIdx.x % TBSPLIT;
  int b = blockIdx.x / TBSPLIT;
  int t = threadIdx.x, w = t >> 6, l = t & 63;
  __shared__ u16 As[128 * 40];
  __shared__ u16 Bs[128 * 40];
  f32x4 acc[2][8];
  f32x4 z = {0.f, 0.f, 0.f, 0.f};
#pragma unroll
  for (int mi = 0; mi < 2; ++mi)
#pragma unroll
    for (int j = 0; j < 8; ++j) acc[mi][j] = z;
  const u16* ae = evTm + (size_t)b * 128 * NPGP + s * TBCHUNK;
  const u16* bh = hT   + (size_t)b * 128 * NPGP + s * TBCHUNK;
  for (int ks = 0; ks < TBCHUNK / 32; ++ks) {
    stage128_b16(As, ae, NPGP, ks * 32);
    stage128_b16(Bs, bh, NPGP, ks * 32);
    __syncthreads();
    short8v a0 = frag(As, w * 32, l);
    short8v a1 = frag(As, w * 32 + 16, l);
    __builtin_amdgcn_s_setprio(1);
#pragma unroll
    for (int j = 0; j < 8; ++j) {
      short8v bj = frag(Bs, j * 16, l);
      MFMA(acc[0][j], a0, bj);
      MFMA(acc[1][j], a1, bj);
    }
    __builtin_amdgcn_s_setprio(0);
    __syncthreads();
  }
  float* op = partials + (size_t)(b * TBSPLIT + s) * 16384;
#pragma unroll
  for (int mi = 0; mi < 2; ++mi)
#pragma unroll
    for (int j = 0; j < 8; ++j)
#pragma unroll
      for (int i = 0; i < 4; ++i) {
        int krow = w * 32 + mi * 16 + (l >> 4) * 4 + i;
        int c = j * 16 + (l & 15);
        op[krow * 128 + c] = acc[mi][j][i];
      }
}

// spec16[b][k][c] = bf16(scale(sum_s partials)); specT16[b][c][k] = bf16(same)
__global__ void k_reduce_scale_t(const float* __restrict__ partials,
                                 const float* __restrict__ evals,
                                 const float* __restrict__ td,
                                 u16* __restrict__ spec16, u16* __restrict__ specT) {
  int b = blockIdx.x >> 6;
  int idx = (blockIdx.x & 63) * 256 + threadIdx.x;
  int k = idx >> 7, c = idx & 127;
  float s = 0.f;
#pragma unroll 8
  for (int sp = 0; sp < TBSPLIT; ++sp)
    s += partials[(size_t)(b * TBSPLIT + sp) * 16384 + idx];
  float tm = fmaxf(fabsf(td[c]), 1e-8f);
  s *= expf(-evals[b * KD + k] * tm);
  u16 sv = f2b(s);
  spec16[(size_t)b * 16384 + idx] = sv;
  specT[(size_t)b * 16384 + c * 128 + k] = sv;
}

// job0: SAT16[b][c][k] = sum_j Agrad[c][j]*spec[b][k][j]
// job1: M1T16[b][c][k] = sum_j W1bT[c][j]*spec[b][k][j]
__global__ __launch_bounds__(256) void k_smallT(const float* __restrict__ Agrad_blk,
                                                const u16* __restrict__ W1bT_blk,
                                                const u16* __restrict__ spec16,
                                                u16* __restrict__ SAT, u16* __restrict__ M1T) {
  int b = blockIdx.x & 7;
  int job = (blockIdx.x >> 3) & 1;
  int q = blockIdx.x >> 4;                 // 0..3: c-row quarter
  int t = threadIdx.x, w = t >> 6, l = t & 63;
  __shared__ u16 As[128 * 40];
  __shared__ u16 Bs[128 * 40];
  f32x4 acc[2][2];
  f32x4 z = {0.f, 0.f, 0.f, 0.f};
#pragma unroll
  for (int mi = 0; mi < 2; ++mi) { acc[mi][0] = z; acc[mi][1] = z; }
  for (int ks = 0; ks < 4; ++ks) {
    if (job == 0) stage128_f32(As, Agrad_blk, 128, ks * 32);
    else          stage128_b16(As, W1bT_blk, 128, ks * 32);
    stage128_b16(Bs, spec16 + (size_t)b * 16384, 128, ks * 32);
    __syncthreads();
    short8v a0 = frag(As, q * 32, l);
    short8v a1 = frag(As, q * 32 + 16, l);
#pragma unroll
    for (int jj = 0; jj < 2; ++jj) {
      short8v bj = frag(Bs, (w * 2 + jj) * 16, l);
      MFMA(acc[0][jj], a0, bj);
      MFMA(acc[1][jj], a1, bj);
    }
    __syncthreads();
  }
  u16* out = (job == 0 ? SAT : M1T) + (size_t)b * 16384;
#pragma unroll
  for (int mi = 0; mi < 2; ++mi)
#pragma unroll
    for (int jj = 0; jj < 2; ++jj)
#pragma unroll
      for (int i = 0; i < 4; ++i)
        out[(q * 32 + mi * 16 + (l >> 4) * 4 + i) * 128 + (w * 2 + jj) * 16 + (l & 15)] =
            f2b(acc[mi][jj][i]);
}

// gf16 = tanh((Gre@spec')*(Gre@SA) + (Gim@spec')*(Gim@SA))   [bf16 out]
__global__ __launch_bounds__(256) void k_gfeat(const u16* __restrict__ Gre,
                                               const u16* __restrict__ Gim,
                                               const u16* __restrict__ specT,
                                               const u16* __restrict__ SAT,
                                               u16* __restrict__ gf) {
  int b = blockIdx.x / NT32, tile = blockIdx.x % NT32;
  int n0 = tile * 32;
  size_t gbase = (size_t)b * NPG;
  int t = threadIdx.x, w = t >> 6, l = t & 63;
  int r0 = (w & 1) * 16, c0 = (w >> 1) * 64;
  __shared__ u16 Sr[32 * 40];
  __shared__ u16 Si[32 * 40];
  __shared__ u16 Bs[128 * 40];
  __shared__ u16 Ba[128 * 40];
  f32x4 aGR[4], aAR[4], aGI[4], aAI[4];
  f32x4 z = {0.f, 0.f, 0.f, 0.f};
#pragma unroll
  for (int j = 0; j < 4; ++j) { aGR[j] = z; aAR[j] = z; aGI[j] = z; aAI[j] = z; }
  int valid = min(32, NPG - n0);
  const u16* gre = Gre + (gbase + n0) * KD;
  const u16* gim = Gim + (gbase + n0) * KD;
  for (int ks = 0; ks < 4; ++ks) {
    stage32_b16(Sr, gre, KD, ks * 32, valid);
    stage32_b16(Si, gim, KD, ks * 32, valid);
    stage128_b16(Bs, specT + (size_t)b * 16384, 128, ks * 32);
    stage128_b16(Ba, SAT + (size_t)b * 16384, 128, ks * 32);
    __syncthreads();
    short8v fr = frag(Sr, r0, l);
    short8v fi = frag(Si, r0, l);
    __builtin_amdgcn_s_setprio(1);
#pragma unroll
    for (int j = 0; j < 4; ++j) {
      short8v bs = frag(Bs, c0 + j * 16, l);
      short8v ba = frag(Ba, c0 + j * 16, l);
      MFMA(aGR[j], fr, bs);
      MFMA(aAR[j], fr, ba);
      MFMA(aGI[j], fi, bs);
      MFMA(aAI[j], fi, ba);
    }
    __builtin_amdgcn_s_setprio(0);
    __syncthreads();
  }
#pragma unroll
  for (int j = 0; j < 4; ++j) {
    int c = c0 + j * 16 + (l & 15);
#pragma unroll
    for (int i = 0; i < 4; ++i) {
      int n = n0 + r0 + (l >> 4) * 4 + i;
      if (n - n0 < valid) {
        float v = tanhf(fmaf(aGR[j][i], aAR[j][i], aGI[j][i] * aAI[j][i]));
        gf[(gbase + n) * CD + c] = f2b(v);
      }
    }
  }
}

// ---- fused mlp1+mlp2, 512 threads / 128-row tiles; persistent-A + dbuf-B ----
__global__ __launch_bounds__(512) void k_mlp12(const float* __restrict__ evf,
                                               const u16* __restrict__ ev16,
                                               int useB16,
                                               const u16* __restrict__ gf,
                                               const u16* __restrict__ W1aT,
                                               const u16* __restrict__ M1T,
                                               const u16* __restrict__ W1cT,
                                               const float* __restrict__ b1,
                                               const u16* __restrict__ W2T,
                                               const float* __restrict__ b2,
                                               u16* __restrict__ h16,
                                               u16* __restrict__ hT,
                                               int writeHT) {
  int b = blockIdx.x / NT128, tile = blockIdx.x % NT128;
  int n0 = tile * 128;
  size_t gbase = (size_t)b * NPG;
  int t = threadIdx.x, w = t >> 6, l = t & 63;     // 8 waves
  __shared__ u16 SH[27648];
  u16* Af  = SH;
  u16* t1S = SH;
  u16* Tm  = SH;
  u16* Bs0 = SH + 17408;
  u16* Bs1 = SH + 22528;
  f32x4 acc[8];
  f32x4 z = {0.f, 0.f, 0.f, 0.f};
#pragma unroll
  for (int j = 0; j < 8; ++j) acc[j] = z;
  int valid = min(128, NPG - n0);
  int r0 = w * 16;                    // wave's row block

  // ===== phase 1: mlp1 (3 segments of K=128), persistent A per segment =====
  for (int seg = 0; seg < 3; ++seg) {
    const u16* bt = (seg == 0) ? W1aT : (seg == 1 ? M1T + (size_t)b * 16384 : W1cT);
    if (seg == 0)      stageA_b16(Af, h16 + (gbase + n0) * CD, CD, valid);
    else if (seg == 1) {
      if (useB16) stageA_b16(Af, ev16 + (gbase + n0) * KD, KD, valid);
      else        stageA_f32(Af, evf + (gbase + n0) * KD, KD, valid);
    }
    else               stageA_b16(Af, gf + (gbase + n0) * CD, CD, valid);
    stB(Bs0, ldB(bt, 0));
    __syncthreads();
#pragma unroll
    for (int ks = 0; ks < 4; ++ks) {
      uint4 bvn;
      if (ks < 3) bvn = ldB(bt, (ks + 1) * 32);        // issue-early
      short8v a = frag_p(Af, r0, l, 136, ks * 32);
      u16* Bcur = (ks & 1) ? Bs1 : Bs0;
      __builtin_amdgcn_s_setprio(1);
#pragma unroll
      for (int j = 0; j < 8; ++j) MFMA(acc[j], a, frag(Bcur, j * 16, l));
      __builtin_amdgcn_s_setprio(0);
      if (ks < 3) stB((ks & 1) ? Bs0 : Bs1, bvn);       // write-late
      __syncthreads();
    }
  }
  // t1 -> LDS (bf16, relu+bias), pitch 132, overlays Af (all A reads done)
#pragma unroll
  for (int j = 0; j < 8; ++j) {
    int c = j * 16 + (l & 15);
    float bias = b1[c];
#pragma unroll
    for (int i = 0; i < 4; ++i) {
      int row = r0 + (l >> 4) * 4 + i;
      t1S[row * 132 + c] = f2b(fmaxf(acc[j][i] + bias, 0.f));
    }
  }
  stB(Bs0, ldB(W2T, 0));
  __syncthreads();

  // ===== phase 2: mlp2 (K=128), A = t1S persistent =====
#pragma unroll
  for (int j = 0; j < 8; ++j) acc[j] = z;
#pragma unroll
  for (int ks = 0; ks < 4; ++ks) {
    uint4 bvn;
    if (ks < 3) bvn = ldB(W2T, (ks + 1) * 32);
    short8v a = frag_p(t1S, r0, l, 132, ks * 32);
    u16* Bcur = (ks & 1) ? Bs1 : Bs0;
    __builtin_amdgcn_s_setprio(1);
#pragma unroll
    for (int j = 0; j < 8; ++j) MFMA(acc[j], a, frag(Bcur, j * 16, l));
    __builtin_amdgcn_s_setprio(0);
    if (ks < 3) stB((ks & 1) ? Bs0 : Bs1, bvn);
    __syncthreads();
  }

  // ===== epilogue: h16 += mlp2 + b2 (bf16 state) ; hT (plain transpose) =====
#pragma unroll
  for (int j = 0; j < 8; ++j) {
    int c = j * 16 + (l & 15);
    float bias = b2[c];
#pragma unroll
    for (int i = 0; i < 4; ++i) {
      int nl = r0 + (l >> 4) * 4 + i;
      float hv = 0.f;
      if (nl < valid) {
        size_t idx = (gbase + n0 + nl) * (size_t)CD + c;
        hv = b2f(h16[idx]) + acc[j][i] + bias;
        h16[idx] = f2b(hv);
      }
      if (writeHT) Tm[c * 130 + nl] = f2b(hv);
    }
  }
  if (writeHT) {
    __syncthreads();
#pragma unroll
    for (int q = 0; q < 4; ++q) {
      int lin = t + q * 512;            // 2048 chunks of 8 u16 (128c x 128n)
      int cc = lin >> 4, chunk = lin & 15;
      *(uint4*)&hT[((size_t)(b * 128 + cc)) * NPGP + n0 + chunk * 8] =
          *(const uint4*)&Tm[cc * 130 + chunk * 8];
    }
  }
}

// ---- fused 2-layer head (bf16 MFMA): out = relu([h|gs]@Wh1+bh1)@Wh2+bh2 ----
__global__ __launch_bounds__(256) void k_head2(
    const u16* __restrict__ h16, const float* __restrict__ gs,
    const int* __restrict__ batch, const u16* __restrict__ B1T,
    const float* __restrict__ bh1, const u16* __restrict__ B2T,
    const float* __restrict__ bh2, float* __restrict__ out) {
  int n0 = blockIdx.x * 64;
  int t = threadIdx.x, w = t >> 6, l = t & 63;
  __shared__ u16 As[64 * 40];
  __shared__ u16 Bs[64 * 40];
  __shared__ u16 zS[64 * 72];
  int valid = min(64, NNODES - n0);
  f32x4 acc1[4];
  f32x4 z = {0.f, 0.f, 0.f, 0.f};
#pragma unroll
  for (int j = 0; j < 4; ++j) acc1[j] = z;
  for (int ks = 0; ks < 5; ++ks) {
    if (ks < 4) {
      stage64_b16(As, h16 + (size_t)n0 * CD, CD, ks * 32, valid);
    } else {
      int row = t >> 2, kq = t & 3;
      alignas(16) u16 tmp[8];
      int bb = (row < valid) ? batch[n0 + row] : 0;
#pragma unroll
      for (int q = 0; q < 8; ++q) {
        int kk = kq * 8 + q;
        float v = (row < valid && kk < GSDIM) ? gs[bb * GSDIM + kk] : 0.f;
        tmp[q] = f2b(v);
      }
      *(uint4*)&As[row * 40 + kq * 8] = *(uint4*)tmp;
    }
    stage64_b16(Bs, B1T, 160, ks * 32, 64);
    __syncthreads();
    short8v a = frag(As, w * 16, l);
#pragma unroll
    for (int j = 0; j < 4; ++j) MFMA(acc1[j], a, frag(Bs, j * 16, l));
    __syncthreads();
  }
#pragma unroll
  for (int j = 0; j < 4; ++j) {
    int c = j * 16 + (l & 15);
    float bias = bh1[c];
#pragma unroll
    for (int i = 0; i < 4; ++i) {
      int row = w * 16 + (l >> 4) * 4 + i;
      zS[row * 72 + c] = f2b(fmaxf(acc1[j][i] + bias, 0.f));
    }
  }
  __syncthreads();
  f32x4 acc2 = z;
  for (int ks = 0; ks < 2; ++ks) {
    stage64_b16(Bs, B2T, 64, ks * 32, 16);
    __syncthreads();
    short8v a2 = frag_p(zS, w * 16, l, 72, ks * 32);
    MFMA(acc2, a2, frag(Bs, 0, l));
    __syncthreads();
  }
  int c = l & 15;
  if (c < NCLF) {
    float bias = bh2[c];
#pragma unroll
    for (int i = 0; i < 4; ++i) {
      int n = n0 + w * 16 + (l >> 4) * 4 + i;
      if (n < NNODES) out[(size_t)n * NCLF + c] = acc2[i] + bias;
    }
  }
}

extern "C" void kernel_launch(void* const* d_in, const int* in_sizes, int n_in,
                              void* d_out, int out_size, void* d_ws, size_t ws_size,
                              hipStream_t stream) {
  const float* x     = (const float*)d_in[0];
  const float* evals = (const float*)d_in[1];
  const float* evecs = (const float*)d_in[2];
  const float* mass  = (const float*)d_in[3];
  const float* gs    = (const float*)d_in[4];
  const int*   batch = (const int*)d_in[5];
  const int*   grows = (const int*)d_in[6];
  const int*   gcols = (const int*)d_in[7];
  const float* vre   = (const float*)d_in[8];
  const float* vim   = (const float*)d_in[9];
  const float* Wemb  = (const float*)d_in[11];
  const float* bemb  = (const float*)d_in[12];
  const float* tdiff = (const float*)d_in[13];
  const float* Agrad = (const float*)d_in[14];
  const float* W1    = (const float*)d_in[15];
  const float* b1    = (const float*)d_in[16];
  const float* W2    = (const float*)d_in[17];
  const float* b2    = (const float*)d_in[18];
  const float* Wh1   = (const float*)d_in[19];
  const float* bh1   = (const float*)d_in[20];
  const float* Wh2   = (const float*)d_in[21];
  const float* bh2   = (const float*)d_in[22];

  char* base = (char*)d_ws;
  size_t off = 0;
  auto alloc = [&](size_t bytes) -> void* {
    void* p = base + off;
    off += (bytes + 255) & ~(size_t)255;
    return p;
  };
  u16*   evT16  = (u16*)alloc((size_t)NGRAPH * 128 * NPGP * 2);       // 26.2 MB (mass-scaled)
  u16*   hT     = (u16*)alloc((size_t)NGRAPH * 128 * NPGP * 2);       // 26.2 MB (plain h^T)
  u16*   Gre16  = (u16*)alloc((size_t)NNODES * KD * 2);               // 25.6 MB
  u16*   Gim16  = (u16*)alloc((size_t)NNODES * KD * 2);               // 25.6 MB
  u16*   h16    = (u16*)alloc((size_t)NNODES * CD * 2);               // 25.6 MB (sole h state)
  u16*   spec16 = (u16*)alloc((size_t)NGRAPH * 16384 * 2);
  u16*   specT16 = (u16*)alloc((size_t)NGRAPH * 16384 * 2);
  u16*   SAT16  = (u16*)alloc((size_t)NGRAPH * 16384 * 2);
  u16*   M1T16  = (u16*)alloc((size_t)NGRAPH * 16384 * 2);
  u16*   W1aT16 = (u16*)alloc((size_t)NBLKS * 16384 * 2);
  u16*   W1bT16 = (u16*)alloc((size_t)NBLKS * 16384 * 2);
  u16*   W1cT16 = (u16*)alloc((size_t)NBLKS * 16384 * 2);
  u16*   W2T16  = (u16*)alloc((size_t)NBLKS * 16384 * 2);
  u16*   B1T16  = (u16*)alloc(64 * 160 * 2);
  u16*   B2T16  = (u16*)alloc(16 * 64 * 2);
  int*   cnt    = (int*)alloc(100352 * 4);
  // R region (25.6 MB): bucket u64[N*32] / partials 21MB / gf16 25.6MB (disjoint liveness)
  void*  R      = alloc((size_t)NNODES * BCAP * 8);
  u64*   bucket = (u64*)R;
  float* partials = (float*)R;
  u16*   gf16   = (u16*)R;
  // bf16 evecs mirror (only if workspace allows)
  int useEv16 = 0;
  u16* ev16 = nullptr;
  if (off + ((size_t)NNODES * KD * 2 + 256) <= ws_size) {
    ev16 = (u16*)alloc((size_t)NNODES * KD * 2);                      // 25.6 MB
    useEv16 = 1;
  }
  float* out    = (float*)d_out;

  // ---- once per launch ----
  k_embed2<<<NGRAPH * 200, 256, 0, stream>>>(x, Wemb, bemb, h16, hT);
  k_fill0<<<98, 256, 0, stream>>>((float4*)cnt, 100352 / 4);
  k_bucket_place<<<(NEDGE + 255) / 256, 256, 0, stream>>>(grows, gcols, vre, vim,
                                                          cnt, bucket);
  k_transpose_nk<<<NGRAPH * 200, 256, 0, stream>>>(evecs, mass, evT16, ev16, useEv16);
  k_gather_ev<<<NNODES / 4, 256, 0, stream>>>(cnt, bucket, evecs, ev16, useEv16,
                                              Gre16, Gim16);
  k_prep_w<<<1024, 256, 0, stream>>>(W1, W2, W1aT16, W1bT16, W1cT16, W2T16);
  k_prep_head<<<1, 256, 0, stream>>>(Wh1, Wh2, B1T16, B2T16);

  for (int blk = 0; blk < NBLKS; ++blk) {
    k_tobasis<<<NGRAPH * TBSPLIT, 256, 0, stream>>>(evT16, hT, partials);
    k_reduce_scale_t<<<NGRAPH * 64, 256, 0, stream>>>(partials, evals, tdiff + blk * CD,
                                                      spec16, specT16);
    k_smallT<<<64, 256, 0, stream>>>(Agrad + (size_t)blk * 16384,
                                     W1bT16 + (size_t)blk * 16384, spec16, SAT16, M1T16);
    k_gfeat<<<NGRAPH * NT32, 256, 0, stream>>>(Gre16, Gim16, specT16, SAT16, gf16);
    k_mlp12<<<NGRAPH * NT128, 512, 0, stream>>>(evecs, ev16, useEv16, gf16,
                                                W1aT16 + (size_t)blk * 16384, M1T16,
                                                W1cT16 + (size_t)blk * 16384,
                                                b1 + blk * CD,
                                                W2T16 + (size_t)blk * 16384,
                                                b2 + blk * CD, h16, hT,
                                                (blk < NBLKS - 1) ? 1 : 0);
  }
  k_head2<<<(NNODES + 63) / 64, 256, 0, stream>>>(h16, gs, batch, B1T16, bh1,
                                                  B2T16, bh2, out);
}

// Round 20
// 623.471 us; speedup vs baseline: 1.0959x; 1.0159x over previous
//
#include <hip/hip_runtime.h>
#include <hip/hip_bf16.h>

#define NNODES 100000
#define NPG    12500
#define NGRAPH 8
#define KD     128
#define CD     128
#define INDIM  7
#define GSDIM  11
#define NBLKS  4
#define NCLF   5
#define NEDGE  800000
#define BCAP   32             // packed u64 entries; Poisson(8) tail P(d>32) ~ 3e-6
#define NPGP   12800          // padded nodes per graph (40 * 320)
#define TBSPLIT 40            // to_basis split-n
#define TBCHUNK 320           // = NPGP / TBSPLIT, 10 k-steps of 32
#define NT32    391           // ceil(12500/32)
#define NT128   98            // ceil(12500/128)

typedef __attribute__((ext_vector_type(8))) short short8v;
typedef __attribute__((ext_vector_type(4))) float f32x4;
typedef unsigned short u16;
typedef unsigned long long u64;

#define MFMA(acc, a, b) acc = __builtin_amdgcn_mfma_f32_16x16x32_bf16(a, b, acc, 0, 0, 0)

__device__ __forceinline__ u16 f2b(float f) {
  union { __hip_bfloat16 h; u16 u; } cv;
  cv.h = __float2bfloat16(f);
  return cv.u;
}
__device__ __forceinline__ float b2f(u16 u) {
  return __uint_as_float((unsigned)u << 16);
}

// ---------- LDS staging helpers (tile layout: [rows][40] u16, 32 valid k) ----------

__device__ __forceinline__ void stage64_f32(u16* S, const float* src, int ld, int k0, int valid) {
  int t = threadIdx.x, row = t >> 2, kq = t & 3;
  alignas(16) u16 tmp[8] = {0, 0, 0, 0, 0, 0, 0, 0};
  if (row < valid) {
    const float* p = src + (size_t)row * ld + k0 + kq * 8;
    float4 f0 = *(const float4*)p, f1 = *(const float4*)(p + 4);
    tmp[0] = f2b(f0.x); tmp[1] = f2b(f0.y); tmp[2] = f2b(f0.z); tmp[3] = f2b(f0.w);
    tmp[4] = f2b(f1.x); tmp[5] = f2b(f1.y); tmp[6] = f2b(f1.z); tmp[7] = f2b(f1.w);
  }
  *(uint4*)&S[row * 40 + kq * 8] = *(uint4*)tmp;
}

__device__ __forceinline__ void stage64_b16(u16* S, const u16* src, long ld, int k0, int valid) {
  int t = threadIdx.x, row = t >> 2, kq = t & 3;
  uint4 v = make_uint4(0, 0, 0, 0);
  if (row < valid) v = *(const uint4*)(src + (size_t)row * ld + k0 + kq * 8);
  *(uint4*)&S[row * 40 + kq * 8] = v;
}

// 32-row variant: threads 0..127 stage a [32][40] tile
__device__ __forceinline__ void stage32_b16(u16* S, const u16* src, long ld, int k0, int valid) {
  int t = threadIdx.x;
  if (t < 128) {
    int row = t >> 2, kq = t & 3;
    uint4 v = make_uint4(0, 0, 0, 0);
    if (row < valid) v = *(const uint4*)(src + (size_t)row * ld + k0 + kq * 8);
    *(uint4*)&S[row * 40 + kq * 8] = v;
  }
}

__device__ __forceinline__ void stage128_b16(u16* S, const u16* src, long ld, int k0) {
  int t = threadIdx.x, row = t >> 1, half = t & 1;
  const u16* p = src + (size_t)row * ld + k0 + half * 16;
  uint4 v0 = *(const uint4*)p, v1 = *(const uint4*)(p + 8);
  *(uint4*)&S[row * 40 + half * 16] = v0;
  *(uint4*)&S[row * 40 + half * 16 + 8] = v1;
}

__device__ __forceinline__ void stage128_f32(u16* S, const float* src, int ld, int k0) {
  int t = threadIdx.x, row = t >> 1, half = t & 1;
  const float* p = src + (size_t)row * ld + k0 + half * 16;
  float4 f0 = *(const float4*)p, f1 = *(const float4*)(p + 4);
  float4 f2 = *(const float4*)(p + 8), f3 = *(const float4*)(p + 12);
  alignas(16) u16 tmp[16];
  tmp[0] = f2b(f0.x); tmp[1] = f2b(f0.y); tmp[2]  = f2b(f0.z); tmp[3]  = f2b(f0.w);
  tmp[4] = f2b(f1.x); tmp[5] = f2b(f1.y); tmp[6]  = f2b(f1.z); tmp[7]  = f2b(f1.w);
  tmp[8] = f2b(f2.x); tmp[9] = f2b(f2.y); tmp[10] = f2b(f2.z); tmp[11] = f2b(f2.w);
  tmp[12] = f2b(f3.x); tmp[13] = f2b(f3.y); tmp[14] = f2b(f3.z); tmp[15] = f2b(f3.w);
  *(uint4*)&S[row * 40 + half * 16] = *(uint4*)&tmp[0];
  *(uint4*)&S[row * 40 + half * 16 + 8] = *(uint4*)&tmp[8];
}

// full 128x128 A tile staged by 512 threads (pitch 136)
__device__ __forceinline__ void stageA_b16(u16* Af, const u16* src, long ld, int valid) {
  int t = threadIdx.x;
#pragma unroll
  for (int q = 0; q < 4; ++q) {
    int lin = t + q * 512;
    int row = lin >> 4, kq = lin & 15;
    uint4 v = make_uint4(0, 0, 0, 0);
    if (row < valid) v = *(const uint4*)(src + (size_t)row * ld + kq * 8);
    *(uint4*)&Af[row * 136 + kq * 8] = v;
  }
}
__device__ __forceinline__ void stageA_f32(u16* Af, const float* src, long ld, int valid) {
  int t = threadIdx.x;
#pragma unroll
  for (int q = 0; q < 4; ++q) {
    int lin = t + q * 512;
    int row = lin >> 4, kq = lin & 15;
    alignas(16) u16 tmp[8] = {0, 0, 0, 0, 0, 0, 0, 0};
    if (row < valid) {
      const float* p = src + (size_t)row * ld + kq * 8;
      float4 f0 = *(const float4*)p, f1 = *(const float4*)(p + 4);
      tmp[0] = f2b(f0.x); tmp[1] = f2b(f0.y); tmp[2] = f2b(f0.z); tmp[3] = f2b(f0.w);
      tmp[4] = f2b(f1.x); tmp[5] = f2b(f1.y); tmp[6] = f2b(f1.z); tmp[7] = f2b(f1.w);
    }
    *(uint4*)&Af[row * 136 + kq * 8] = *(uint4*)tmp;
  }
}

// B tile (128 rows x 32 k) load/store: 1 uint4 per thread at 512 threads
__device__ __forceinline__ uint4 ldB(const u16* bt, int k0) {
  int t = threadIdx.x, row = t >> 2, kq = t & 3;
  return *(const uint4*)(bt + (size_t)row * 128 + k0 + kq * 8);
}
__device__ __forceinline__ void stB(u16* Bs, uint4 v) {
  int t = threadIdx.x, row = t >> 2, kq = t & 3;
  *(uint4*)&Bs[row * 40 + kq * 8] = v;
}

__device__ __forceinline__ short8v frag(const u16* S, int row0, int l) {
  return *(const short8v*)&S[(row0 + (l & 15)) * 40 + (l >> 4) * 8];
}
__device__ __forceinline__ short8v frag_p(const u16* S, int row0, int l, int pitch, int k0) {
  return *(const short8v*)&S[(row0 + (l & 15)) * pitch + k0 + (l >> 4) * 8];
}

// ---------------------- utility kernels ----------------------

__global__ void k_fill0(float4* p, int n4) {
  int i = blockIdx.x * blockDim.x + threadIdx.x;
  int s = gridDim.x * blockDim.x;
  float4 z = make_float4(0.f, 0.f, 0.f, 0.f);
  for (; i < n4; i += s) p[i] = z;
}

// fused embed: h16 = bf16(relu(x@W+b)); hT = plain transpose (mass folded into evT)
__global__ __launch_bounds__(256) void k_embed2(const float* __restrict__ x,
                                                const float* __restrict__ W,
                                                const float* __restrict__ bv,
                                                u16* __restrict__ h16,
                                                u16* __restrict__ hT) {
  int b = blockIdx.x / 200, tile = blockIdx.x % 200;
  int n0 = tile * 64;
  size_t gbase = (size_t)b * NPG;
  int t = threadIdx.x;
  __shared__ float xs[64][8];
  __shared__ float Ws[INDIM][128];
  __shared__ float bs[128];
  __shared__ float ld[64][132];
  if (t < 128) bs[t] = bv[t];
  for (int i = t; i < INDIM * 128; i += 256) Ws[i >> 7][i & 127] = W[i];
  for (int i = t; i < 64 * INDIM; i += 256) {
    int r = i / INDIM, q = i % INDIM;
    int gn = n0 + r;
    xs[r][q] = (gn < NPG) ? x[(gbase + gn) * INDIM + q] : 0.f;
  }
  __syncthreads();
  {
    int row = t & 63, c0 = (t >> 6) * 32;
#pragma unroll
    for (int cc = 0; cc < 32; ++cc) {
      int c = c0 + cc;
      float acc = bs[c];
#pragma unroll
      for (int i = 0; i < INDIM; ++i) acc = fmaf(xs[row][i], Ws[i][c], acc);
      ld[row][c] = fmaxf(acc, 0.f);
    }
  }
  __syncthreads();
  {
    int row = t >> 2, q = t & 3;
    if (n0 + row < NPG) {
      size_t base = (gbase + n0 + row) * (size_t)CD + q * 32;
      alignas(16) u16 tmp[8];
#pragma unroll
      for (int u = 0; u < 4; ++u) {
#pragma unroll
        for (int i = 0; i < 8; ++i) tmp[i] = f2b(ld[row][q * 32 + u * 8 + i]);
        *(uint4*)&h16[base + u * 8] = *(uint4*)tmp;
      }
    }
  }
  {
    int crow = t >> 1, half = t & 1;
    alignas(16) u16 tmp[8];
#pragma unroll
    for (int q = 0; q < 4; ++q) {
      int nb = half * 32 + q * 8;
#pragma unroll
      for (int i = 0; i < 8; ++i) tmp[i] = f2b(ld[nb + i][crow]);
      *(uint4*)&hT[((size_t)(b * 128 + crow)) * NPGP + n0 + nb] = *(uint4*)tmp;
    }
  }
}

// packed bucket: entry = col | bf16(vre)<<32 | bf16(vim)<<48
__global__ void k_bucket_place(const int* __restrict__ rows, const int* __restrict__ cols,
                               const float* __restrict__ vre, const float* __restrict__ vim,
                               int* cnt, u64* bucket) {
  int e = blockIdx.x * 256 + threadIdx.x;
  if (e >= NEDGE) return;
  int r = rows[e];
  int pos = atomicAdd(&cnt[r], 1);
  if (pos < BCAP) {
    u64 ent = (u64)(unsigned)cols[e]
            | ((u64)f2b(vre[e]) << 32)
            | ((u64)f2b(vim[e]) << 48);
    bucket[(size_t)r * BCAP + pos] = ent;
  }
}

// gather: one wave per row; packed entries; 4-way unroll; XCD-swizzled
__global__ void k_gather_ev(const int* __restrict__ cnt, const u64* __restrict__ bucket,
                            const float* __restrict__ evf, const u16* __restrict__ ev16,
                            int useB16,
                            u16* __restrict__ gre, u16* __restrict__ gim) {
  int orig = blockIdx.x;                       // 25000 = 8 * 3125
  int blk  = (orig & 7) * 3125 + (orig >> 3);  // graph (orig&7) -> XCD (orig&7)
  int wv = threadIdx.x >> 6;
  int ln = threadIdx.x & 63;
  int r  = blk * 4 + wv;
  int d = min(cnt[r], BCAP);
  const u64* bk = bucket + (size_t)r * BCAP;
  float2 ra0 = make_float2(0.f, 0.f), ia0 = make_float2(0.f, 0.f);
  float2 ra1 = make_float2(0.f, 0.f), ia1 = make_float2(0.f, 0.f);
  float2 ra2 = make_float2(0.f, 0.f), ia2 = make_float2(0.f, 0.f);
  float2 ra3 = make_float2(0.f, 0.f), ia3 = make_float2(0.f, 0.f);
  if (useB16) {
    int i = 0;
    for (; i + 4 <= d; i += 4) {
      u64 e0 = bk[i], e1 = bk[i + 1], e2 = bk[i + 2], e3 = bk[i + 3];
      int c0 = (int)(unsigned)e0, c1 = (int)(unsigned)e1;
      int c2 = (int)(unsigned)e2, c3 = (int)(unsigned)e3;
      float a0 = b2f((u16)(e0 >> 32)), b0 = b2f((u16)(e0 >> 48));
      float a1 = b2f((u16)(e1 >> 32)), b1 = b2f((u16)(e1 >> 48));
      float a2 = b2f((u16)(e2 >> 32)), b2 = b2f((u16)(e2 >> 48));
      float a3 = b2f((u16)(e3 >> 32)), b3 = b2f((u16)(e3 >> 48));
      ushort2 u0 = *(const ushort2*)&ev16[(size_t)c0 * KD + ln * 2];
      ushort2 u1 = *(const ushort2*)&ev16[(size_t)c1 * KD + ln * 2];
      ushort2 u2 = *(const ushort2*)&ev16[(size_t)c2 * KD + ln * 2];
      ushort2 u3 = *(const ushort2*)&ev16[(size_t)c3 * KD + ln * 2];
      float vx0 = b2f(u0.x), vy0 = b2f(u0.y);
      float vx1 = b2f(u1.x), vy1 = b2f(u1.y);
      float vx2 = b2f(u2.x), vy2 = b2f(u2.y);
      float vx3 = b2f(u3.x), vy3 = b2f(u3.y);
      ra0.x = fmaf(a0, vx0, ra0.x); ra0.y = fmaf(a0, vy0, ra0.y);
      ia0.x = fmaf(b0, vx0, ia0.x); ia0.y = fmaf(b0, vy0, ia0.y);
      ra1.x = fmaf(a1, vx1, ra1.x); ra1.y = fmaf(a1, vy1, ra1.y);
      ia1.x = fmaf(b1, vx1, ia1.x); ia1.y = fmaf(b1, vy1, ia1.y);
      ra2.x = fmaf(a2, vx2, ra2.x); ra2.y = fmaf(a2, vy2, ra2.y);
      ia2.x = fmaf(b2, vx2, ia2.x); ia2.y = fmaf(b2, vy2, ia2.y);
      ra3.x = fmaf(a3, vx3, ra3.x); ra3.y = fmaf(a3, vy3, ra3.y);
      ia3.x = fmaf(b3, vx3, ia3.x); ia3.y = fmaf(b3, vy3, ia3.y);
    }
    for (; i < d; ++i) {
      u64 e0 = bk[i];
      int c0 = (int)(unsigned)e0;
      float a0 = b2f((u16)(e0 >> 32)), b0 = b2f((u16)(e0 >> 48));
      ushort2 u0 = *(const ushort2*)&ev16[(size_t)c0 * KD + ln * 2];
      float vx0 = b2f(u0.x), vy0 = b2f(u0.y);
      ra0.x = fmaf(a0, vx0, ra0.x); ra0.y = fmaf(a0, vy0, ra0.y);
      ia0.x = fmaf(b0, vx0, ia0.x); ia0.y = fmaf(b0, vy0, ia0.y);
    }
  } else {
    for (int i = 0; i < d; ++i) {
      u64 e0 = bk[i];
      int c0 = (int)(unsigned)e0;
      float a = b2f((u16)(e0 >> 32)), b = b2f((u16)(e0 >> 48));
      float2 v = *(const float2*)&evf[(size_t)c0 * KD + ln * 2];
      ra0.x = fmaf(a, v.x, ra0.x); ra0.y = fmaf(a, v.y, ra0.y);
      ia0.x = fmaf(b, v.x, ia0.x); ia0.y = fmaf(b, v.y, ia0.y);
    }
  }
  ushort2 ro, io;
  ro.x = f2b((ra0.x + ra1.x) + (ra2.x + ra3.x));
  ro.y = f2b((ra0.y + ra1.y) + (ra2.y + ra3.y));
  io.x = f2b((ia0.x + ia1.x) + (ia2.x + ia3.x));
  io.y = f2b((ia0.y + ia1.y) + (ia2.y + ia3.y));
  *(ushort2*)&gre[(size_t)r * KD + ln * 2] = ro;
  *(ushort2*)&gim[(size_t)r * KD + ln * 2] = io;
}

// Transposed bf16 weights: W*T[c][j] = W[j][c]
__global__ void k_prep_w(const float* __restrict__ W1, const float* __restrict__ W2,
                         u16* W1aT, u16* W1bT, u16* W1cT, u16* W2T) {
  int idx = blockIdx.x * 256 + threadIdx.x;      // 4 * 4 * 16384
  int blk = idx >> 16, rem = idx & 65535;
  int mat = rem >> 14, e = rem & 16383;
  int j = e >> 7, c = e & 127;
  float v;
  u16* dst;
  if (mat < 3) {
    v = W1[(size_t)blk * 3 * 16384 + (size_t)mat * 16384 + e];
    dst = (mat == 0) ? W1aT : (mat == 1 ? W1bT : W1cT);
  } else {
    v = W2[(size_t)blk * 16384 + e];
    dst = W2T;
  }
  dst[(size_t)blk * 16384 + c * 128 + j] = f2b(v);
}

// head weights: B1T[c][k] (64 x 160, k<139 valid), B2T[c][k] (16 x 64, c<5 valid)
__global__ void k_prep_head(const float* __restrict__ Wh1, const float* __restrict__ Wh2,
                            u16* __restrict__ B1T, u16* __restrict__ B2T) {
  for (int idx = threadIdx.x; idx < 64 * 160; idx += 256) {
    int c = idx / 160, k = idx % 160;
    B1T[idx] = f2b(k < (CD + GSDIM) ? Wh1[k * 64 + c] : 0.f);
  }
  for (int idx = threadIdx.x; idx < 16 * 64; idx += 256) {
    int c = idx >> 6, k = idx & 63;
    B2T[idx] = f2b(c < NCLF ? Wh2[k * NCLF + c] : 0.f);
  }
}

// evT_m[b][k][n_pad] = evecs[n][k]*mass[n] bf16 ; ev16 mirror stays UNscaled
__global__ void k_transpose_nk(const float* __restrict__ src, const float* __restrict__ mass,
                               u16* __restrict__ dst, u16* __restrict__ ev16, int writeMir) {
  int b = blockIdx.x / 200, tile = blockIdx.x % 200;
  int n0 = tile * 64;
  size_t gbase = (size_t)b * NPG;
  int t = threadIdx.x;
  __shared__ float ld[64][132];
  __shared__ float ms[64];
  if (t < 64) {
    int gn = n0 + t;
    ms[t] = (gn < NPG) ? mass[gbase + gn] : 0.f;
  }
  int row0 = t >> 5, c4 = t & 31;
#pragma unroll
  for (int it = 0; it < 8; ++it) {
    int r = it * 8 + row0;
    int gn = n0 + r;
    float4 v = make_float4(0.f, 0.f, 0.f, 0.f);
    if (gn < NPG) v = *(const float4*)&src[(gbase + gn) * KD + c4 * 4];
    *(float4*)&ld[r][c4 * 4] = v;
    if (writeMir && gn < NPG) {
      ushort4 o;
      o.x = f2b(v.x); o.y = f2b(v.y); o.z = f2b(v.z); o.w = f2b(v.w);
      *(ushort4*)&ev16[(gbase + gn) * KD + c4 * 4] = o;
    }
  }
  __syncthreads();
  int crow = t >> 1, half = t & 1;
  alignas(16) u16 tmp[8];
#pragma unroll
  for (int q = 0; q < 4; ++q) {
    int nb = half * 32 + q * 8;
#pragma unroll
    for (int i = 0; i < 8; ++i) tmp[i] = f2b(ld[nb + i][crow] * ms[nb + i]);
    *(uint4*)&dst[((size_t)(b * 128 + crow)) * NPGP + n0 + nb] = *(uint4*)tmp;
  }
}

// ---------------------- MFMA kernels ----------------------

// partials16[(b*TBSPLIT+s)][k][c] = bf16(sum_{n in chunk} evTm[b][k][n]*hT[b][c][n])
__global__ __launch_bounds__(256) void k_tobasis(const u16* __restrict__ evTm,
                                                 const u16* __restrict__ hT,
                                                 u16* __restrict__ partials16) {
  int s = blockIdx.x % TBSPLIT;
  int b = blockIdx.x / TBSPLIT;
  int t = threadIdx.x, w = t >> 6, l = t & 63;
  __shared__ u16 As[128 * 40];
  __shared__ u16 Bs[128 * 40];
  f32x4 acc[2][8];
  f32x4 z = {0.f, 0.f, 0.f, 0.f};
#pragma unroll
  for (int mi = 0; mi < 2; ++mi)
#pragma unroll
    for (int j = 0; j < 8; ++j) acc[mi][j] = z;
  const u16* ae = evTm + (size_t)b * 128 * NPGP + s * TBCHUNK;
  const u16* bh = hT   + (size_t)b * 128 * NPGP + s * TBCHUNK;
  for (int ks = 0; ks < TBCHUNK / 32; ++ks) {
    stage128_b16(As, ae, NPGP, ks * 32);
    stage128_b16(Bs, bh, NPGP, ks * 32);
    __syncthreads();
    short8v a0 = frag(As, w * 32, l);
    short8v a1 = frag(As, w * 32 + 16, l);
    __builtin_amdgcn_s_setprio(1);
#pragma unroll
    for (int j = 0; j < 8; ++j) {
      short8v bj = frag(Bs, j * 16, l);
      MFMA(acc[0][j], a0, bj);
      MFMA(acc[1][j], a1, bj);
    }
    __builtin_amdgcn_s_setprio(0);
    __syncthreads();
  }
  u16* op = partials16 + (size_t)(b * TBSPLIT + s) * 16384;
#pragma unroll
  for (int mi = 0; mi < 2; ++mi)
#pragma unroll
    for (int j = 0; j < 8; ++j)
#pragma unroll
      for (int i = 0; i < 4; ++i) {
        int krow = w * 32 + mi * 16 + (l >> 4) * 4 + i;
        int c = j * 16 + (l & 15);
        op[krow * 128 + c] = f2b(acc[mi][j][i]);
      }
}

// spec16[b][k][c] = bf16(scale(sum_s partials)); specT16[b][c][k] = same
// 2 c-channels per thread (ushort2 loads); grid = NGRAPH * 32
__global__ void k_reduce_scale_t(const u16* __restrict__ partials16,
                                 const float* __restrict__ evals,
                                 const float* __restrict__ td,
                                 u16* __restrict__ spec16, u16* __restrict__ specT) {
  int b = blockIdx.x >> 5;
  int idx = ((blockIdx.x & 31) * 256 + threadIdx.x) * 2;
  int k = idx >> 7, c = idx & 127;
  float s0 = 0.f, s1 = 0.f;
#pragma unroll 8
  for (int sp = 0; sp < TBSPLIT; ++sp) {
    ushort2 v = *(const ushort2*)&partials16[(size_t)(b * TBSPLIT + sp) * 16384 + idx];
    s0 += b2f(v.x);
    s1 += b2f(v.y);
  }
  float ef = expf(-evals[b * KD + k] * 0.f);   // placeholder removed below
  (void)ef;
  float tm0 = fmaxf(fabsf(td[c]), 1e-8f);
  float tm1 = fmaxf(fabsf(td[c + 1]), 1e-8f);
  float ev = evals[b * KD + k];
  s0 *= expf(-ev * tm0);
  s1 *= expf(-ev * tm1);
  ushort2 sv;
  sv.x = f2b(s0);
  sv.y = f2b(s1);
  *(ushort2*)&spec16[(size_t)b * 16384 + idx] = sv;
  specT[(size_t)b * 16384 + c * 128 + k] = sv.x;
  specT[(size_t)b * 16384 + (c + 1) * 128 + k] = sv.y;
}

// job0: SAT16[b][c][k] = sum_j Agrad[c][j]*spec[b][k][j]
// job1: M1T16[b][c][k] = sum_j W1bT[c][j]*spec[b][k][j]
__global__ __launch_bounds__(256) void k_smallT(const float* __restrict__ Agrad_blk,
                                                const u16* __restrict__ W1bT_blk,
                                                const u16* __restrict__ spec16,
                                                u16* __restrict__ SAT, u16* __restrict__ M1T) {
  int b = blockIdx.x & 7;
  int job = (blockIdx.x >> 3) & 1;
  int q = blockIdx.x >> 4;                 // 0..3: c-row quarter
  int t = threadIdx.x, w = t >> 6, l = t & 63;
  __shared__ u16 As[128 * 40];
  __shared__ u16 Bs[128 * 40];
  f32x4 acc[2][2];
  f32x4 z = {0.f, 0.f, 0.f, 0.f};
#pragma unroll
  for (int mi = 0; mi < 2; ++mi) { acc[mi][0] = z; acc[mi][1] = z; }
  for (int ks = 0; ks < 4; ++ks) {
    if (job == 0) stage128_f32(As, Agrad_blk, 128, ks * 32);
    else          stage128_b16(As, W1bT_blk, 128, ks * 32);
    stage128_b16(Bs, spec16 + (size_t)b * 16384, 128, ks * 32);
    __syncthreads();
    short8v a0 = frag(As, q * 32, l);
    short8v a1 = frag(As, q * 32 + 16, l);
#pragma unroll
    for (int jj = 0; jj < 2; ++jj) {
      short8v bj = frag(Bs, (w * 2 + jj) * 16, l);
      MFMA(acc[0][jj], a0, bj);
      MFMA(acc[1][jj], a1, bj);
    }
    __syncthreads();
  }
  u16* out = (job == 0 ? SAT : M1T) + (size_t)b * 16384;
#pragma unroll
  for (int mi = 0; mi < 2; ++mi)
#pragma unroll
    for (int jj = 0; jj < 2; ++jj)
#pragma unroll
      for (int i = 0; i < 4; ++i)
        out[(q * 32 + mi * 16 + (l >> 4) * 4 + i) * 128 + (w * 2 + jj) * 16 + (l & 15)] =
            f2b(acc[mi][jj][i]);
}

// gf16 = tanh((Gre@spec')*(Gre@SA) + (Gim@spec')*(Gim@SA))   [bf16 out]
__global__ __launch_bounds__(256) void k_gfeat(const u16* __restrict__ Gre,
                                               const u16* __restrict__ Gim,
                                               const u16* __restrict__ specT,
                                               const u16* __restrict__ SAT,
                                               u16* __restrict__ gf) {
  int b = blockIdx.x / NT32, tile = blockIdx.x % NT32;
  int n0 = tile * 32;
  size_t gbase = (size_t)b * NPG;
  int t = threadIdx.x, w = t >> 6, l = t & 63;
  int r0 = (w & 1) * 16, c0 = (w >> 1) * 64;
  __shared__ u16 Sr[32 * 40];
  __shared__ u16 Si[32 * 40];
  __shared__ u16 Bs[128 * 40];
  __shared__ u16 Ba[128 * 40];
  f32x4 aGR[4], aAR[4], aGI[4], aAI[4];
  f32x4 z = {0.f, 0.f, 0.f, 0.f};
#pragma unroll
  for (int j = 0; j < 4; ++j) { aGR[j] = z; aAR[j] = z; aGI[j] = z; aAI[j] = z; }
  int valid = min(32, NPG - n0);
  const u16* gre = Gre + (gbase + n0) * KD;
  const u16* gim = Gim + (gbase + n0) * KD;
  for (int ks = 0; ks < 4; ++ks) {
    stage32_b16(Sr, gre, KD, ks * 32, valid);
    stage32_b16(Si, gim, KD, ks * 32, valid);
    stage128_b16(Bs, specT + (size_t)b * 16384, 128, ks * 32);
    stage128_b16(Ba, SAT + (size_t)b * 16384, 128, ks * 32);
    __syncthreads();
    short8v fr = frag(Sr, r0, l);
    short8v fi = frag(Si, r0, l);
    __builtin_amdgcn_s_setprio(1);
#pragma unroll
    for (int j = 0; j < 4; ++j) {
      short8v bs = frag(Bs, c0 + j * 16, l);
      short8v ba = frag(Ba, c0 + j * 16, l);
      MFMA(aGR[j], fr, bs);
      MFMA(aAR[j], fr, ba);
      MFMA(aGI[j], fi, bs);
      MFMA(aAI[j], fi, ba);
    }
    __builtin_amdgcn_s_setprio(0);
    __syncthreads();
  }
#pragma unroll
  for (int j = 0; j < 4; ++j) {
    int c = c0 + j * 16 + (l & 15);
#pragma unroll
    for (int i = 0; i < 4; ++i) {
      int n = n0 + r0 + (l >> 4) * 4 + i;
      if (n - n0 < valid) {
        float v = tanhf(fmaf(aGR[j][i], aAR[j][i], aGI[j][i] * aAI[j][i]));
        gf[(gbase + n) * CD + c] = f2b(v);
      }
    }
  }
}

// ---- fused mlp1+mlp2, 512 threads / 128-row tiles; persistent-A + dbuf-B ----
__global__ __launch_bounds__(512) void k_mlp12(const float* __restrict__ evf,
                                               const u16* __restrict__ ev16,
                                               int useB16,
                                               const u16* __restrict__ gf,
                                               const u16* __restrict__ W1aT,
                                               const u16* __restrict__ M1T,
                                               const u16* __restrict__ W1cT,
                                               const float* __restrict__ b1,
                                               const u16* __restrict__ W2T,
                                               const float* __restrict__ b2,
                                               u16* __restrict__ h16,
                                               u16* __restrict__ hT,
                                               int writeHT) {
  int b = blockIdx.x / NT128, tile = blockIdx.x % NT128;
  int n0 = tile * 128;
  size_t gbase = (size_t)b * NPG;
  int t = threadIdx.x, w = t >> 6, l = t & 63;     // 8 waves
  __shared__ u16 SH[27648];
  u16* Af  = SH;
  u16* t1S = SH;
  u16* Tm  = SH;
  u16* Bs0 = SH + 17408;
  u16* Bs1 = SH + 22528;
  f32x4 acc[8];
  f32x4 z = {0.f, 0.f, 0.f, 0.f};
#pragma unroll
  for (int j = 0; j < 8; ++j) acc[j] = z;
  int valid = min(128, NPG - n0);
  int r0 = w * 16;                    // wave's row block

  // ===== phase 1: mlp1 (3 segments of K=128), persistent A per segment =====
  for (int seg = 0; seg < 3; ++seg) {
    const u16* bt = (seg == 0) ? W1aT : (seg == 1 ? M1T + (size_t)b * 16384 : W1cT);
    if (seg == 0)      stageA_b16(Af, h16 + (gbase + n0) * CD, CD, valid);
    else if (seg == 1) {
      if (useB16) stageA_b16(Af, ev16 + (gbase + n0) * KD, KD, valid);
      else        stageA_f32(Af, evf + (gbase + n0) * KD, KD, valid);
    }
    else               stageA_b16(Af, gf + (gbase + n0) * CD, CD, valid);
    stB(Bs0, ldB(bt, 0));
    __syncthreads();
#pragma unroll
    for (int ks = 0; ks < 4; ++ks) {
      uint4 bvn;
      if (ks < 3) bvn = ldB(bt, (ks + 1) * 32);        // issue-early
      short8v a = frag_p(Af, r0, l, 136, ks * 32);
      u16* Bcur = (ks & 1) ? Bs1 : Bs0;
      __builtin_amdgcn_s_setprio(1);
#pragma unroll
      for (int j = 0; j < 8; ++j) MFMA(acc[j], a, frag(Bcur, j * 16, l));
      __builtin_amdgcn_s_setprio(0);
      if (ks < 3) stB((ks & 1) ? Bs0 : Bs1, bvn);       // write-late
      __syncthreads();
    }
  }
  // t1 -> LDS (bf16, relu+bias), pitch 132, overlays Af (all A reads done)
#pragma unroll
  for (int j = 0; j < 8; ++j) {
    int c = j * 16 + (l & 15);
    float bias = b1[c];
#pragma unroll
    for (int i = 0; i < 4; ++i) {
      int row = r0 + (l >> 4) * 4 + i;
      t1S[row * 132 + c] = f2b(fmaxf(acc[j][i] + bias, 0.f));
    }
  }
  stB(Bs0, ldB(W2T, 0));
  __syncthreads();

  // ===== phase 2: mlp2 (K=128), A = t1S persistent =====
#pragma unroll
  for (int j = 0; j < 8; ++j) acc[j] = z;
#pragma unroll
  for (int ks = 0; ks < 4; ++ks) {
    uint4 bvn;
    if (ks < 3) bvn = ldB(W2T, (ks + 1) * 32);
    short8v a = frag_p(t1S, r0, l, 132, ks * 32);
    u16* Bcur = (ks & 1) ? Bs1 : Bs0;
    __builtin_amdgcn_s_setprio(1);
#pragma unroll
    for (int j = 0; j < 8; ++j) MFMA(acc[j], a, frag(Bcur, j * 16, l));
    __builtin_amdgcn_s_setprio(0);
    if (ks < 3) stB((ks & 1) ? Bs0 : Bs1, bvn);
    __syncthreads();
  }

  // ===== epilogue: h16 += mlp2 + b2 (bf16 state) ; hT (plain transpose) =====
#pragma unroll
  for (int j = 0; j < 8; ++j) {
    int c = j * 16 + (l & 15);
    float bias = b2[c];
#pragma unroll
    for (int i = 0; i < 4; ++i) {
      int nl = r0 + (l >> 4) * 4 + i;
      float hv = 0.f;
      if (nl < valid) {
        size_t idx = (gbase + n0 + nl) * (size_t)CD + c;
        hv = b2f(h16[idx]) + acc[j][i] + bias;
        h16[idx] = f2b(hv);
      }
      if (writeHT) Tm[c * 130 + nl] = f2b(hv);
    }
  }
  if (writeHT) {
    __syncthreads();
#pragma unroll
    for (int q = 0; q < 4; ++q) {
      int lin = t + q * 512;            // 2048 chunks of 8 u16 (128c x 128n)
      int cc = lin >> 4, chunk = lin & 15;
      *(uint4*)&hT[((size_t)(b * 128 + cc)) * NPGP + n0 + chunk * 8] =
          *(const uint4*)&Tm[cc * 130 + chunk * 8];
    }
  }
}

// ---- fused 2-layer head (bf16 MFMA): out = relu([h|gs]@Wh1+bh1)@Wh2+bh2 ----
__global__ __launch_bounds__(256) void k_head2(
    const u16* __restrict__ h16, const float* __restrict__ gs,
    const int* __restrict__ batch, const u16* __restrict__ B1T,
    const float* __restrict__ bh1, const u16* __restrict__ B2T,
    const float* __restrict__ bh2, float* __restrict__ out) {
  int n0 = blockIdx.x * 64;
  int t = threadIdx.x, w = t >> 6, l = t & 63;
  __shared__ u16 As[64 * 40];
  __shared__ u16 Bs[64 * 40];
  __shared__ u16 zS[64 * 72];
  int valid = min(64, NNODES - n0);
  f32x4 acc1[4];
  f32x4 z = {0.f, 0.f, 0.f, 0.f};
#pragma unroll
  for (int j = 0; j < 4; ++j) acc1[j] = z;
  for (int ks = 0; ks < 5; ++ks) {
    if (ks < 4) {
      stage64_b16(As, h16 + (size_t)n0 * CD, CD, ks * 32, valid);
    } else {
      int row = t >> 2, kq = t & 3;
      alignas(16) u16 tmp[8];
      int bb = (row < valid) ? batch[n0 + row] : 0;
#pragma unroll
      for (int q = 0; q < 8; ++q) {
        int kk = kq * 8 + q;
        float v = (row < valid && kk < GSDIM) ? gs[bb * GSDIM + kk] : 0.f;
        tmp[q] = f2b(v);
      }
      *(uint4*)&As[row * 40 + kq * 8] = *(uint4*)tmp;
    }
    stage64_b16(Bs, B1T, 160, ks * 32, 64);
    __syncthreads();
    short8v a = frag(As, w * 16, l);
#pragma unroll
    for (int j = 0; j < 4; ++j) MFMA(acc1[j], a, frag(Bs, j * 16, l));
    __syncthreads();
  }
#pragma unroll
  for (int j = 0; j < 4; ++j) {
    int c = j * 16 + (l & 15);
    float bias = bh1[c];
#pragma unroll
    for (int i = 0; i < 4; ++i) {
      int row = w * 16 + (l >> 4) * 4 + i;
      zS[row * 72 + c] = f2b(fmaxf(acc1[j][i] + bias, 0.f));
    }
  }
  __syncthreads();
  f32x4 acc2 = z;
  for (int ks = 0; ks < 2; ++ks) {
    stage64_b16(Bs, B2T, 64, ks * 32, 16);
    __syncthreads();
    short8v a2 = frag_p(zS, w * 16, l, 72, ks * 32);
    MFMA(acc2, a2, frag(Bs, 0, l));
    __syncthreads();
  }
  int c = l & 15;
  if (c < NCLF) {
    float bias = bh2[c];
#pragma unroll
    for (int i = 0; i < 4; ++i) {
      int n = n0 + w * 16 + (l >> 4) * 4 + i;
      if (n < NNODES) out[(size_t)n * NCLF + c] = acc2[i] + bias;
    }
  }
}

extern "C" void kernel_launch(void* const* d_in, const int* in_sizes, int n_in,
                              void* d_out, int out_size, void* d_ws, size_t ws_size,
                              hipStream_t stream) {
  const float* x     = (const float*)d_in[0];
  const float* evals = (const float*)d_in[1];
  const float* evecs = (const float*)d_in[2];
  const float* mass  = (const float*)d_in[3];
  const float* gs    = (const float*)d_in[4];
  const int*   batch = (const int*)d_in[5];
  const int*   grows = (const int*)d_in[6];
  const int*   gcols = (const int*)d_in[7];
  const float* vre   = (const float*)d_in[8];
  const float* vim   = (const float*)d_in[9];
  const float* Wemb  = (const float*)d_in[11];
  const float* bemb  = (const float*)d_in[12];
  const float* tdiff = (const float*)d_in[13];
  const float* Agrad = (const float*)d_in[14];
  const float* W1    = (const float*)d_in[15];
  const float* b1    = (const float*)d_in[16];
  const float* W2    = (const float*)d_in[17];
  const float* b2    = (const float*)d_in[18];
  const float* Wh1   = (const float*)d_in[19];
  const float* bh1   = (const float*)d_in[20];
  const float* Wh2   = (const float*)d_in[21];
  const float* bh2   = (const float*)d_in[22];

  char* base = (char*)d_ws;
  size_t off = 0;
  auto alloc = [&](size_t bytes) -> void* {
    void* p = base + off;
    off += (bytes + 255) & ~(size_t)255;
    return p;
  };
  u16*   evT16  = (u16*)alloc((size_t)NGRAPH * 128 * NPGP * 2);       // 26.2 MB (mass-scaled)
  u16*   hT     = (u16*)alloc((size_t)NGRAPH * 128 * NPGP * 2);       // 26.2 MB (plain h^T)
  u16*   Gre16  = (u16*)alloc((size_t)NNODES * KD * 2);               // 25.6 MB
  u16*   Gim16  = (u16*)alloc((size_t)NNODES * KD * 2);               // 25.6 MB
  u16*   h16    = (u16*)alloc((size_t)NNODES * CD * 2);               // 25.6 MB (sole h state)
  u16*   spec16 = (u16*)alloc((size_t)NGRAPH * 16384 * 2);
  u16*   specT16 = (u16*)alloc((size_t)NGRAPH * 16384 * 2);
  u16*   SAT16  = (u16*)alloc((size_t)NGRAPH * 16384 * 2);
  u16*   M1T16  = (u16*)alloc((size_t)NGRAPH * 16384 * 2);
  u16*   W1aT16 = (u16*)alloc((size_t)NBLKS * 16384 * 2);
  u16*   W1bT16 = (u16*)alloc((size_t)NBLKS * 16384 * 2);
  u16*   W1cT16 = (u16*)alloc((size_t)NBLKS * 16384 * 2);
  u16*   W2T16  = (u16*)alloc((size_t)NBLKS * 16384 * 2);
  u16*   B1T16  = (u16*)alloc(64 * 160 * 2);
  u16*   B2T16  = (u16*)alloc(16 * 64 * 2);
  int*   cnt    = (int*)alloc(100352 * 4);
  // R region (25.6 MB): bucket u64[N*32] / partials16 10.5MB / gf16 25.6MB
  void*  R      = alloc((size_t)NNODES * BCAP * 8);
  u64*   bucket = (u64*)R;
  u16*   partials16 = (u16*)R;
  u16*   gf16   = (u16*)R;
  // bf16 evecs mirror (only if workspace allows)
  int useEv16 = 0;
  u16* ev16 = nullptr;
  if (off + ((size_t)NNODES * KD * 2 + 256) <= ws_size) {
    ev16 = (u16*)alloc((size_t)NNODES * KD * 2);                      // 25.6 MB
    useEv16 = 1;
  }
  float* out    = (float*)d_out;

  // ---- once per launch ----
  k_embed2<<<NGRAPH * 200, 256, 0, stream>>>(x, Wemb, bemb, h16, hT);
  k_fill0<<<98, 256, 0, stream>>>((float4*)cnt, 100352 / 4);
  k_bucket_place<<<(NEDGE + 255) / 256, 256, 0, stream>>>(grows, gcols, vre, vim,
                                                          cnt, bucket);
  k_transpose_nk<<<NGRAPH * 200, 256, 0, stream>>>(evecs, mass, evT16, ev16, useEv16);
  k_gather_ev<<<NNODES / 4, 256, 0, stream>>>(cnt, bucket, evecs, ev16, useEv16,
                                              Gre16, Gim16);
  k_prep_w<<<1024, 256, 0, stream>>>(W1, W2, W1aT16, W1bT16, W1cT16, W2T16);
  k_prep_head<<<1, 256, 0, stream>>>(Wh1, Wh2, B1T16, B2T16);

  for (int blk = 0; blk < NBLKS; ++blk) {
    k_tobasis<<<NGRAPH * TBSPLIT, 256, 0, stream>>>(evT16, hT, partials16);
    k_reduce_scale_t<<<NGRAPH * 32, 256, 0, stream>>>(partials16, evals, tdiff + blk * CD,
                                                      spec16, specT16);
    k_smallT<<<64, 256, 0, stream>>>(Agrad + (size_t)blk * 16384,
                                     W1bT16 + (size_t)blk * 16384, spec16, SAT16, M1T16);
    k_gfeat<<<NGRAPH * NT32, 256, 0, stream>>>(Gre16, Gim16, specT16, SAT16, gf16);
    k_mlp12<<<NGRAPH * NT128, 512, 0, stream>>>(evecs, ev16, useEv16, gf16,
                                                W1aT16 + (size_t)blk * 16384, M1T16,
                                                W1cT16 + (size_t)blk * 16384,
                                                b1 + blk * CD,
                                                W2T16 + (size_t)blk * 16384,
                                                b2 + blk * CD, h16, hT,
                                                (blk < NBLKS - 1) ? 1 : 0);
  }
  k_head2<<<(NNODES + 63) / 64, 256, 0, stream>>>(h16, gs, batch, B1T16, bh1,
                                                  B2T16, bh2, out);
}